// Round 3
// baseline (353.683 us; speedup 1.0000x reference)
//
#include <hip/hip_runtime.h>

typedef unsigned short u16;
typedef unsigned int u32;
typedef __attribute__((ext_vector_type(8))) __bf16 bf16x8;
typedef __attribute__((ext_vector_type(4))) float f32x4;
typedef __attribute__((ext_vector_type(8))) unsigned short u16x8;

typedef const __attribute__((address_space(1))) u32 gu32;
typedef __attribute__((address_space(3))) u32 lu32;

// fp32 -> bf16 round-to-nearest-even
__device__ __forceinline__ u16 f2b(float f) {
  u32 u = __builtin_bit_cast(u32, f);
  u32 r = u + 0x7fffu + ((u >> 16) & 1u);
  return (u16)(r >> 16);
}

// packed fp32 pair -> bf16 pair (RNE), hi in [31:16]
__device__ __forceinline__ u32 pk2(float lo, float hi) {
  u32 d;
  asm("v_cvt_pk_bf16_f32 %0, %1, %2" : "=v"(d) : "v"(lo), "v"(hi));
  return d;
}

__device__ __forceinline__ bf16x8 ld8(const u16* p) {
  return __builtin_bit_cast(bf16x8, *(const u16x8*)p);
}

__device__ __forceinline__ void gll16(const void* g, void* l) {
  __builtin_amdgcn_global_load_lds((gu32*)g, (lu32*)l, 16, 0, 0);
}

__device__ __forceinline__ f32x4 mfma16(bf16x8 a, bf16x8 b, f32x4 c) {
  return __builtin_amdgcn_mfma_f32_16x16x32_bf16(a, b, c, 0, 0, 0);
}

// ---------------- fp32 -> bf16 elementwise ----------------
__global__ void k_cvt(const float* __restrict__ in, u16* __restrict__ out, int n4) {
  int i = blockIdx.x * blockDim.x + threadIdx.x;
  int stride = gridDim.x * blockDim.x;
  for (int idx = i; idx < n4; idx += stride) {
    float4 v = ((const float4*)in)[idx];
    u32 lo = (u32)f2b(v.x) | ((u32)f2b(v.y) << 16);
    u32 hi = (u32)f2b(v.z) | ((u32)f2b(v.w) << 16);
    ((uint2*)out)[idx] = make_uint2(lo, hi);
  }
}

// ---------------- transpose+convert: in[R][C] f32 -> out[C][R] bf16 ----------------
__global__ void k_tr(const float* __restrict__ in, u16* __restrict__ out, int R, int C) {
  __shared__ u16 tile[32][33];
  int bx = blockIdx.x * 32;  // along C
  int by = blockIdx.y * 32;  // along R
  int tx = threadIdx.x, ty = threadIdx.y;  // (32, 8)
#pragma unroll
  for (int i = 0; i < 32; i += 8)
    tile[ty + i][tx] = f2b(in[(size_t)(by + ty + i) * C + bx + tx]);
  __syncthreads();
#pragma unroll
  for (int i = 0; i < 32; i += 8)
    out[(size_t)(bx + ty + i) * R + by + tx] = tile[tx][ty + i];
}

// ---------------- GEMM: A[M][1024] * B^T (B given as [N][1024]), 128x128 tile ----------------
// EPI=0: scatter bf16 into q/k [B=4][H=16][T=2048][64] and V TRANSPOSED [B][H][64][T=2048]
//        (V^T lets attention read V fragments directly from global -> no LDS transpose).
// EPI=1: fp32 out [M][1024]
template <int EPI>
__global__ __launch_bounds__(256) void k_gemm(const u16* __restrict__ A,
                                              const u16* __restrict__ B,
                                              void* __restrict__ Cp) {
  const int K = 1024;
  __shared__ __align__(16) u16 As[128 * 32];
  __shared__ __align__(16) u16 Bs[128 * 32];
  int tid = threadIdx.x;
  int lane = tid & 63, wid = tid >> 6;
  int wr = wid >> 1, wc = wid & 1;
  int m0 = blockIdx.y * 128, n0 = blockIdx.x * 128;
  int r = lane & 15, qq = lane >> 4;

  const u16* Ag0 = A + (size_t)(m0 + wid * 32 + (lane >> 2)) * K + (lane & 3) * 8;
  const u16* Bg0 = B + (size_t)(n0 + wid * 32 + (lane >> 2)) * K + (lane & 3) * 8;
  u16* Asl0 = As + (wid * 32) * 32;
  u16* Asl1 = As + (wid * 32 + 16) * 32;
  u16* Bsl0 = Bs + (wid * 32) * 32;
  u16* Bsl1 = Bs + (wid * 32 + 16) * 32;

  f32x4 acc[4][4] = {};

  for (int k0 = 0; k0 < K; k0 += 32) {
    gll16(Ag0 + k0, Asl0);
    gll16(Ag0 + 16 * K + k0, Asl1);
    gll16(Bg0 + k0, Bsl0);
    gll16(Bg0 + 16 * K + k0, Bsl1);
    __syncthreads();
    bf16x8 af[4], bfr[4];
#pragma unroll
    for (int m = 0; m < 4; ++m) af[m] = ld8(&As[(wr * 64 + m * 16 + r) * 32 + qq * 8]);
#pragma unroll
    for (int n = 0; n < 4; ++n) bfr[n] = ld8(&Bs[(wc * 64 + n * 16 + r) * 32 + qq * 8]);
#pragma unroll
    for (int m = 0; m < 4; ++m)
#pragma unroll
      for (int n = 0; n < 4; ++n) acc[m][n] = mfma16(af[m], bfr[n], acc[m][n]);
    __syncthreads();
  }

  if constexpr (EPI == 0) {
    u16* qkv = (u16*)Cp;
#pragma unroll
    for (int m = 0; m < 4; ++m) {
      int gr = m0 + wr * 64 + m * 16 + qq * 4;
      int b = gr >> 11, t0 = gr & 2047;
#pragma unroll
      for (int n = 0; n < 4; ++n) {
        int gc = n0 + wc * 64 + n * 16 + r;
        int which = gc >> 10, rem = gc & 1023;
        int hh = rem >> 6, d = rem & 63;
        if (which == 2) {
          // V^T: [(b*16+hh)*64 + d][2048] ; acc i-index is t (contiguous) -> one 8B store
          u16* dst = qkv + (size_t)2 * 8388608u +
                     ((size_t)((b * 16 + hh) * 64 + d)) * 2048 + t0;
          u32 p0 = pk2(acc[m][n][0], acc[m][n][1]);
          u32 p1 = pk2(acc[m][n][2], acc[m][n][3]);
          *(uint2*)dst = make_uint2(p0, p1);
        } else {
          u16* dst = qkv + (size_t)which * 8388608u +
                     ((size_t)((b * 16 + hh) * 2048 + t0)) * 64 + d;
#pragma unroll
          for (int i = 0; i < 4; ++i) dst[(size_t)i * 64] = f2b(acc[m][n][i]);
        }
      }
    }
  } else {
    float* out = (float*)Cp;
#pragma unroll
    for (int m = 0; m < 4; ++m) {
      int gr = m0 + wr * 64 + m * 16 + qq * 4;
#pragma unroll
      for (int n = 0; n < 4; ++n) {
        int gc = n0 + wc * 64 + n * 16 + r;
#pragma unroll
        for (int i = 0; i < 4; ++i) out[(size_t)(gr + i) * 1024 + gc] = acc[m][n][i];
      }
    }
  }
}

// ---------------- flash attention v2 (barrier-free, L2-direct K/V) ----------------
// q,k [bh][2048][64] bf16; V TRANSPOSED [bh][64][2048] bf16 -> y [B][2048][1024] bf16.
// 1024 blocks (1-D, XCD-swizzled), 4 waves/block, each wave an INDEPENDENT 32-row
// q-tile: no __syncthreads anywhere. K and V^T fragments are loaded directly
// global->reg (per-head K+V = 512 KB, L2-resident; staging them in LDS was pure
// serialization). Each wave loops over exactly its causal tile count.
// Only P round-trips through per-wave LDS (slot-swizzled, lgkmcnt fence only).
// XCD swizzle: block i -> (bh, x) with i = ((bh>>3)*16 + x)*8 + (bh&7), so all 16
// blocks of a head share an XCD residue (head's K/V stays in one L2); x=0 ->
// longest q-block first.
__global__ __launch_bounds__(256) void k_attn(const u16* __restrict__ Qm,
                                              const u16* __restrict__ Km,
                                              const u16* __restrict__ VTm,
                                              u16* __restrict__ Y) {
  int bi = blockIdx.x;
  int kk = bi >> 3;
  int x = kk & 15;
  int bh = (bi & 7) + ((kk >> 4) << 3);
  int b = bh >> 4, h = bh & 15;
  int qb0 = (15 - x) * 128;  // x=0 -> longest
  int tid = threadIdx.x, lane = tid & 63, w = tid >> 6;
  int r = lane & 15, qq = lane >> 4;
  __shared__ __align__(16) u16 Ps[4][32 * 64];  // per-wave P, slot-swizzled
  const size_t base = (size_t)bh * (2048 * 64);  // same extent for K and V^T
  int q0w = qb0 + w * 32;  // this wave's first q row (global)

  // Q fragments: rows m*16+r, k-slices kc*32+qq*8
  bf16x8 qf[2][2];
#pragma unroll
  for (int m = 0; m < 2; ++m)
#pragma unroll
    for (int kc = 0; kc < 2; ++kc)
      qf[m][kc] = ld8(Qm + base + (size_t)(q0w + m * 16 + r) * 64 + kc * 32 + qq * 8);

  f32x4 acc[2][4] = {};
  float m_run[2][4], l_run[2][4];  // l_run: PER-LANE partial sums
#pragma unroll
  for (int m = 0; m < 2; ++m)
#pragma unroll
    for (int i = 0; i < 4; ++i) { m_run[m][i] = -1e30f; l_run[m][i] = 0.f; }
  const float csc = 0.125f * 1.44269504089f;  // 1/sqrt(64) * log2(e)
  int ntw = ((q0w + 31) >> 6) + 1;  // exactly this wave's causal tiles

  for (int it = 0; it < ntw; ++it) {
    int j0 = it << 6;
    // K fragments direct from global (L2): rows nt*16+r of K[key][64]
    bf16x8 kf[4][2];
#pragma unroll
    for (int nt = 0; nt < 4; ++nt)
#pragma unroll
      for (int kc = 0; kc < 2; ++kc)
        kf[nt][kc] = ld8(Km + base + (size_t)(j0 + nt * 16 + r) * 64 + kc * 32 + qq * 8);

    // S = Q K^T
    f32x4 s[2][4] = {};
#pragma unroll
    for (int nt = 0; nt < 4; ++nt)
#pragma unroll
      for (int kc = 0; kc < 2; ++kc)
#pragma unroll
        for (int m = 0; m < 2; ++m) s[m][nt] = mfma16(qf[m][kc], kf[nt][kc], s[m][nt]);

    // V^T fragments direct from global (issued here; softmax below hides latency)
    bf16x8 vfr[4][2];
#pragma unroll
    for (int n = 0; n < 4; ++n)
#pragma unroll
      for (int kc = 0; kc < 2; ++kc)
        vfr[n][kc] = ld8(VTm + base + (size_t)(n * 16 + r) * 2048 + j0 + kc * 32 + qq * 8);

    // scale (log2 domain); causal mask only on diagonal tiles (wave-uniform branch)
    bool nm = (j0 + 63 > q0w);
    if (nm) {
#pragma unroll
      for (int m = 0; m < 2; ++m)
#pragma unroll
        for (int nt = 0; nt < 4; ++nt)
#pragma unroll
          for (int i = 0; i < 4; ++i) {
            int qg = q0w + m * 16 + qq * 4 + i;
            int kg = j0 + nt * 16 + r;
            s[m][nt][i] = (kg <= qg) ? s[m][nt][i] * csc : -1e30f;
          }
    } else {
#pragma unroll
      for (int m = 0; m < 2; ++m)
#pragma unroll
        for (int nt = 0; nt < 4; ++nt)
#pragma unroll
          for (int i = 0; i < 4; ++i) s[m][nt][i] *= csc;
    }

    // row max: fold nt in-lane, then across the 16 r-lanes
    float tm[2][4];
#pragma unroll
    for (int m = 0; m < 2; ++m)
#pragma unroll
      for (int i = 0; i < 4; ++i)
        tm[m][i] = fmaxf(fmaxf(s[m][0][i], s[m][1][i]), fmaxf(s[m][2][i], s[m][3][i]));
#pragma unroll
    for (int d = 1; d < 16; d <<= 1)
#pragma unroll
      for (int m = 0; m < 2; ++m)
#pragma unroll
        for (int i = 0; i < 4; ++i) tm[m][i] = fmaxf(tm[m][i], __shfl_xor(tm[m][i], d));

    // rescale only if the running max grew (corr would be exactly 1 otherwise)
    int growf = 0;
#pragma unroll
    for (int m = 0; m < 2; ++m)
#pragma unroll
      for (int i = 0; i < 4; ++i) growf |= (tm[m][i] > m_run[m][i]) ? 1 : 0;
    if (__any(growf)) {
#pragma unroll
      for (int m = 0; m < 2; ++m)
#pragma unroll
        for (int i = 0; i < 4; ++i) {
          float mn = fmaxf(m_run[m][i], tm[m][i]);
          float corr = exp2f(m_run[m][i] - mn);
          m_run[m][i] = mn;
          l_run[m][i] *= corr;
#pragma unroll
          for (int n = 0; n < 4; ++n) acc[m][n][i] *= corr;
        }
    }

    // P = exp2(S - m); per-lane partial row sums
#pragma unroll
    for (int m = 0; m < 2; ++m)
#pragma unroll
      for (int i = 0; i < 4; ++i) {
        float ls = 0.f;
#pragma unroll
        for (int nt = 0; nt < 4; ++nt) {
          float e = exp2f(s[m][nt][i] - m_run[m][i]);
          s[m][nt][i] = e;
          ls += e;
        }
        l_run[m][i] += ls;
      }

    // P -> per-wave LDS (swizzled) packed bf16; wave-local fence; re-read as A-frags
#pragma unroll
    for (int m = 0; m < 2; ++m)
#pragma unroll
      for (int nt = 0; nt < 4; ++nt) {
        int key = nt * 16 + r;
        int kb = key >> 3, kl = key & 7;
#pragma unroll
        for (int ii = 0; ii < 4; ii += 2) {
          u32 pk = pk2(s[m][nt][ii], s[m][nt][ii + 1]);
          int ql0 = m * 16 + qq * 4 + ii;
          int ql1 = ql0 + 1;
          Ps[w][ql0 * 64 + ((kb ^ (ql0 & 7)) * 8) + kl] = (u16)pk;
          Ps[w][ql1 * 64 + ((kb ^ (ql1 & 7)) * 8) + kl] = (u16)(pk >> 16);
        }
      }
    asm volatile("s_waitcnt lgkmcnt(0)" ::: "memory");  // wave-local LDS RAW fence

#pragma unroll
    for (int m = 0; m < 2; ++m) {
      bf16x8 pf[2];
#pragma unroll
      for (int kc = 0; kc < 2; ++kc)
        pf[kc] = ld8(&Ps[w][(m * 16 + r) * 64 + (((kc * 4 + qq) ^ (r & 7)) * 8)]);
#pragma unroll
      for (int n = 0; n < 4; ++n)
#pragma unroll
        for (int kc = 0; kc < 2; ++kc)
          acc[m][n] = mfma16(pf[kc], vfr[n][kc], acc[m][n]);
    }
  }

  // epilogue: reduce per-lane partial sums across the 16 r-lanes (once)
#pragma unroll
  for (int d = 1; d < 16; d <<= 1)
#pragma unroll
    for (int m = 0; m < 2; ++m)
#pragma unroll
      for (int i = 0; i < 4; ++i) l_run[m][i] += __shfl_xor(l_run[m][i], d);

  float inv[2][4];
#pragma unroll
  for (int m = 0; m < 2; ++m)
#pragma unroll
    for (int i = 0; i < 4; ++i) inv[m][i] = 1.0f / l_run[m][i];
#pragma unroll
  for (int m = 0; m < 2; ++m)
#pragma unroll
    for (int n = 0; n < 4; ++n)
#pragma unroll
      for (int i = 0; i < 4; ++i)
        Y[((size_t)(b * 2048 + q0w + m * 16 + qq * 4 + i)) * 1024 + h * 64 + n * 16 + r] =
            f2b(acc[m][n][i] * inv[m][i]);
}

// ---------------- launch ----------------
extern "C" void kernel_launch(void* const* d_in, const int* in_sizes, int n_in,
                              void* d_out, int out_size, void* d_ws, size_t ws_size,
                              hipStream_t stream) {
  const float* x = (const float*)d_in[0];       // [4,2048,1024]
  const float* w_attn = (const float*)d_in[1];  // [1024,3072]
  const float* w_o = (const float*)d_in[2];     // [1024,1024]
  float* out = (float*)d_out;                   // [4,2048,1024]

  char* ws = (char*)d_ws;
  u16* xb = (u16*)(ws + 0);                    // [8192][1024]        16,777,216 B
  u16* watT = (u16*)(ws + 16777216);           // [3072][1024]         6,291,456 B
  u16* woT = (u16*)(ws + 23068672);            // [1024][1024]         2,097,152 B
  u16* qb = (u16*)(ws + 25165824);             // q [4][16][2048][64] 16,777,216 B
  u16* kb = (u16*)(ws + 41943040);             // k                   16,777,216 B
  u16* vb = (u16*)(ws + 58720256);             // V^T [4][16][64][2048] 16,777,216 B
  u16* yb = (u16*)(ws + 75497472);             // y [4][2048][1024]   16,777,216 B

  k_cvt<<<2048, 256, 0, stream>>>(x, xb, 8192 * 1024 / 4);
  k_tr<<<dim3(3072 / 32, 1024 / 32), dim3(32, 8), 0, stream>>>(w_attn, watT, 1024, 3072);
  k_tr<<<dim3(1024 / 32, 1024 / 32), dim3(32, 8), 0, stream>>>(w_o, woT, 1024, 1024);
  k_gemm<0><<<dim3(24, 64), 256, 0, stream>>>(xb, watT, (void*)qb);
  k_attn<<<dim3(1024), 256, 0, stream>>>(qb, kb, vb, yb);
  k_gemm<1><<<dim3(8, 64), 256, 0, stream>>>(yb, woT, (void*)out);
}

// Round 4
// 291.301 us; speedup vs baseline: 1.2142x; 1.2142x over previous
//
#include <hip/hip_runtime.h>

typedef unsigned short u16;
typedef unsigned int u32;
typedef __attribute__((ext_vector_type(8))) __bf16 bf16x8;
typedef __attribute__((ext_vector_type(4))) float f32x4;
typedef __attribute__((ext_vector_type(8))) unsigned short u16x8;

typedef const __attribute__((address_space(1))) u32 gu32;
typedef __attribute__((address_space(3))) u32 lu32;

// fp32 -> bf16 round-to-nearest-even
__device__ __forceinline__ u16 f2b(float f) {
  u32 u = __builtin_bit_cast(u32, f);
  u32 r = u + 0x7fffu + ((u >> 16) & 1u);
  return (u16)(r >> 16);
}

// packed fp32 pair -> bf16 pair (RNE), hi in [31:16]
__device__ __forceinline__ u32 pk2(float lo, float hi) {
  u32 d;
  asm("v_cvt_pk_bf16_f32 %0, %1, %2" : "=v"(d) : "v"(lo), "v"(hi));
  return d;
}

__device__ __forceinline__ bf16x8 ld8(const u16* p) {
  return __builtin_bit_cast(bf16x8, *(const u16x8*)p);
}

__device__ __forceinline__ void gll16(const void* g, void* l) {
  __builtin_amdgcn_global_load_lds((gu32*)g, (lu32*)l, 16, 0, 0);
}

__device__ __forceinline__ f32x4 mfma16(bf16x8 a, bf16x8 b, f32x4 c) {
  return __builtin_amdgcn_mfma_f32_16x16x32_bf16(a, b, c, 0, 0, 0);
}

// ---------------- fp32 -> bf16 elementwise ----------------
__global__ void k_cvt(const float* __restrict__ in, u16* __restrict__ out, int n4) {
  int i = blockIdx.x * blockDim.x + threadIdx.x;
  int stride = gridDim.x * blockDim.x;
  for (int idx = i; idx < n4; idx += stride) {
    float4 v = ((const float4*)in)[idx];
    u32 lo = (u32)f2b(v.x) | ((u32)f2b(v.y) << 16);
    u32 hi = (u32)f2b(v.z) | ((u32)f2b(v.w) << 16);
    ((uint2*)out)[idx] = make_uint2(lo, hi);
  }
}

// ---------------- transpose+convert: in[R][C] f32 -> out[C][R] bf16 ----------------
__global__ void k_tr(const float* __restrict__ in, u16* __restrict__ out, int R, int C) {
  __shared__ u16 tile[32][33];
  int bx = blockIdx.x * 32;  // along C
  int by = blockIdx.y * 32;  // along R
  int tx = threadIdx.x, ty = threadIdx.y;  // (32, 8)
#pragma unroll
  for (int i = 0; i < 32; i += 8)
    tile[ty + i][tx] = f2b(in[(size_t)(by + ty + i) * C + bx + tx]);
  __syncthreads();
#pragma unroll
  for (int i = 0; i < 32; i += 8)
    out[(size_t)(bx + ty + i) * R + by + tx] = tile[tx][ty + i];
}

// ---------------- GEMM: A[M][1024] * B^T (B given as [N][1024]), 128x128 tile ----------------
// EPI=0: scatter bf16 into q/k [B=4][H=16][T=2048][64] and V TRANSPOSED [B][H][64][T=2048]
//        (V^T lets attention read V fragments directly from global -> no LDS transpose).
// EPI=1: fp32 out [M][1024]
template <int EPI>
__global__ __launch_bounds__(256) void k_gemm(const u16* __restrict__ A,
                                              const u16* __restrict__ B,
                                              void* __restrict__ Cp) {
  const int K = 1024;
  __shared__ __align__(16) u16 As[128 * 32];
  __shared__ __align__(16) u16 Bs[128 * 32];
  int tid = threadIdx.x;
  int lane = tid & 63, wid = tid >> 6;
  int wr = wid >> 1, wc = wid & 1;
  int m0 = blockIdx.y * 128, n0 = blockIdx.x * 128;
  int r = lane & 15, qq = lane >> 4;

  const u16* Ag0 = A + (size_t)(m0 + wid * 32 + (lane >> 2)) * K + (lane & 3) * 8;
  const u16* Bg0 = B + (size_t)(n0 + wid * 32 + (lane >> 2)) * K + (lane & 3) * 8;
  u16* Asl0 = As + (wid * 32) * 32;
  u16* Asl1 = As + (wid * 32 + 16) * 32;
  u16* Bsl0 = Bs + (wid * 32) * 32;
  u16* Bsl1 = Bs + (wid * 32 + 16) * 32;

  f32x4 acc[4][4] = {};

  for (int k0 = 0; k0 < K; k0 += 32) {
    gll16(Ag0 + k0, Asl0);
    gll16(Ag0 + 16 * K + k0, Asl1);
    gll16(Bg0 + k0, Bsl0);
    gll16(Bg0 + 16 * K + k0, Bsl1);
    __syncthreads();
    bf16x8 af[4], bfr[4];
#pragma unroll
    for (int m = 0; m < 4; ++m) af[m] = ld8(&As[(wr * 64 + m * 16 + r) * 32 + qq * 8]);
#pragma unroll
    for (int n = 0; n < 4; ++n) bfr[n] = ld8(&Bs[(wc * 64 + n * 16 + r) * 32 + qq * 8]);
#pragma unroll
    for (int m = 0; m < 4; ++m)
#pragma unroll
      for (int n = 0; n < 4; ++n) acc[m][n] = mfma16(af[m], bfr[n], acc[m][n]);
    __syncthreads();
  }

  if constexpr (EPI == 0) {
    u16* qkv = (u16*)Cp;
#pragma unroll
    for (int m = 0; m < 4; ++m) {
      int gr = m0 + wr * 64 + m * 16 + qq * 4;
      int b = gr >> 11, t0 = gr & 2047;
#pragma unroll
      for (int n = 0; n < 4; ++n) {
        int gc = n0 + wc * 64 + n * 16 + r;
        int which = gc >> 10, rem = gc & 1023;
        int hh = rem >> 6, d = rem & 63;
        if (which == 2) {
          // V^T: [(b*16+hh)*64 + d][2048] ; acc i-index is t (contiguous) -> one 8B store
          u16* dst = qkv + (size_t)2 * 8388608u +
                     ((size_t)((b * 16 + hh) * 64 + d)) * 2048 + t0;
          u32 p0 = pk2(acc[m][n][0], acc[m][n][1]);
          u32 p1 = pk2(acc[m][n][2], acc[m][n][3]);
          *(uint2*)dst = make_uint2(p0, p1);
        } else {
          u16* dst = qkv + (size_t)which * 8388608u +
                     ((size_t)((b * 16 + hh) * 2048 + t0)) * 64 + d;
#pragma unroll
          for (int i = 0; i < 4; ++i) dst[(size_t)i * 64] = f2b(acc[m][n][i]);
        }
      }
    }
  } else {
    float* out = (float*)Cp;
#pragma unroll
    for (int m = 0; m < 4; ++m) {
      int gr = m0 + wr * 64 + m * 16 + qq * 4;
#pragma unroll
      for (int n = 0; n < 4; ++n) {
        int gc = n0 + wc * 64 + n * 16 + r;
#pragma unroll
        for (int i = 0; i < 4; ++i) out[(size_t)(gr + i) * 1024 + gc] = acc[m][n][i];
      }
    }
  }
}

// ---------------- flash attention v2 (barrier-free, L2-direct K/V, K-prefetch) ----------------
// q,k [bh][2048][64] bf16; V TRANSPOSED [bh][64][2048] bf16 -> y [B][2048][1024] bf16.
// 1024 blocks, 4 waves/block, each wave an INDEPENDENT 32-row q-tile; no __syncthreads.
// K and V^T fragments load directly global->reg (per-head K+V = 512 KB, L2-resident).
// Dispatch order (R4): bi = x*64 + bh -> ALL heads' longest q-blocks (x=0) dispatch
// first; short blocks backfill the tail (R3's per-head-group order left heads 48-63's
// 32-tile blocks starting last -> avg occupancy 8.2%). XCD locality kept: bi%8 = bh%8.
// K prefetch (R4): kf for tile it+1 is reloaded right after QK^T consumes kf for tile
// it -> softmax+PV (~1000 cy) hides the L2 latency that R3 exposed serially.
// Only P round-trips through per-wave LDS (slot-swizzled, lgkmcnt fence only).
__global__ __launch_bounds__(256) void k_attn(const u16* __restrict__ Qm,
                                              const u16* __restrict__ Km,
                                              const u16* __restrict__ VTm,
                                              u16* __restrict__ Y) {
  int bi = blockIdx.x;
  int x = bi >> 6;        // 0..15, 0 = longest q-block
  int bh = bi & 63;       // all 16 blocks of a head share bi%8 -> same XCD L2
  int b = bh >> 4, h = bh & 15;
  int qb0 = (15 - x) * 128;
  int tid = threadIdx.x, lane = tid & 63, w = tid >> 6;
  int r = lane & 15, qq = lane >> 4;
  __shared__ __align__(16) u16 Ps[4][32 * 64];  // per-wave P, slot-swizzled
  const size_t base = (size_t)bh * (2048 * 64);  // same extent for K and V^T
  int q0w = qb0 + w * 32;  // this wave's first q row (global)

  // Q fragments: rows m*16+r, k-slices kc*32+qq*8
  bf16x8 qf[2][2];
#pragma unroll
  for (int m = 0; m < 2; ++m)
#pragma unroll
    for (int kc = 0; kc < 2; ++kc)
      qf[m][kc] = ld8(Qm + base + (size_t)(q0w + m * 16 + r) * 64 + kc * 32 + qq * 8);

  f32x4 acc[2][4] = {};
  float m_run[2][4], l_run[2][4];  // l_run: PER-LANE partial sums
#pragma unroll
  for (int m = 0; m < 2; ++m)
#pragma unroll
    for (int i = 0; i < 4; ++i) { m_run[m][i] = -1e30f; l_run[m][i] = 0.f; }
  const float csc = 0.125f * 1.44269504089f;  // 1/sqrt(64) * log2(e)
  int ntw = ((q0w + 31) >> 6) + 1;  // exactly this wave's causal tiles

  // preload K tile 0 fragments
  bf16x8 kf[4][2];
#pragma unroll
  for (int nt = 0; nt < 4; ++nt)
#pragma unroll
    for (int kc = 0; kc < 2; ++kc)
      kf[nt][kc] = ld8(Km + base + (size_t)(nt * 16 + r) * 64 + kc * 32 + qq * 8);

  for (int it = 0; it < ntw; ++it) {
    int j0 = it << 6;

    // S = Q K^T (kf consumed here; its regs are reloaded below for it+1)
    f32x4 s[2][4] = {};
    __builtin_amdgcn_s_setprio(1);
#pragma unroll
    for (int nt = 0; nt < 4; ++nt)
#pragma unroll
      for (int kc = 0; kc < 2; ++kc)
#pragma unroll
        for (int m = 0; m < 2; ++m) s[m][nt] = mfma16(qf[m][kc], kf[nt][kc], s[m][nt]);
    __builtin_amdgcn_s_setprio(0);

    // V^T fragments for THIS tile (consumed at PV; softmax hides latency)
    bf16x8 vfr[4][2];
#pragma unroll
    for (int n = 0; n < 4; ++n)
#pragma unroll
      for (int kc = 0; kc < 2; ++kc)
        vfr[n][kc] = ld8(VTm + base + (size_t)(n * 16 + r) * 2048 + j0 + kc * 32 + qq * 8);

    // K fragments for NEXT tile (in-flight across softmax+PV and the loop edge)
    if (it + 1 < ntw) {
#pragma unroll
      for (int nt = 0; nt < 4; ++nt)
#pragma unroll
        for (int kc = 0; kc < 2; ++kc)
          kf[nt][kc] =
              ld8(Km + base + (size_t)(j0 + 64 + nt * 16 + r) * 64 + kc * 32 + qq * 8);
    }

    // scale (log2 domain); causal mask only on diagonal tiles (wave-uniform branch)
    bool nm = (j0 + 63 > q0w);
    if (nm) {
#pragma unroll
      for (int m = 0; m < 2; ++m)
#pragma unroll
        for (int nt = 0; nt < 4; ++nt)
#pragma unroll
          for (int i = 0; i < 4; ++i) {
            int qg = q0w + m * 16 + qq * 4 + i;
            int kg = j0 + nt * 16 + r;
            s[m][nt][i] = (kg <= qg) ? s[m][nt][i] * csc : -1e30f;
          }
    } else {
#pragma unroll
      for (int m = 0; m < 2; ++m)
#pragma unroll
        for (int nt = 0; nt < 4; ++nt)
#pragma unroll
          for (int i = 0; i < 4; ++i) s[m][nt][i] *= csc;
    }

    // row max: fold nt in-lane, then across the 16 r-lanes
    float tm[2][4];
#pragma unroll
    for (int m = 0; m < 2; ++m)
#pragma unroll
      for (int i = 0; i < 4; ++i)
        tm[m][i] = fmaxf(fmaxf(s[m][0][i], s[m][1][i]), fmaxf(s[m][2][i], s[m][3][i]));
#pragma unroll
    for (int d = 1; d < 16; d <<= 1)
#pragma unroll
      for (int m = 0; m < 2; ++m)
#pragma unroll
        for (int i = 0; i < 4; ++i) tm[m][i] = fmaxf(tm[m][i], __shfl_xor(tm[m][i], d));

    // rescale only if the running max grew (corr would be exactly 1 otherwise)
    int growf = 0;
#pragma unroll
    for (int m = 0; m < 2; ++m)
#pragma unroll
      for (int i = 0; i < 4; ++i) growf |= (tm[m][i] > m_run[m][i]) ? 1 : 0;
    if (__any(growf)) {
#pragma unroll
      for (int m = 0; m < 2; ++m)
#pragma unroll
        for (int i = 0; i < 4; ++i) {
          float mn = fmaxf(m_run[m][i], tm[m][i]);
          float corr = exp2f(m_run[m][i] - mn);
          m_run[m][i] = mn;
          l_run[m][i] *= corr;
#pragma unroll
          for (int n = 0; n < 4; ++n) acc[m][n][i] *= corr;
        }
    }

    // P = exp2(S - m); per-lane partial row sums
#pragma unroll
    for (int m = 0; m < 2; ++m)
#pragma unroll
      for (int i = 0; i < 4; ++i) {
        float ls = 0.f;
#pragma unroll
        for (int nt = 0; nt < 4; ++nt) {
          float e = exp2f(s[m][nt][i] - m_run[m][i]);
          s[m][nt][i] = e;
          ls += e;
        }
        l_run[m][i] += ls;
      }

    // P -> per-wave LDS (swizzled) packed bf16; wave-local fence; re-read as A-frags
#pragma unroll
    for (int m = 0; m < 2; ++m)
#pragma unroll
      for (int nt = 0; nt < 4; ++nt) {
        int key = nt * 16 + r;
        int kb = key >> 3, kl = key & 7;
#pragma unroll
        for (int ii = 0; ii < 4; ii += 2) {
          u32 pk = pk2(s[m][nt][ii], s[m][nt][ii + 1]);
          int ql0 = m * 16 + qq * 4 + ii;
          int ql1 = ql0 + 1;
          Ps[w][ql0 * 64 + ((kb ^ (ql0 & 7)) * 8) + kl] = (u16)pk;
          Ps[w][ql1 * 64 + ((kb ^ (ql1 & 7)) * 8) + kl] = (u16)(pk >> 16);
        }
      }
    asm volatile("s_waitcnt lgkmcnt(0)" ::: "memory");  // wave-local LDS RAW fence

    __builtin_amdgcn_s_setprio(1);
#pragma unroll
    for (int m = 0; m < 2; ++m) {
      bf16x8 pf[2];
#pragma unroll
      for (int kc = 0; kc < 2; ++kc)
        pf[kc] = ld8(&Ps[w][(m * 16 + r) * 64 + (((kc * 4 + qq) ^ (r & 7)) * 8)]);
#pragma unroll
      for (int n = 0; n < 4; ++n)
#pragma unroll
        for (int kc = 0; kc < 2; ++kc)
          acc[m][n] = mfma16(pf[kc], vfr[n][kc], acc[m][n]);
    }
    __builtin_amdgcn_s_setprio(0);
  }

  // epilogue: reduce per-lane partial sums across the 16 r-lanes (once)
#pragma unroll
  for (int d = 1; d < 16; d <<= 1)
#pragma unroll
    for (int m = 0; m < 2; ++m)
#pragma unroll
      for (int i = 0; i < 4; ++i) l_run[m][i] += __shfl_xor(l_run[m][i], d);

  float inv[2][4];
#pragma unroll
  for (int m = 0; m < 2; ++m)
#pragma unroll
    for (int i = 0; i < 4; ++i) inv[m][i] = 1.0f / l_run[m][i];
#pragma unroll
  for (int m = 0; m < 2; ++m)
#pragma unroll
    for (int n = 0; n < 4; ++n)
#pragma unroll
      for (int i = 0; i < 4; ++i)
        Y[((size_t)(b * 2048 + q0w + m * 16 + qq * 4 + i)) * 1024 + h * 64 + n * 16 + r] =
            f2b(acc[m][n][i] * inv[m][i]);
}

// ---------------- launch ----------------
extern "C" void kernel_launch(void* const* d_in, const int* in_sizes, int n_in,
                              void* d_out, int out_size, void* d_ws, size_t ws_size,
                              hipStream_t stream) {
  const float* x = (const float*)d_in[0];       // [4,2048,1024]
  const float* w_attn = (const float*)d_in[1];  // [1024,3072]
  const float* w_o = (const float*)d_in[2];     // [1024,1024]
  float* out = (float*)d_out;                   // [4,2048,1024]

  char* ws = (char*)d_ws;
  u16* xb = (u16*)(ws + 0);                    // [8192][1024]        16,777,216 B
  u16* watT = (u16*)(ws + 16777216);           // [3072][1024]         6,291,456 B
  u16* woT = (u16*)(ws + 23068672);            // [1024][1024]         2,097,152 B
  u16* qb = (u16*)(ws + 25165824);             // q [4][16][2048][64] 16,777,216 B
  u16* kb = (u16*)(ws + 41943040);             // k                   16,777,216 B
  u16* vb = (u16*)(ws + 58720256);             // V^T [4][16][64][2048] 16,777,216 B
  u16* yb = (u16*)(ws + 75497472);             // y [4][2048][1024]   16,777,216 B

  k_cvt<<<2048, 256, 0, stream>>>(x, xb, 8192 * 1024 / 4);
  k_tr<<<dim3(3072 / 32, 1024 / 32), dim3(32, 8), 0, stream>>>(w_attn, watT, 1024, 3072);
  k_tr<<<dim3(1024 / 32, 1024 / 32), dim3(32, 8), 0, stream>>>(w_o, woT, 1024, 1024);
  k_gemm<0><<<dim3(24, 64), 256, 0, stream>>>(xb, watT, (void*)qb);
  k_attn<<<dim3(1024), 256, 0, stream>>>(qb, kb, vb, yb);
  k_gemm<1><<<dim3(8, 64), 256, 0, stream>>>(yb, woT, (void*)out);
}

// Round 5
// 264.033 us; speedup vs baseline: 1.3395x; 1.1033x over previous
//
#include <hip/hip_runtime.h>

typedef unsigned short u16;
typedef unsigned int u32;
typedef __attribute__((ext_vector_type(8))) __bf16 bf16x8;
typedef __attribute__((ext_vector_type(4))) float f32x4;
typedef __attribute__((ext_vector_type(8))) unsigned short u16x8;
typedef __attribute__((ext_vector_type(4))) unsigned int u32x4;

typedef const __attribute__((address_space(1))) u32 gu32;
typedef __attribute__((address_space(3))) u32 lu32;

// fp32 -> bf16 round-to-nearest-even
__device__ __forceinline__ u16 f2b(float f) {
  u32 u = __builtin_bit_cast(u32, f);
  u32 r = u + 0x7fffu + ((u >> 16) & 1u);
  return (u16)(r >> 16);
}

// packed fp32 pair -> bf16 pair (RNE), lo in [15:0]
__device__ __forceinline__ u32 pk2(float lo, float hi) {
  u32 d;
  asm("v_cvt_pk_bf16_f32 %0, %1, %2" : "=v"(d) : "v"(lo), "v"(hi));
  return d;
}

// two f32x4 -> one bf16x8 (elements 0..3 from a, 4..7 from b)
__device__ __forceinline__ bf16x8 pack8(f32x4 a, f32x4 b) {
  u32x4 u;
  u[0] = pk2(a[0], a[1]);
  u[1] = pk2(a[2], a[3]);
  u[2] = pk2(b[0], b[1]);
  u[3] = pk2(b[2], b[3]);
  return __builtin_bit_cast(bf16x8, u);
}

__device__ __forceinline__ bf16x8 ld8(const u16* p) {
  return __builtin_bit_cast(bf16x8, *(const u16x8*)p);
}

__device__ __forceinline__ void gll16(const void* g, void* l) {
  __builtin_amdgcn_global_load_lds((gu32*)g, (lu32*)l, 16, 0, 0);
}

__device__ __forceinline__ f32x4 mfma16(bf16x8 a, bf16x8 b, f32x4 c) {
  return __builtin_amdgcn_mfma_f32_16x16x32_bf16(a, b, c, 0, 0, 0);
}

// ---------------- fp32 -> bf16 elementwise ----------------
__global__ void k_cvt(const float* __restrict__ in, u16* __restrict__ out, int n4) {
  int i = blockIdx.x * blockDim.x + threadIdx.x;
  int stride = gridDim.x * blockDim.x;
  for (int idx = i; idx < n4; idx += stride) {
    float4 v = ((const float4*)in)[idx];
    u32 lo = (u32)f2b(v.x) | ((u32)f2b(v.y) << 16);
    u32 hi = (u32)f2b(v.z) | ((u32)f2b(v.w) << 16);
    ((uint2*)out)[idx] = make_uint2(lo, hi);
  }
}

// ---------------- transpose+convert: in[R][C] f32 -> out[C][R] bf16 ----------------
__global__ void k_tr(const float* __restrict__ in, u16* __restrict__ out, int R, int C) {
  __shared__ u16 tile[32][33];
  int bx = blockIdx.x * 32;  // along C
  int by = blockIdx.y * 32;  // along R
  int tx = threadIdx.x, ty = threadIdx.y;  // (32, 8)
#pragma unroll
  for (int i = 0; i < 32; i += 8)
    tile[ty + i][tx] = f2b(in[(size_t)(by + ty + i) * C + bx + tx]);
  __syncthreads();
#pragma unroll
  for (int i = 0; i < 32; i += 8)
    out[(size_t)(bx + ty + i) * R + by + tx] = tile[tx][ty + i];
}

// ---------------- GEMM: A[M][1024] * B^T (B given as [N][1024]), 128x128 tile ----------------
// EPI=0: scatter bf16 into q/k [B=4][H=16][T=2048][64] and V TRANSPOSED [B][H][64][T=2048].
//        q is stored PRE-SCALED by csc = 1/sqrt(64)*log2(e) (folded out of the attn loop).
// EPI=1: fp32 out [M][1024]
template <int EPI>
__global__ __launch_bounds__(256) void k_gemm(const u16* __restrict__ A,
                                              const u16* __restrict__ B,
                                              void* __restrict__ Cp) {
  const int K = 1024;
  __shared__ __align__(16) u16 As[128 * 32];
  __shared__ __align__(16) u16 Bs[128 * 32];
  int tid = threadIdx.x;
  int lane = tid & 63, wid = tid >> 6;
  int wr = wid >> 1, wc = wid & 1;
  int m0 = blockIdx.y * 128, n0 = blockIdx.x * 128;
  int r = lane & 15, qq = lane >> 4;

  const u16* Ag0 = A + (size_t)(m0 + wid * 32 + (lane >> 2)) * K + (lane & 3) * 8;
  const u16* Bg0 = B + (size_t)(n0 + wid * 32 + (lane >> 2)) * K + (lane & 3) * 8;
  u16* Asl0 = As + (wid * 32) * 32;
  u16* Asl1 = As + (wid * 32 + 16) * 32;
  u16* Bsl0 = Bs + (wid * 32) * 32;
  u16* Bsl1 = Bs + (wid * 32 + 16) * 32;

  f32x4 acc[4][4] = {};

  for (int k0 = 0; k0 < K; k0 += 32) {
    gll16(Ag0 + k0, Asl0);
    gll16(Ag0 + 16 * K + k0, Asl1);
    gll16(Bg0 + k0, Bsl0);
    gll16(Bg0 + 16 * K + k0, Bsl1);
    __syncthreads();
    bf16x8 af[4], bfr[4];
#pragma unroll
    for (int m = 0; m < 4; ++m) af[m] = ld8(&As[(wr * 64 + m * 16 + r) * 32 + qq * 8]);
#pragma unroll
    for (int n = 0; n < 4; ++n) bfr[n] = ld8(&Bs[(wc * 64 + n * 16 + r) * 32 + qq * 8]);
#pragma unroll
    for (int m = 0; m < 4; ++m)
#pragma unroll
      for (int n = 0; n < 4; ++n) acc[m][n] = mfma16(af[m], bfr[n], acc[m][n]);
    __syncthreads();
  }

  if constexpr (EPI == 0) {
    u16* qkv = (u16*)Cp;
#pragma unroll
    for (int m = 0; m < 4; ++m) {
      int gr = m0 + wr * 64 + m * 16 + qq * 4;
      int b = gr >> 11, t0 = gr & 2047;
#pragma unroll
      for (int n = 0; n < 4; ++n) {
        int gc = n0 + wc * 64 + n * 16 + r;
        int which = gc >> 10, rem = gc & 1023;
        int hh = rem >> 6, d = rem & 63;
        if (which == 2) {
          // V^T: [(b*16+hh)*64 + d][2048] ; acc i-index is t (contiguous) -> one 8B store
          u16* dst = qkv + (size_t)2 * 8388608u +
                     ((size_t)((b * 16 + hh) * 64 + d)) * 2048 + t0;
          u32 p0 = pk2(acc[m][n][0], acc[m][n][1]);
          u32 p1 = pk2(acc[m][n][2], acc[m][n][3]);
          *(uint2*)dst = make_uint2(p0, p1);
        } else {
          // q (which==0) pre-scaled by csc; k (which==1) raw
          float sc = (which == 0) ? 0.18033688011112042f : 1.0f;
          u16* dst = qkv + (size_t)which * 8388608u +
                     ((size_t)((b * 16 + hh) * 2048 + t0)) * 64 + d;
#pragma unroll
          for (int i = 0; i < 4; ++i) dst[(size_t)i * 64] = f2b(acc[m][n][i] * sc);
        }
      }
    }
  } else {
    float* out = (float*)Cp;
#pragma unroll
    for (int m = 0; m < 4; ++m) {
      int gr = m0 + wr * 64 + m * 16 + qq * 4;
#pragma unroll
      for (int n = 0; n < 4; ++n) {
        int gc = n0 + wc * 64 + n * 16 + r;
#pragma unroll
        for (int i = 0; i < 4; ++i) out[(size_t)(gr + i) * 1024 + gc] = acc[m][n][i];
      }
    }
  }
}

// ---------------- flash attention v2 (swapped QK^T, fully in-register, zero LDS) ----------------
// q (pre-scaled), k [bh][2048][64] bf16; V TRANSPOSED [bh][64][2048] bf16 -> y bf16.
// 1024 blocks (bi = x*64 + bh, longest-first, bi%8=bh%8 keeps a head on one XCD's L2),
// 4 independent waves/block, 32 q-rows each, no barriers, NO LDS AT ALL.
//
// Swapped product (R5): S-tile computed as mfma(A=K-frag, B=Q-frag) so each lane holds
// P[key][q=m*16+r] with q LANE-LOCAL along r. K-fragment rows are FREELY ASSIGNED
// (direct global loads): A-tile nt, row a holds key knt + 8*(a>>2) + (a&3), where
// knt = 32*(nt>>1) + 4*(nt&1). Then lane (r,qq)'s S outputs are keys knt+8*qq+i --
// exactly the PV A-operand keys kc*32+qq*8+j with nt=2*kc+(j>>2), i=j&3. So P packs
// into PV A-fragments with 8 v_cvt_pk per m: ZERO cross-lane, ZERO LDS round-trip.
// Row-max: 15 in-lane fmax + 2 shfl rounds (xor 16,32). m_run/l_run: 2 scalars/lane.
// Rescale (rare) and final 1/l redistribute to acc layout (q=qq*4+i) via 8 shfl.
// csc folded into the q GEMM epilogue -> non-diagonal tiles do no per-element prep.
__global__ __launch_bounds__(256) void k_attn(const u16* __restrict__ Qm,
                                              const u16* __restrict__ Km,
                                              const u16* __restrict__ VTm,
                                              u16* __restrict__ Y) {
  int bi = blockIdx.x;
  int x = bi >> 6;   // 0..15, 0 = longest q-block
  int bh = bi & 63;  // bi%8 = bh%8 -> head pinned to one XCD residue
  int b = bh >> 4, h = bh & 15;
  int qb0 = (15 - x) * 128;
  int tid = threadIdx.x, lane = tid & 63, w = tid >> 6;
  int r = lane & 15, qq = lane >> 4;
  const size_t base = (size_t)bh * (2048 * 64);
  int q0w = qb0 + w * 32;  // this wave's first q row (global)

  // Q fragments (B-operand): q rows m*16+r, d-slices kc*32+qq*8
  bf16x8 qf[2][2];
#pragma unroll
  for (int m = 0; m < 2; ++m)
#pragma unroll
    for (int kc = 0; kc < 2; ++kc)
      qf[m][kc] = ld8(Qm + base + (size_t)(q0w + m * 16 + r) * 64 + kc * 32 + qq * 8);

  f32x4 acc[2][4] = {};
  float m_run[2] = {-1e30f, -1e30f};
  float l_run[2] = {0.f, 0.f};  // per-lane partial sums over this lane's keys
  int ntw = ((q0w + 31) >> 6) + 1;  // exactly this wave's causal tiles

  // K A-fragment per-lane row offset: row = 8*(r>>2) + (r&3) (+ knt per tile-quarter)
  int ar = 8 * (r >> 2) + (r & 3);
  const u16* Kp = Km + base + (size_t)ar * 64 + qq * 8;    // + (j0+knt)*64 + kc*32
  const u16* Vp = VTm + base + (size_t)r * 2048 + qq * 8;  // + n*16*2048 + j0 + kc*32

  // preload K tile 0 fragments (A-operand, free row assignment)
  bf16x8 kf[4][2];
#pragma unroll
  for (int nt = 0; nt < 4; ++nt) {
    int knt = 32 * (nt >> 1) + 4 * (nt & 1);
#pragma unroll
    for (int kc = 0; kc < 2; ++kc) kf[nt][kc] = ld8(Kp + (size_t)knt * 64 + kc * 32);
  }

  for (int it = 0; it < ntw; ++it) {
    int j0 = it << 6;

    // S = K . Q^T : lane holds S[key = j0+knt+8*qq+i][q = m*16+r]
    f32x4 s[4][2] = {};
    __builtin_amdgcn_s_setprio(1);
#pragma unroll
    for (int nt = 0; nt < 4; ++nt)
#pragma unroll
      for (int kc = 0; kc < 2; ++kc)
#pragma unroll
        for (int m = 0; m < 2; ++m) s[nt][m] = mfma16(kf[nt][kc], qf[m][kc], s[nt][m]);
    __builtin_amdgcn_s_setprio(0);

    // V^T fragments for THIS tile (B-operand; softmax below hides L2 latency)
    bf16x8 vfr[4][2];
#pragma unroll
    for (int n = 0; n < 4; ++n)
#pragma unroll
      for (int kc = 0; kc < 2; ++kc)
        vfr[n][kc] = ld8(Vp + (size_t)(n * 16) * 2048 + j0 + kc * 32);

    // K fragments for NEXT tile (in flight across softmax+PV and the loop edge)
    if (it + 1 < ntw) {
#pragma unroll
      for (int nt = 0; nt < 4; ++nt) {
        int knt = 32 * (nt >> 1) + 4 * (nt & 1);
#pragma unroll
        for (int kc = 0; kc < 2; ++kc)
          kf[nt][kc] = ld8(Kp + (size_t)(j0 + 64 + knt) * 64 + kc * 32);
      }
    }

    // causal mask, diagonal tiles only (wave-uniform branch); q pre-scaled -> no scale op
    bool nm = (j0 + 63 > q0w);
    if (nm) {
#pragma unroll
      for (int nt = 0; nt < 4; ++nt) {
        int kb = j0 + 32 * (nt >> 1) + 4 * (nt & 1) + 8 * qq;
#pragma unroll
        for (int m = 0; m < 2; ++m) {
          int qg = q0w + m * 16 + r;
#pragma unroll
          for (int i = 0; i < 4; ++i)
            s[nt][m][i] = (kb + i <= qg) ? s[nt][m][i] : -1e30f;
        }
      }
    }

    // row max: fold 16 in-lane, then 2 shuffle rounds across qq groups
    float tm[2];
#pragma unroll
    for (int m = 0; m < 2; ++m) {
      float t0 = fmaxf(fmaxf(s[0][m][0], s[0][m][1]), fmaxf(s[0][m][2], s[0][m][3]));
      float t1 = fmaxf(fmaxf(s[1][m][0], s[1][m][1]), fmaxf(s[1][m][2], s[1][m][3]));
      float t2 = fmaxf(fmaxf(s[2][m][0], s[2][m][1]), fmaxf(s[2][m][2], s[2][m][3]));
      float t3 = fmaxf(fmaxf(s[3][m][0], s[3][m][1]), fmaxf(s[3][m][2], s[3][m][3]));
      float t = fmaxf(fmaxf(t0, t1), fmaxf(t2, t3));
      t = fmaxf(t, __shfl_xor(t, 16));
      t = fmaxf(t, __shfl_xor(t, 32));
      tm[m] = t;
    }

    // rescale only if the running max grew (corr would be exactly 1 otherwise)
    int grow = (tm[0] > m_run[0]) | (tm[1] > m_run[1]);
    if (__any(grow)) {
#pragma unroll
      for (int m = 0; m < 2; ++m) {
        float mn = fmaxf(m_run[m], tm[m]);
        float corr = exp2f(m_run[m] - mn);
        m_run[m] = mn;
        l_run[m] *= corr;
        // acc layout has q = m*16 + qq*4 + i -> pull corr from lane qq*4+i
#pragma unroll
        for (int i = 0; i < 4; ++i) {
          float c = __shfl(corr, qq * 4 + i);
#pragma unroll
          for (int n = 0; n < 4; ++n) acc[m][n][i] *= c;
        }
      }
    }

    // P = exp2(S - m); per-lane partial row sums (cross-lane reduce once, in epilogue)
#pragma unroll
    for (int m = 0; m < 2; ++m) {
      float ls = 0.f;
#pragma unroll
      for (int nt = 0; nt < 4; ++nt)
#pragma unroll
        for (int i = 0; i < 4; ++i) {
          float e = exp2f(s[nt][m][i] - m_run[m]);
          s[nt][m][i] = e;
          ls += e;
        }
      l_run[m] += ls;
    }

    // PV: P packs straight into A-fragments in-lane (8 cvt_pk per m), no LDS
    __builtin_amdgcn_s_setprio(1);
#pragma unroll
    for (int m = 0; m < 2; ++m) {
      bf16x8 pa0 = pack8(s[0][m], s[1][m]);  // keys qq*8+0..7
      bf16x8 pa1 = pack8(s[2][m], s[3][m]);  // keys 32+qq*8+0..7
#pragma unroll
      for (int n = 0; n < 4; ++n) acc[m][n] = mfma16(pa0, vfr[n][0], acc[m][n]);
#pragma unroll
      for (int n = 0; n < 4; ++n) acc[m][n] = mfma16(pa1, vfr[n][1], acc[m][n]);
    }
    __builtin_amdgcn_s_setprio(0);
  }

  // epilogue: sum partials across qq groups, invert, redistribute to acc layout
  float li[2][4];
#pragma unroll
  for (int m = 0; m < 2; ++m) {
    float l = l_run[m];
    l += __shfl_xor(l, 16);
    l += __shfl_xor(l, 32);
    float inv = 1.0f / l;
#pragma unroll
    for (int i = 0; i < 4; ++i) li[m][i] = __shfl(inv, qq * 4 + i);
  }
#pragma unroll
  for (int m = 0; m < 2; ++m)
#pragma unroll
    for (int n = 0; n < 4; ++n)
#pragma unroll
      for (int i = 0; i < 4; ++i)
        Y[((size_t)(b * 2048 + q0w + m * 16 + qq * 4 + i)) * 1024 + h * 64 + n * 16 + r] =
            f2b(acc[m][n][i] * li[m][i]);
}

// ---------------- launch ----------------
extern "C" void kernel_launch(void* const* d_in, const int* in_sizes, int n_in,
                              void* d_out, int out_size, void* d_ws, size_t ws_size,
                              hipStream_t stream) {
  const float* x = (const float*)d_in[0];       // [4,2048,1024]
  const float* w_attn = (const float*)d_in[1];  // [1024,3072]
  const float* w_o = (const float*)d_in[2];     // [1024,1024]
  float* out = (float*)d_out;                   // [4,2048,1024]

  char* ws = (char*)d_ws;
  u16* xb = (u16*)(ws + 0);                    // [8192][1024]        16,777,216 B
  u16* watT = (u16*)(ws + 16777216);           // [3072][1024]         6,291,456 B
  u16* woT = (u16*)(ws + 23068672);            // [1024][1024]         2,097,152 B
  u16* qb = (u16*)(ws + 25165824);             // q [4][16][2048][64] 16,777,216 B
  u16* kb = (u16*)(ws + 41943040);             // k                   16,777,216 B
  u16* vb = (u16*)(ws + 58720256);             // V^T [4][16][64][2048] 16,777,216 B
  u16* yb = (u16*)(ws + 75497472);             // y [4][2048][1024]   16,777,216 B

  k_cvt<<<2048, 256, 0, stream>>>(x, xb, 8192 * 1024 / 4);
  k_tr<<<dim3(3072 / 32, 1024 / 32), dim3(32, 8), 0, stream>>>(w_attn, watT, 1024, 3072);
  k_tr<<<dim3(1024 / 32, 1024 / 32), dim3(32, 8), 0, stream>>>(w_o, woT, 1024, 1024);
  k_gemm<0><<<dim3(24, 64), 256, 0, stream>>>(xb, watT, (void*)qb);
  k_attn<<<dim3(1024), 256, 0, stream>>>(qb, kb, vb, yb);
  k_gemm<1><<<dim3(8, 64), 256, 0, stream>>>(yb, woT, (void*)out);
}

// Round 6
// 258.139 us; speedup vs baseline: 1.3701x; 1.0228x over previous
//
#include <hip/hip_runtime.h>

typedef unsigned short u16;
typedef unsigned int u32;
typedef __attribute__((ext_vector_type(8))) __bf16 bf16x8;
typedef __attribute__((ext_vector_type(4))) float f32x4;
typedef __attribute__((ext_vector_type(8))) unsigned short u16x8;
typedef __attribute__((ext_vector_type(4))) unsigned int u32x4;

typedef const __attribute__((address_space(1))) u32 gu32;
typedef __attribute__((address_space(3))) u32 lu32;

// fp32 -> bf16 round-to-nearest-even
__device__ __forceinline__ u16 f2b(float f) {
  u32 u = __builtin_bit_cast(u32, f);
  u32 r = u + 0x7fffu + ((u >> 16) & 1u);
  return (u16)(r >> 16);
}

// packed fp32 pair -> bf16 pair (RNE), lo in [15:0]
__device__ __forceinline__ u32 pk2(float lo, float hi) {
  u32 d;
  asm("v_cvt_pk_bf16_f32 %0, %1, %2" : "=v"(d) : "v"(lo), "v"(hi));
  return d;
}

// two f32x4 -> one bf16x8 (elements 0..3 from a, 4..7 from b)
__device__ __forceinline__ bf16x8 pack8(f32x4 a, f32x4 b) {
  u32x4 u;
  u[0] = pk2(a[0], a[1]);
  u[1] = pk2(a[2], a[3]);
  u[2] = pk2(b[0], b[1]);
  u[3] = pk2(b[2], b[3]);
  return __builtin_bit_cast(bf16x8, u);
}

__device__ __forceinline__ bf16x8 ld8(const u16* p) {
  return __builtin_bit_cast(bf16x8, *(const u16x8*)p);
}

__device__ __forceinline__ void gll16(const void* g, void* l) {
  __builtin_amdgcn_global_load_lds((gu32*)g, (lu32*)l, 16, 0, 0);
}

__device__ __forceinline__ f32x4 mfma16(bf16x8 a, bf16x8 b, f32x4 c) {
  return __builtin_amdgcn_mfma_f32_16x16x32_bf16(a, b, c, 0, 0, 0);
}

// ---------------- fp32 -> bf16 elementwise ----------------
__global__ void k_cvt(const float* __restrict__ in, u16* __restrict__ out, int n4) {
  int i = blockIdx.x * blockDim.x + threadIdx.x;
  int stride = gridDim.x * blockDim.x;
  for (int idx = i; idx < n4; idx += stride) {
    float4 v = ((const float4*)in)[idx];
    u32 lo = (u32)f2b(v.x) | ((u32)f2b(v.y) << 16);
    u32 hi = (u32)f2b(v.z) | ((u32)f2b(v.w) << 16);
    ((uint2*)out)[idx] = make_uint2(lo, hi);
  }
}

// ---------------- transpose+convert: in[R][C] f32 -> out[C][R] bf16 ----------------
__global__ void k_tr(const float* __restrict__ in, u16* __restrict__ out, int R, int C) {
  __shared__ u16 tile[32][33];
  int bx = blockIdx.x * 32;  // along C
  int by = blockIdx.y * 32;  // along R
  int tx = threadIdx.x, ty = threadIdx.y;  // (32, 8)
#pragma unroll
  for (int i = 0; i < 32; i += 8)
    tile[ty + i][tx] = f2b(in[(size_t)(by + ty + i) * C + bx + tx]);
  __syncthreads();
#pragma unroll
  for (int i = 0; i < 32; i += 8)
    out[(size_t)(bx + ty + i) * R + by + tx] = tile[tx][ty + i];
}

// ---------------- GEMM: A[M][1024] * B^T (B given as [N][1024]), 128x128 tile ----------------
// EPI=0: scatter bf16 into q/k [B=4][H=16][T=2048][64] and V TRANSPOSED [B][H][64][T=2048].
//        q is stored PRE-SCALED by csc = 1/sqrt(64)*log2(e) (folded out of the attn loop).
// EPI=1: fp32 out [M][1024]
template <int EPI>
__global__ __launch_bounds__(256) void k_gemm(const u16* __restrict__ A,
                                              const u16* __restrict__ B,
                                              void* __restrict__ Cp) {
  const int K = 1024;
  __shared__ __align__(16) u16 As[128 * 32];
  __shared__ __align__(16) u16 Bs[128 * 32];
  int tid = threadIdx.x;
  int lane = tid & 63, wid = tid >> 6;
  int wr = wid >> 1, wc = wid & 1;
  int m0 = blockIdx.y * 128, n0 = blockIdx.x * 128;
  int r = lane & 15, qq = lane >> 4;

  const u16* Ag0 = A + (size_t)(m0 + wid * 32 + (lane >> 2)) * K + (lane & 3) * 8;
  const u16* Bg0 = B + (size_t)(n0 + wid * 32 + (lane >> 2)) * K + (lane & 3) * 8;
  u16* Asl0 = As + (wid * 32) * 32;
  u16* Asl1 = As + (wid * 32 + 16) * 32;
  u16* Bsl0 = Bs + (wid * 32) * 32;
  u16* Bsl1 = Bs + (wid * 32 + 16) * 32;

  f32x4 acc[4][4] = {};

  for (int k0 = 0; k0 < K; k0 += 32) {
    gll16(Ag0 + k0, Asl0);
    gll16(Ag0 + 16 * K + k0, Asl1);
    gll16(Bg0 + k0, Bsl0);
    gll16(Bg0 + 16 * K + k0, Bsl1);
    __syncthreads();
    bf16x8 af[4], bfr[4];
#pragma unroll
    for (int m = 0; m < 4; ++m) af[m] = ld8(&As[(wr * 64 + m * 16 + r) * 32 + qq * 8]);
#pragma unroll
    for (int n = 0; n < 4; ++n) bfr[n] = ld8(&Bs[(wc * 64 + n * 16 + r) * 32 + qq * 8]);
#pragma unroll
    for (int m = 0; m < 4; ++m)
#pragma unroll
      for (int n = 0; n < 4; ++n) acc[m][n] = mfma16(af[m], bfr[n], acc[m][n]);
    __syncthreads();
  }

  if constexpr (EPI == 0) {
    u16* qkv = (u16*)Cp;
#pragma unroll
    for (int m = 0; m < 4; ++m) {
      int gr = m0 + wr * 64 + m * 16 + qq * 4;
      int b = gr >> 11, t0 = gr & 2047;
#pragma unroll
      for (int n = 0; n < 4; ++n) {
        int gc = n0 + wc * 64 + n * 16 + r;
        int which = gc >> 10, rem = gc & 1023;
        int hh = rem >> 6, d = rem & 63;
        if (which == 2) {
          // V^T: [(b*16+hh)*64 + d][2048] ; acc i-index is t (contiguous) -> one 8B store
          u16* dst = qkv + (size_t)2 * 8388608u +
                     ((size_t)((b * 16 + hh) * 64 + d)) * 2048 + t0;
          u32 p0 = pk2(acc[m][n][0], acc[m][n][1]);
          u32 p1 = pk2(acc[m][n][2], acc[m][n][3]);
          *(uint2*)dst = make_uint2(p0, p1);
        } else {
          // q (which==0) pre-scaled by csc; k (which==1) raw
          float sc = (which == 0) ? 0.18033688011112042f : 1.0f;
          u16* dst = qkv + (size_t)which * 8388608u +
                     ((size_t)((b * 16 + hh) * 2048 + t0)) * 64 + d;
#pragma unroll
          for (int i = 0; i < 4; ++i) dst[(size_t)i * 64] = f2b(acc[m][n][i] * sc);
        }
      }
    }
  } else {
    float* out = (float*)Cp;
#pragma unroll
    for (int m = 0; m < 4; ++m) {
      int gr = m0 + wr * 64 + m * 16 + qq * 4;
#pragma unroll
      for (int n = 0; n < 4; ++n) {
        int gc = n0 + wc * 64 + n * 16 + r;
#pragma unroll
        for (int i = 0; i < 4; ++i) out[(size_t)(gr + i) * 1024 + gc] = acc[m][n][i];
      }
    }
  }
}

// ---------------- flash attention v2 (1 wave per workgroup, swapped QK^T, zero LDS) ----------------
// q (pre-scaled), k [bh][2048][64] bf16; V TRANSPOSED [bh][64][2048] bf16 -> y bf16.
// R6: workgroup = ONE WAVE (64 thr), grid = 4096 = 64 heads x 64 q-tiles of 32 rows.
// The per-wave code was already barrier-free and LDS-free; bundling 4 unequal waves
// (ntw 1..33) into 256-thr blocks pinned wave-slots until the block's LONGEST wave
// finished -> avg occupancy 19%. Wave-granular workgroups let the HW scheduler
// backfill each slot immediately; residency sits at the VGPR cap and the dispatch
// tail is the shortest tasks. Task map: qt = bi>>6 (0 = longest, q0w = 2016-qt*32),
// bh = bi&63 -> bi%8 = bh%8 keeps each head's K/V on one XCD's L2.
//
// Swapped product (R5): S = mfma(A=K-frag, B=Q-frag); lane holds P[key][q=m*16+r],
// keys knt+8*qq+i are exactly the PV A-operand keys -> P packs into PV A-fragments
// with 8 v_cvt_pk per m: zero cross-lane, zero LDS. Row-max: 15 in-lane fmax + 2
// shfl. csc folded into q GEMM epilogue. K prefetched 1 tile ahead (R4).
__global__ __launch_bounds__(64) void k_attn(const u16* __restrict__ Qm,
                                             const u16* __restrict__ Km,
                                             const u16* __restrict__ VTm,
                                             u16* __restrict__ Y) {
  int bi = blockIdx.x;
  int qt = bi >> 6;  // 0..63, 0 = longest q-tile
  int bh = bi & 63;  // bi%8 = bh%8 -> head pinned to one XCD residue
  int b = bh >> 4, h = bh & 15;
  int q0w = 2016 - qt * 32;  // this wave's first q row
  int lane = threadIdx.x & 63;
  int r = lane & 15, qq = lane >> 4;
  const size_t base = (size_t)bh * (2048 * 64);

  // Q fragments (B-operand): q rows m*16+r, d-slices kc*32+qq*8
  bf16x8 qf[2][2];
#pragma unroll
  for (int m = 0; m < 2; ++m)
#pragma unroll
    for (int kc = 0; kc < 2; ++kc)
      qf[m][kc] = ld8(Qm + base + (size_t)(q0w + m * 16 + r) * 64 + kc * 32 + qq * 8);

  f32x4 acc[2][4] = {};
  float m_run[2] = {-1e30f, -1e30f};
  float l_run[2] = {0.f, 0.f};  // per-lane partial sums over this lane's keys
  int ntw = ((q0w + 31) >> 6) + 1;  // exactly this wave's causal tiles

  // K A-fragment per-lane row offset: row = 8*(r>>2) + (r&3) (+ knt per tile-quarter)
  int ar = 8 * (r >> 2) + (r & 3);
  const u16* Kp = Km + base + (size_t)ar * 64 + qq * 8;    // + (j0+knt)*64 + kc*32
  const u16* Vp = VTm + base + (size_t)r * 2048 + qq * 8;  // + n*16*2048 + j0 + kc*32

  // preload K tile 0 fragments (A-operand, free row assignment)
  bf16x8 kf[4][2];
#pragma unroll
  for (int nt = 0; nt < 4; ++nt) {
    int knt = 32 * (nt >> 1) + 4 * (nt & 1);
#pragma unroll
    for (int kc = 0; kc < 2; ++kc) kf[nt][kc] = ld8(Kp + (size_t)knt * 64 + kc * 32);
  }

  for (int it = 0; it < ntw; ++it) {
    int j0 = it << 6;

    // S = K . Q^T : lane holds S[key = j0+knt+8*qq+i][q = m*16+r]
    f32x4 s[4][2] = {};
    __builtin_amdgcn_s_setprio(1);
#pragma unroll
    for (int nt = 0; nt < 4; ++nt)
#pragma unroll
      for (int kc = 0; kc < 2; ++kc)
#pragma unroll
        for (int m = 0; m < 2; ++m) s[nt][m] = mfma16(kf[nt][kc], qf[m][kc], s[nt][m]);
    __builtin_amdgcn_s_setprio(0);

    // V^T fragments for THIS tile (B-operand; softmax below hides L2 latency)
    bf16x8 vfr[4][2];
#pragma unroll
    for (int n = 0; n < 4; ++n)
#pragma unroll
      for (int kc = 0; kc < 2; ++kc)
        vfr[n][kc] = ld8(Vp + (size_t)(n * 16) * 2048 + j0 + kc * 32);

    // K fragments for NEXT tile (in flight across softmax+PV and the loop edge)
    if (it + 1 < ntw) {
#pragma unroll
      for (int nt = 0; nt < 4; ++nt) {
        int knt = 32 * (nt >> 1) + 4 * (nt & 1);
#pragma unroll
        for (int kc = 0; kc < 2; ++kc)
          kf[nt][kc] = ld8(Kp + (size_t)(j0 + 64 + knt) * 64 + kc * 32);
      }
    }

    // causal mask, diagonal tiles only (wave-uniform branch); q pre-scaled -> no scale op
    bool nm = (j0 + 63 > q0w);
    if (nm) {
#pragma unroll
      for (int nt = 0; nt < 4; ++nt) {
        int kb = j0 + 32 * (nt >> 1) + 4 * (nt & 1) + 8 * qq;
#pragma unroll
        for (int m = 0; m < 2; ++m) {
          int qg = q0w + m * 16 + r;
#pragma unroll
          for (int i = 0; i < 4; ++i)
            s[nt][m][i] = (kb + i <= qg) ? s[nt][m][i] : -1e30f;
        }
      }
    }

    // row max: fold 16 in-lane, then 2 shuffle rounds across qq groups
    float tm[2];
#pragma unroll
    for (int m = 0; m < 2; ++m) {
      float t0 = fmaxf(fmaxf(s[0][m][0], s[0][m][1]), fmaxf(s[0][m][2], s[0][m][3]));
      float t1 = fmaxf(fmaxf(s[1][m][0], s[1][m][1]), fmaxf(s[1][m][2], s[1][m][3]));
      float t2 = fmaxf(fmaxf(s[2][m][0], s[2][m][1]), fmaxf(s[2][m][2], s[2][m][3]));
      float t3 = fmaxf(fmaxf(s[3][m][0], s[3][m][1]), fmaxf(s[3][m][2], s[3][m][3]));
      float t = fmaxf(fmaxf(t0, t1), fmaxf(t2, t3));
      t = fmaxf(t, __shfl_xor(t, 16));
      t = fmaxf(t, __shfl_xor(t, 32));
      tm[m] = t;
    }

    // rescale only if the running max grew (corr would be exactly 1 otherwise)
    int grow = (tm[0] > m_run[0]) | (tm[1] > m_run[1]);
    if (__any(grow)) {
#pragma unroll
      for (int m = 0; m < 2; ++m) {
        float mn = fmaxf(m_run[m], tm[m]);
        float corr = exp2f(m_run[m] - mn);
        m_run[m] = mn;
        l_run[m] *= corr;
        // acc layout has q = m*16 + qq*4 + i -> pull corr from lane qq*4+i
#pragma unroll
        for (int i = 0; i < 4; ++i) {
          float c = __shfl(corr, qq * 4 + i);
#pragma unroll
          for (int n = 0; n < 4; ++n) acc[m][n][i] *= c;
        }
      }
    }

    // P = exp2(S - m); per-lane partial row sums (cross-lane reduce once, in epilogue)
#pragma unroll
    for (int m = 0; m < 2; ++m) {
      float ls = 0.f;
#pragma unroll
      for (int nt = 0; nt < 4; ++nt)
#pragma unroll
        for (int i = 0; i < 4; ++i) {
          float e = exp2f(s[nt][m][i] - m_run[m]);
          s[nt][m][i] = e;
          ls += e;
        }
      l_run[m] += ls;
    }

    // PV: P packs straight into A-fragments in-lane (8 cvt_pk per m), no LDS
    __builtin_amdgcn_s_setprio(1);
#pragma unroll
    for (int m = 0; m < 2; ++m) {
      bf16x8 pa0 = pack8(s[0][m], s[1][m]);  // keys qq*8+0..7
      bf16x8 pa1 = pack8(s[2][m], s[3][m]);  // keys 32+qq*8+0..7
#pragma unroll
      for (int n = 0; n < 4; ++n) acc[m][n] = mfma16(pa0, vfr[n][0], acc[m][n]);
#pragma unroll
      for (int n = 0; n < 4; ++n) acc[m][n] = mfma16(pa1, vfr[n][1], acc[m][n]);
    }
    __builtin_amdgcn_s_setprio(0);
  }

  // epilogue: sum partials across qq groups, invert, redistribute to acc layout
  float li[2][4];
#pragma unroll
  for (int m = 0; m < 2; ++m) {
    float l = l_run[m];
    l += __shfl_xor(l, 16);
    l += __shfl_xor(l, 32);
    float inv = 1.0f / l;
#pragma unroll
    for (int i = 0; i < 4; ++i) li[m][i] = __shfl(inv, qq * 4 + i);
  }
#pragma unroll
  for (int m = 0; m < 2; ++m)
#pragma unroll
    for (int n = 0; n < 4; ++n)
#pragma unroll
      for (int i = 0; i < 4; ++i)
        Y[((size_t)(b * 2048 + q0w + m * 16 + qq * 4 + i)) * 1024 + h * 64 + n * 16 + r] =
            f2b(acc[m][n][i] * li[m][i]);
}

// ---------------- launch ----------------
extern "C" void kernel_launch(void* const* d_in, const int* in_sizes, int n_in,
                              void* d_out, int out_size, void* d_ws, size_t ws_size,
                              hipStream_t stream) {
  const float* x = (const float*)d_in[0];       // [4,2048,1024]
  const float* w_attn = (const float*)d_in[1];  // [1024,3072]
  const float* w_o = (const float*)d_in[2];     // [1024,1024]
  float* out = (float*)d_out;                   // [4,2048,1024]

  char* ws = (char*)d_ws;
  u16* xb = (u16*)(ws + 0);                    // [8192][1024]        16,777,216 B
  u16* watT = (u16*)(ws + 16777216);           // [3072][1024]         6,291,456 B
  u16* woT = (u16*)(ws + 23068672);            // [1024][1024]         2,097,152 B
  u16* qb = (u16*)(ws + 25165824);             // q [4][16][2048][64] 16,777,216 B
  u16* kb = (u16*)(ws + 41943040);             // k                   16,777,216 B
  u16* vb = (u16*)(ws + 58720256);             // V^T [4][16][64][2048] 16,777,216 B
  u16* yb = (u16*)(ws + 75497472);             // y [4][2048][1024]   16,777,216 B

  k_cvt<<<2048, 256, 0, stream>>>(x, xb, 8192 * 1024 / 4);
  k_tr<<<dim3(3072 / 32, 1024 / 32), dim3(32, 8), 0, stream>>>(w_attn, watT, 1024, 3072);
  k_tr<<<dim3(1024 / 32, 1024 / 32), dim3(32, 8), 0, stream>>>(w_o, woT, 1024, 1024);
  k_gemm<0><<<dim3(24, 64), 256, 0, stream>>>(xb, watT, (void*)qb);
  k_attn<<<dim3(4096), 64, 0, stream>>>(qb, kb, vb, yb);
  k_gemm<1><<<dim3(8, 64), 256, 0, stream>>>(yb, woT, (void*)out);
}

// Round 7
// 255.363 us; speedup vs baseline: 1.3850x; 1.0109x over previous
//
#include <hip/hip_runtime.h>

typedef unsigned short u16;
typedef unsigned int u32;
typedef __attribute__((ext_vector_type(8))) __bf16 bf16x8;
typedef __attribute__((ext_vector_type(4))) float f32x4;
typedef __attribute__((ext_vector_type(8))) unsigned short u16x8;
typedef __attribute__((ext_vector_type(4))) unsigned int u32x4;

typedef const __attribute__((address_space(1))) u32 gu32;
typedef __attribute__((address_space(3))) u32 lu32;

// fp32 -> bf16 round-to-nearest-even
__device__ __forceinline__ u16 f2b(float f) {
  u32 u = __builtin_bit_cast(u32, f);
  u32 r = u + 0x7fffu + ((u >> 16) & 1u);
  return (u16)(r >> 16);
}

// packed fp32 pair -> bf16 pair (RNE), lo in [15:0]
__device__ __forceinline__ u32 pk2(float lo, float hi) {
  u32 d;
  asm("v_cvt_pk_bf16_f32 %0, %1, %2" : "=v"(d) : "v"(lo), "v"(hi));
  return d;
}

// two f32x4 -> one bf16x8 (elements 0..3 from a, 4..7 from b)
__device__ __forceinline__ bf16x8 pack8(f32x4 a, f32x4 b) {
  u32x4 u;
  u[0] = pk2(a[0], a[1]);
  u[1] = pk2(a[2], a[3]);
  u[2] = pk2(b[0], b[1]);
  u[3] = pk2(b[2], b[3]);
  return __builtin_bit_cast(bf16x8, u);
}

__device__ __forceinline__ bf16x8 ld8(const u16* p) {
  return __builtin_bit_cast(bf16x8, *(const u16x8*)p);
}

__device__ __forceinline__ void gll16(const void* g, void* l) {
  __builtin_amdgcn_global_load_lds((gu32*)g, (lu32*)l, 16, 0, 0);
}

__device__ __forceinline__ f32x4 mfma16(bf16x8 a, bf16x8 b, f32x4 c) {
  return __builtin_amdgcn_mfma_f32_16x16x32_bf16(a, b, c, 0, 0, 0);
}

// ---------------- fp32 -> bf16 elementwise ----------------
__global__ void k_cvt(const float* __restrict__ in, u16* __restrict__ out, int n4) {
  int i = blockIdx.x * blockDim.x + threadIdx.x;
  int stride = gridDim.x * blockDim.x;
  for (int idx = i; idx < n4; idx += stride) {
    float4 v = ((const float4*)in)[idx];
    u32 lo = (u32)f2b(v.x) | ((u32)f2b(v.y) << 16);
    u32 hi = (u32)f2b(v.z) | ((u32)f2b(v.w) << 16);
    ((uint2*)out)[idx] = make_uint2(lo, hi);
  }
}

// ---------------- transpose+convert: in[R][C] f32 -> out[C][R] bf16 ----------------
__global__ void k_tr(const float* __restrict__ in, u16* __restrict__ out, int R, int C) {
  __shared__ u16 tile[32][33];
  int bx = blockIdx.x * 32;  // along C
  int by = blockIdx.y * 32;  // along R
  int tx = threadIdx.x, ty = threadIdx.y;  // (32, 8)
#pragma unroll
  for (int i = 0; i < 32; i += 8)
    tile[ty + i][tx] = f2b(in[(size_t)(by + ty + i) * C + bx + tx]);
  __syncthreads();
#pragma unroll
  for (int i = 0; i < 32; i += 8)
    out[(size_t)(bx + ty + i) * R + by + tx] = tile[tx][ty + i];
}

// ---------------- GEMM: A[M][1024] * B^T (B given as [N][1024]), 128x128 tile ----------------
// EPI=0: scatter bf16 into q/k [B=4][H=16][T=2048][64] and V TRANSPOSED [B][H][64][T=2048].
//        q is stored PRE-SCALED by csc = 1/sqrt(64)*log2(e) (folded out of the attn loop).
// EPI=1: fp32 out [M][1024]
template <int EPI>
__global__ __launch_bounds__(256) void k_gemm(const u16* __restrict__ A,
                                              const u16* __restrict__ B,
                                              void* __restrict__ Cp) {
  const int K = 1024;
  __shared__ __align__(16) u16 As[128 * 32];
  __shared__ __align__(16) u16 Bs[128 * 32];
  int tid = threadIdx.x;
  int lane = tid & 63, wid = tid >> 6;
  int wr = wid >> 1, wc = wid & 1;
  int m0 = blockIdx.y * 128, n0 = blockIdx.x * 128;
  int r = lane & 15, qq = lane >> 4;

  const u16* Ag0 = A + (size_t)(m0 + wid * 32 + (lane >> 2)) * K + (lane & 3) * 8;
  const u16* Bg0 = B + (size_t)(n0 + wid * 32 + (lane >> 2)) * K + (lane & 3) * 8;
  u16* Asl0 = As + (wid * 32) * 32;
  u16* Asl1 = As + (wid * 32 + 16) * 32;
  u16* Bsl0 = Bs + (wid * 32) * 32;
  u16* Bsl1 = Bs + (wid * 32 + 16) * 32;

  f32x4 acc[4][4] = {};

  for (int k0 = 0; k0 < K; k0 += 32) {
    gll16(Ag0 + k0, Asl0);
    gll16(Ag0 + 16 * K + k0, Asl1);
    gll16(Bg0 + k0, Bsl0);
    gll16(Bg0 + 16 * K + k0, Bsl1);
    __syncthreads();
    bf16x8 af[4], bfr[4];
#pragma unroll
    for (int m = 0; m < 4; ++m) af[m] = ld8(&As[(wr * 64 + m * 16 + r) * 32 + qq * 8]);
#pragma unroll
    for (int n = 0; n < 4; ++n) bfr[n] = ld8(&Bs[(wc * 64 + n * 16 + r) * 32 + qq * 8]);
#pragma unroll
    for (int m = 0; m < 4; ++m)
#pragma unroll
      for (int n = 0; n < 4; ++n) acc[m][n] = mfma16(af[m], bfr[n], acc[m][n]);
    __syncthreads();
  }

  if constexpr (EPI == 0) {
    u16* qkv = (u16*)Cp;
#pragma unroll
    for (int m = 0; m < 4; ++m) {
      int gr = m0 + wr * 64 + m * 16 + qq * 4;
      int b = gr >> 11, t0 = gr & 2047;
#pragma unroll
      for (int n = 0; n < 4; ++n) {
        int gc = n0 + wc * 64 + n * 16 + r;
        int which = gc >> 10, rem = gc & 1023;
        int hh = rem >> 6, d = rem & 63;
        if (which == 2) {
          // V^T: [(b*16+hh)*64 + d][2048] ; acc i-index is t (contiguous) -> one 8B store
          u16* dst = qkv + (size_t)2 * 8388608u +
                     ((size_t)((b * 16 + hh) * 64 + d)) * 2048 + t0;
          u32 p0 = pk2(acc[m][n][0], acc[m][n][1]);
          u32 p1 = pk2(acc[m][n][2], acc[m][n][3]);
          *(uint2*)dst = make_uint2(p0, p1);
        } else {
          // q (which==0) pre-scaled by csc; k (which==1) raw
          float sc = (which == 0) ? 0.18033688011112042f : 1.0f;
          u16* dst = qkv + (size_t)which * 8388608u +
                     ((size_t)((b * 16 + hh) * 2048 + t0)) * 64 + d;
#pragma unroll
          for (int i = 0; i < 4; ++i) dst[(size_t)i * 64] = f2b(acc[m][n][i] * sc);
        }
      }
    }
  } else {
    float* out = (float*)Cp;
#pragma unroll
    for (int m = 0; m < 4; ++m) {
      int gr = m0 + wr * 64 + m * 16 + qq * 4;
#pragma unroll
      for (int n = 0; n < 4; ++n) {
        int gc = n0 + wc * 64 + n * 16 + r;
#pragma unroll
        for (int i = 0; i < 4; ++i) out[(size_t)(gr + i) * 1024 + gc] = acc[m][n][i];
      }
    }
  }
}

// ---------------- flash attention v2 (1 wave/WG, swapped QK^T, zero LDS) ----------------
// R7 changes (both attack the per-tile critical path of the longest 32-tile waves,
// which R6 showed is the binding constraint -- the whole grid is resident at t=0):
// 1. __launch_bounds__(64, 2): R6's 124-VGPR allocation (4 waves/SIMD target) forced
//    register reuse across the K/V prefetch -> compiler had to drain loads early,
//    putting L2 latency back on the serial chain. Full overlap needs ~180 VGPRs
//    (s32+acc32+kf32+kf'32+vfr32+qf16+addr). Avg occupancy was only 1.6 waves/SIMD,
//    so the 4->2 wave cap costs ~nothing. (NOT R1's bug: this RAISES the budget.)
// 2. exp2f() -> __builtin_amdgcn_exp2f (raw v_exp_f32): OCML exp2 carries ~6-instr
//    denormal-range fixup; inputs here are always <= 0 and the row max maps to 2^0=1,
//    so the raw instruction is exact where it matters (deep-negative -> 0).
// 3. V^T loads issued BEFORE the QK^T MFMA block (independent of it) for max lead.
__global__ __launch_bounds__(64, 2) void k_attn(const u16* __restrict__ Qm,
                                                const u16* __restrict__ Km,
                                                const u16* __restrict__ VTm,
                                                u16* __restrict__ Y) {
  int bi = blockIdx.x;
  int qt = bi >> 6;  // 0..63, 0 = longest q-tile
  int bh = bi & 63;  // bi%8 = bh%8 -> head pinned to one XCD residue
  int b = bh >> 4, h = bh & 15;
  int q0w = 2016 - qt * 32;  // this wave's first q row
  int lane = threadIdx.x & 63;
  int r = lane & 15, qq = lane >> 4;
  const size_t base = (size_t)bh * (2048 * 64);

  // Q fragments (B-operand): q rows m*16+r, d-slices kc*32+qq*8
  bf16x8 qf[2][2];
#pragma unroll
  for (int m = 0; m < 2; ++m)
#pragma unroll
    for (int kc = 0; kc < 2; ++kc)
      qf[m][kc] = ld8(Qm + base + (size_t)(q0w + m * 16 + r) * 64 + kc * 32 + qq * 8);

  f32x4 acc[2][4] = {};
  float m_run[2] = {-1e30f, -1e30f};
  float l_run[2] = {0.f, 0.f};  // per-lane partial sums over this lane's keys
  int ntw = ((q0w + 31) >> 6) + 1;  // exactly this wave's causal tiles

  // K A-fragment per-lane row offset: row = 8*(r>>2) + (r&3) (+ knt per tile-quarter)
  int ar = 8 * (r >> 2) + (r & 3);
  const u16* Kp = Km + base + (size_t)ar * 64 + qq * 8;    // + (j0+knt)*64 + kc*32
  const u16* Vp = VTm + base + (size_t)r * 2048 + qq * 8;  // + n*16*2048 + j0 + kc*32

  // preload K tile 0 fragments (A-operand, free row assignment)
  bf16x8 kf[4][2];
#pragma unroll
  for (int nt = 0; nt < 4; ++nt) {
    int knt = 32 * (nt >> 1) + 4 * (nt & 1);
#pragma unroll
    for (int kc = 0; kc < 2; ++kc) kf[nt][kc] = ld8(Kp + (size_t)knt * 64 + kc * 32);
  }

  for (int it = 0; it < ntw; ++it) {
    int j0 = it << 6;

    // V^T fragments for THIS tile: issued FIRST (independent of QK^T) -> latency
    // hides under QK^T issue + the whole softmax.
    bf16x8 vfr[4][2];
#pragma unroll
    for (int n = 0; n < 4; ++n)
#pragma unroll
      for (int kc = 0; kc < 2; ++kc)
        vfr[n][kc] = ld8(Vp + (size_t)(n * 16) * 2048 + j0 + kc * 32);

    // S = K . Q^T : lane holds S[key = j0+knt+8*qq+i][q = m*16+r]
    f32x4 s[4][2] = {};
    __builtin_amdgcn_s_setprio(1);
#pragma unroll
    for (int nt = 0; nt < 4; ++nt)
#pragma unroll
      for (int kc = 0; kc < 2; ++kc)
#pragma unroll
        for (int m = 0; m < 2; ++m) s[nt][m] = mfma16(kf[nt][kc], qf[m][kc], s[nt][m]);
    __builtin_amdgcn_s_setprio(0);

    // K fragments for NEXT tile (in flight across softmax+PV and the loop edge)
    if (it + 1 < ntw) {
#pragma unroll
      for (int nt = 0; nt < 4; ++nt) {
        int knt = 32 * (nt >> 1) + 4 * (nt & 1);
#pragma unroll
        for (int kc = 0; kc < 2; ++kc)
          kf[nt][kc] = ld8(Kp + (size_t)(j0 + 64 + knt) * 64 + kc * 32);
      }
    }

    // causal mask, diagonal tiles only (wave-uniform branch); q pre-scaled -> no scale op
    bool nm = (j0 + 63 > q0w);
    if (nm) {
#pragma unroll
      for (int nt = 0; nt < 4; ++nt) {
        int kb = j0 + 32 * (nt >> 1) + 4 * (nt & 1) + 8 * qq;
#pragma unroll
        for (int m = 0; m < 2; ++m) {
          int qg = q0w + m * 16 + r;
#pragma unroll
          for (int i = 0; i < 4; ++i)
            s[nt][m][i] = (kb + i <= qg) ? s[nt][m][i] : -1e30f;
        }
      }
    }

    // row max: fold 16 in-lane, then 2 shuffle rounds across qq groups
    float tm[2];
#pragma unroll
    for (int m = 0; m < 2; ++m) {
      float t0 = fmaxf(fmaxf(s[0][m][0], s[0][m][1]), fmaxf(s[0][m][2], s[0][m][3]));
      float t1 = fmaxf(fmaxf(s[1][m][0], s[1][m][1]), fmaxf(s[1][m][2], s[1][m][3]));
      float t2 = fmaxf(fmaxf(s[2][m][0], s[2][m][1]), fmaxf(s[2][m][2], s[2][m][3]));
      float t3 = fmaxf(fmaxf(s[3][m][0], s[3][m][1]), fmaxf(s[3][m][2], s[3][m][3]));
      float t = fmaxf(fmaxf(t0, t1), fmaxf(t2, t3));
      t = fmaxf(t, __shfl_xor(t, 16));
      t = fmaxf(t, __shfl_xor(t, 32));
      tm[m] = t;
    }

    // rescale only if the running max grew (corr would be exactly 1 otherwise)
    int grow = (tm[0] > m_run[0]) | (tm[1] > m_run[1]);
    if (__any(grow)) {
#pragma unroll
      for (int m = 0; m < 2; ++m) {
        float mn = fmaxf(m_run[m], tm[m]);
        float corr = __builtin_amdgcn_exp2f(m_run[m] - mn);
        m_run[m] = mn;
        l_run[m] *= corr;
        // acc layout has q = m*16 + qq*4 + i -> pull corr from lane qq*4+i
#pragma unroll
        for (int i = 0; i < 4; ++i) {
          float c = __shfl(corr, qq * 4 + i);
#pragma unroll
          for (int n = 0; n < 4; ++n) acc[m][n][i] *= c;
        }
      }
    }

    // P = exp2(S - m) via raw v_exp_f32; per-lane partial row sums
#pragma unroll
    for (int m = 0; m < 2; ++m) {
      float ls = 0.f;
#pragma unroll
      for (int nt = 0; nt < 4; ++nt)
#pragma unroll
        for (int i = 0; i < 4; ++i) {
          float e = __builtin_amdgcn_exp2f(s[nt][m][i] - m_run[m]);
          s[nt][m][i] = e;
          ls += e;
        }
      l_run[m] += ls;
    }

    // PV: P packs straight into A-fragments in-lane (8 cvt_pk per m), no LDS
    __builtin_amdgcn_s_setprio(1);
#pragma unroll
    for (int m = 0; m < 2; ++m) {
      bf16x8 pa0 = pack8(s[0][m], s[1][m]);  // keys qq*8+0..7
      bf16x8 pa1 = pack8(s[2][m], s[3][m]);  // keys 32+qq*8+0..7
#pragma unroll
      for (int n = 0; n < 4; ++n) acc[m][n] = mfma16(pa0, vfr[n][0], acc[m][n]);
#pragma unroll
      for (int n = 0; n < 4; ++n) acc[m][n] = mfma16(pa1, vfr[n][1], acc[m][n]);
    }
    __builtin_amdgcn_s_setprio(0);
  }

  // epilogue: sum partials across qq groups, invert, redistribute to acc layout
  float li[2][4];
#pragma unroll
  for (int m = 0; m < 2; ++m) {
    float l = l_run[m];
    l += __shfl_xor(l, 16);
    l += __shfl_xor(l, 32);
    float inv = 1.0f / l;
#pragma unroll
    for (int i = 0; i < 4; ++i) li[m][i] = __shfl(inv, qq * 4 + i);
  }
#pragma unroll
  for (int m = 0; m < 2; ++m)
#pragma unroll
    for (int n = 0; n < 4; ++n)
#pragma unroll
      for (int i = 0; i < 4; ++i)
        Y[((size_t)(b * 2048 + q0w + m * 16 + qq * 4 + i)) * 1024 + h * 64 + n * 16 + r] =
            f2b(acc[m][n][i] * li[m][i]);
}

// ---------------- launch ----------------
extern "C" void kernel_launch(void* const* d_in, const int* in_sizes, int n_in,
                              void* d_out, int out_size, void* d_ws, size_t ws_size,
                              hipStream_t stream) {
  const float* x = (const float*)d_in[0];       // [4,2048,1024]
  const float* w_attn = (const float*)d_in[1];  // [1024,3072]
  const float* w_o = (const float*)d_in[2];     // [1024,1024]
  float* out = (float*)d_out;                   // [4,2048,1024]

  char* ws = (char*)d_ws;
  u16* xb = (u16*)(ws + 0);                    // [8192][1024]        16,777,216 B
  u16* watT = (u16*)(ws + 16777216);           // [3072][1024]         6,291,456 B
  u16* woT = (u16*)(ws + 23068672);            // [1024][1024]         2,097,152 B
  u16* qb = (u16*)(ws + 25165824);             // q [4][16][2048][64] 16,777,216 B
  u16* kb = (u16*)(ws + 41943040);             // k                   16,777,216 B
  u16* vb = (u16*)(ws + 58720256);             // V^T [4][16][64][2048] 16,777,216 B
  u16* yb = (u16*)(ws + 75497472);             // y [4][2048][1024]   16,777,216 B

  k_cvt<<<2048, 256, 0, stream>>>(x, xb, 8192 * 1024 / 4);
  k_tr<<<dim3(3072 / 32, 1024 / 32), dim3(32, 8), 0, stream>>>(w_attn, watT, 1024, 3072);
  k_tr<<<dim3(1024 / 32, 1024 / 32), dim3(32, 8), 0, stream>>>(w_o, woT, 1024, 1024);
  k_gemm<0><<<dim3(24, 64), 256, 0, stream>>>(xb, watT, (void*)qb);
  k_attn<<<dim3(4096), 64, 0, stream>>>(qb, kb, vb, yb);
  k_gemm<1><<<dim3(8, 64), 256, 0, stream>>>(yb, woT, (void*)out);
}

// Round 8
// 229.917 us; speedup vs baseline: 1.5383x; 1.1107x over previous
//
#include <hip/hip_runtime.h>

typedef unsigned short u16;
typedef unsigned int u32;
typedef __attribute__((ext_vector_type(8))) __bf16 bf16x8;
typedef __attribute__((ext_vector_type(4))) float f32x4;
typedef __attribute__((ext_vector_type(8))) unsigned short u16x8;
typedef __attribute__((ext_vector_type(4))) unsigned int u32x4;

typedef const __attribute__((address_space(1))) u32 gu32;
typedef __attribute__((address_space(3))) u32 lu32;

// fp32 -> bf16 round-to-nearest-even
__device__ __forceinline__ u16 f2b(float f) {
  u32 u = __builtin_bit_cast(u32, f);
  u32 r = u + 0x7fffu + ((u >> 16) & 1u);
  return (u16)(r >> 16);
}

// packed fp32 pair -> bf16 pair (RNE), lo in [15:0]
__device__ __forceinline__ u32 pk2(float lo, float hi) {
  u32 d;
  asm("v_cvt_pk_bf16_f32 %0, %1, %2" : "=v"(d) : "v"(lo), "v"(hi));
  return d;
}

// two f32x4 -> one bf16x8 (elements 0..3 from a, 4..7 from b)
__device__ __forceinline__ bf16x8 pack8(f32x4 a, f32x4 b) {
  u32x4 u;
  u[0] = pk2(a[0], a[1]);
  u[1] = pk2(a[2], a[3]);
  u[2] = pk2(b[0], b[1]);
  u[3] = pk2(b[2], b[3]);
  return __builtin_bit_cast(bf16x8, u);
}

__device__ __forceinline__ bf16x8 ld8(const u16* p) {
  return __builtin_bit_cast(bf16x8, *(const u16x8*)p);
}

__device__ __forceinline__ void gll16(const void* g, void* l) {
  __builtin_amdgcn_global_load_lds((gu32*)g, (lu32*)l, 16, 0, 0);
}

__device__ __forceinline__ f32x4 mfma16(bf16x8 a, bf16x8 b, f32x4 c) {
  return __builtin_amdgcn_mfma_f32_16x16x32_bf16(a, b, c, 0, 0, 0);
}

// ---------------- fp32 -> bf16 elementwise ----------------
__global__ void k_cvt(const float* __restrict__ in, u16* __restrict__ out, int n4) {
  int i = blockIdx.x * blockDim.x + threadIdx.x;
  int stride = gridDim.x * blockDim.x;
  for (int idx = i; idx < n4; idx += stride) {
    float4 v = ((const float4*)in)[idx];
    u32 lo = (u32)f2b(v.x) | ((u32)f2b(v.y) << 16);
    u32 hi = (u32)f2b(v.z) | ((u32)f2b(v.w) << 16);
    ((uint2*)out)[idx] = make_uint2(lo, hi);
  }
}

// ---------------- transpose+convert: in[R][C] f32 -> out[C][R] bf16 ----------------
__global__ void k_tr(const float* __restrict__ in, u16* __restrict__ out, int R, int C) {
  __shared__ u16 tile[32][33];
  int bx = blockIdx.x * 32;  // along C
  int by = blockIdx.y * 32;  // along R
  int tx = threadIdx.x, ty = threadIdx.y;  // (32, 8)
#pragma unroll
  for (int i = 0; i < 32; i += 8)
    tile[ty + i][tx] = f2b(in[(size_t)(by + ty + i) * C + bx + tx]);
  __syncthreads();
#pragma unroll
  for (int i = 0; i < 32; i += 8)
    out[(size_t)(bx + ty + i) * R + by + tx] = tile[tx][ty + i];
}

// ---------------- GEMM: A[M][1024] * B^T (B given as [N][1024]), 128x128 tile ----------------
// EPI=0: scatter bf16 into q/k [B=4][H=16][T=2048][64] and V TRANSPOSED [B][H][64][T=2048].
//        q is stored PRE-SCALED by csc = 1/sqrt(64)*log2(e) (folded out of the attn loop).
// EPI=1: fp32 out [M][1024]
template <int EPI>
__global__ __launch_bounds__(256) void k_gemm(const u16* __restrict__ A,
                                              const u16* __restrict__ B,
                                              void* __restrict__ Cp) {
  const int K = 1024;
  __shared__ __align__(16) u16 As[128 * 32];
  __shared__ __align__(16) u16 Bs[128 * 32];
  int tid = threadIdx.x;
  int lane = tid & 63, wid = tid >> 6;
  int wr = wid >> 1, wc = wid & 1;
  int m0 = blockIdx.y * 128, n0 = blockIdx.x * 128;
  int r = lane & 15, qq = lane >> 4;

  const u16* Ag0 = A + (size_t)(m0 + wid * 32 + (lane >> 2)) * K + (lane & 3) * 8;
  const u16* Bg0 = B + (size_t)(n0 + wid * 32 + (lane >> 2)) * K + (lane & 3) * 8;
  u16* Asl0 = As + (wid * 32) * 32;
  u16* Asl1 = As + (wid * 32 + 16) * 32;
  u16* Bsl0 = Bs + (wid * 32) * 32;
  u16* Bsl1 = Bs + (wid * 32 + 16) * 32;

  f32x4 acc[4][4] = {};

  for (int k0 = 0; k0 < K; k0 += 32) {
    gll16(Ag0 + k0, Asl0);
    gll16(Ag0 + 16 * K + k0, Asl1);
    gll16(Bg0 + k0, Bsl0);
    gll16(Bg0 + 16 * K + k0, Bsl1);
    __syncthreads();
    bf16x8 af[4], bfr[4];
#pragma unroll
    for (int m = 0; m < 4; ++m) af[m] = ld8(&As[(wr * 64 + m * 16 + r) * 32 + qq * 8]);
#pragma unroll
    for (int n = 0; n < 4; ++n) bfr[n] = ld8(&Bs[(wc * 64 + n * 16 + r) * 32 + qq * 8]);
#pragma unroll
    for (int m = 0; m < 4; ++m)
#pragma unroll
      for (int n = 0; n < 4; ++n) acc[m][n] = mfma16(af[m], bfr[n], acc[m][n]);
    __syncthreads();
  }

  if constexpr (EPI == 0) {
    u16* qkv = (u16*)Cp;
#pragma unroll
    for (int m = 0; m < 4; ++m) {
      int gr = m0 + wr * 64 + m * 16 + qq * 4;
      int b = gr >> 11, t0 = gr & 2047;
#pragma unroll
      for (int n = 0; n < 4; ++n) {
        int gc = n0 + wc * 64 + n * 16 + r;
        int which = gc >> 10, rem = gc & 1023;
        int hh = rem >> 6, d = rem & 63;
        if (which == 2) {
          // V^T: [(b*16+hh)*64 + d][2048] ; acc i-index is t (contiguous) -> one 8B store
          u16* dst = qkv + (size_t)2 * 8388608u +
                     ((size_t)((b * 16 + hh) * 64 + d)) * 2048 + t0;
          u32 p0 = pk2(acc[m][n][0], acc[m][n][1]);
          u32 p1 = pk2(acc[m][n][2], acc[m][n][3]);
          *(uint2*)dst = make_uint2(p0, p1);
        } else {
          // q (which==0) pre-scaled by csc; k (which==1) raw
          float sc = (which == 0) ? 0.18033688011112042f : 1.0f;
          u16* dst = qkv + (size_t)which * 8388608u +
                     ((size_t)((b * 16 + hh) * 2048 + t0)) * 64 + d;
#pragma unroll
          for (int i = 0; i < 4; ++i) dst[(size_t)i * 64] = f2b(acc[m][n][i] * sc);
        }
      }
    }
  } else {
    float* out = (float*)Cp;
#pragma unroll
    for (int m = 0; m < 4; ++m) {
      int gr = m0 + wr * 64 + m * 16 + qq * 4;
#pragma unroll
      for (int n = 0; n < 4; ++n) {
        int gc = n0 + wc * 64 + n * 16 + r;
#pragma unroll
        for (int i = 0; i < 4; ++i) out[(size_t)(gr + i) * 1024 + gc] = acc[m][n][i];
      }
    }
  }
}

// ---------------- flash attention v2 (1 wave/WG, QBLK=64, swapped QK^T, zero LDS) ----------------
// R8: QBLK 32 -> 64 q-rows per wave (m: 2 -> 4). R7's wave-seconds arithmetic showed a
// UNIFORM ~8k-cycle stall per tile per wave (56 us avg wave lifetime / 16.5 tiles) with
// all pipes <21% busy -- a fixed per-iteration latency cost (load-batch waits + softmax
// dependency chain) that occupancy (avg 1.6 waves/SIMD) cannot hide. Doubling the work
// per iteration amortizes that fixed cost: QK^T/PV MFMA per tile 32->64, exp2 32->64,
// while K/V LOADS PER TILE ARE UNCHANGED (16). Grid halves to 2048 waves = exactly the
// 2-waves/SIMD residency cap from the ~240-VGPR allocation (__launch_bounds__(64,2)
// caps at 256). This also forces the compiler to keep the load pipeline register-
// resident (R7: at low liveness it chose to serialize loads instead of using regs).
// q0w is now a multiple of 64 -> exactly one diagonal (masked) tile per wave.
// Spill tripwire: WRITE_SIZE must stay ~16.4 MB.
__global__ __launch_bounds__(64, 2) void k_attn(const u16* __restrict__ Qm,
                                                const u16* __restrict__ Km,
                                                const u16* __restrict__ VTm,
                                                u16* __restrict__ Y) {
  int bi = blockIdx.x;
  int qt = bi >> 6;  // 0..31, 0 = longest q-tile
  int bh = bi & 63;  // bi%8 = bh%8 -> head pinned to one XCD residue
  int b = bh >> 4, h = bh & 15;
  int q0w = 1984 - qt * 64;  // this wave's first q row (multiple of 64)
  int lane = threadIdx.x & 63;
  int r = lane & 15, qq = lane >> 4;
  const size_t base = (size_t)bh * (2048 * 64);

  // Q fragments (B-operand): q rows m*16+r, d-slices kc*32+qq*8
  bf16x8 qf[4][2];
#pragma unroll
  for (int m = 0; m < 4; ++m)
#pragma unroll
    for (int kc = 0; kc < 2; ++kc)
      qf[m][kc] = ld8(Qm + base + (size_t)(q0w + m * 16 + r) * 64 + kc * 32 + qq * 8);

  f32x4 acc[4][4] = {};
  float m_run[4] = {-1e30f, -1e30f, -1e30f, -1e30f};
  float l_run[4] = {0.f, 0.f, 0.f, 0.f};  // per-lane partial sums over this lane's keys
  int ntw = (q0w >> 6) + 1;  // exactly this wave's causal tiles (q0w % 64 == 0)

  // K A-fragment per-lane row offset: row = 8*(r>>2) + (r&3) (+ knt per tile-quarter)
  int ar = 8 * (r >> 2) + (r & 3);
  const u16* Kp = Km + base + (size_t)ar * 64 + qq * 8;    // + (j0+knt)*64 + kc*32
  const u16* Vp = VTm + base + (size_t)r * 2048 + qq * 8;  // + n*16*2048 + j0 + kc*32

  // preload K tile 0 fragments (A-operand, free row assignment)
  bf16x8 kf[4][2];
#pragma unroll
  for (int nt = 0; nt < 4; ++nt) {
    int knt = 32 * (nt >> 1) + 4 * (nt & 1);
#pragma unroll
    for (int kc = 0; kc < 2; ++kc) kf[nt][kc] = ld8(Kp + (size_t)knt * 64 + kc * 32);
  }

  for (int it = 0; it < ntw; ++it) {
    int j0 = it << 6;

    // V^T fragments for THIS tile: issued FIRST (independent of QK^T) -> latency
    // hides under QK^T issue + the whole softmax.
    bf16x8 vfr[4][2];
#pragma unroll
    for (int n = 0; n < 4; ++n)
#pragma unroll
      for (int kc = 0; kc < 2; ++kc)
        vfr[n][kc] = ld8(Vp + (size_t)(n * 16) * 2048 + j0 + kc * 32);

    // S = K . Q^T : lane holds S[key = j0+knt+8*qq+i][q = m*16+r]
    f32x4 s[4][4] = {};
    __builtin_amdgcn_s_setprio(1);
#pragma unroll
    for (int nt = 0; nt < 4; ++nt)
#pragma unroll
      for (int kc = 0; kc < 2; ++kc)
#pragma unroll
        for (int m = 0; m < 4; ++m) s[nt][m] = mfma16(kf[nt][kc], qf[m][kc], s[nt][m]);
    __builtin_amdgcn_s_setprio(0);

    // K fragments for NEXT tile (in flight across softmax+PV and the loop edge)
    if (it + 1 < ntw) {
#pragma unroll
      for (int nt = 0; nt < 4; ++nt) {
        int knt = 32 * (nt >> 1) + 4 * (nt & 1);
#pragma unroll
        for (int kc = 0; kc < 2; ++kc)
          kf[nt][kc] = ld8(Kp + (size_t)(j0 + 64 + knt) * 64 + kc * 32);
      }
    }

    // causal mask: only the single diagonal tile (j0 == q0w); q pre-scaled -> no scale op
    bool nm = (j0 + 63 > q0w);
    if (nm) {
#pragma unroll
      for (int nt = 0; nt < 4; ++nt) {
        int kb = j0 + 32 * (nt >> 1) + 4 * (nt & 1) + 8 * qq;
#pragma unroll
        for (int m = 0; m < 4; ++m) {
          int qg = q0w + m * 16 + r;
#pragma unroll
          for (int i = 0; i < 4; ++i)
            s[nt][m][i] = (kb + i <= qg) ? s[nt][m][i] : -1e30f;
        }
      }
    }

    // row max: fold 16 in-lane, then 2 shuffle rounds across qq groups
    float tm[4];
#pragma unroll
    for (int m = 0; m < 4; ++m) {
      float t0 = fmaxf(fmaxf(s[0][m][0], s[0][m][1]), fmaxf(s[0][m][2], s[0][m][3]));
      float t1 = fmaxf(fmaxf(s[1][m][0], s[1][m][1]), fmaxf(s[1][m][2], s[1][m][3]));
      float t2 = fmaxf(fmaxf(s[2][m][0], s[2][m][1]), fmaxf(s[2][m][2], s[2][m][3]));
      float t3 = fmaxf(fmaxf(s[3][m][0], s[3][m][1]), fmaxf(s[3][m][2], s[3][m][3]));
      float t = fmaxf(fmaxf(t0, t1), fmaxf(t2, t3));
      t = fmaxf(t, __shfl_xor(t, 16));
      t = fmaxf(t, __shfl_xor(t, 32));
      tm[m] = t;
    }

    // rescale only if the running max grew (corr would be exactly 1 otherwise)
    int grow = (tm[0] > m_run[0]) | (tm[1] > m_run[1]) | (tm[2] > m_run[2]) |
               (tm[3] > m_run[3]);
    if (__any(grow)) {
#pragma unroll
      for (int m = 0; m < 4; ++m) {
        float mn = fmaxf(m_run[m], tm[m]);
        float corr = __builtin_amdgcn_exp2f(m_run[m] - mn);
        m_run[m] = mn;
        l_run[m] *= corr;
        // acc layout has q = m*16 + qq*4 + i -> pull corr from lane qq*4+i
#pragma unroll
        for (int i = 0; i < 4; ++i) {
          float c = __shfl(corr, qq * 4 + i);
#pragma unroll
          for (int n = 0; n < 4; ++n) acc[m][n][i] *= c;
        }
      }
    }

    // P = exp2(S - m) via raw v_exp_f32; per-lane partial row sums
#pragma unroll
    for (int m = 0; m < 4; ++m) {
      float ls = 0.f;
#pragma unroll
      for (int nt = 0; nt < 4; ++nt)
#pragma unroll
        for (int i = 0; i < 4; ++i) {
          float e = __builtin_amdgcn_exp2f(s[nt][m][i] - m_run[m]);
          s[nt][m][i] = e;
          ls += e;
        }
      l_run[m] += ls;
    }

    // PV: P packs straight into A-fragments in-lane (8 cvt_pk per m), no LDS
    __builtin_amdgcn_s_setprio(1);
#pragma unroll
    for (int m = 0; m < 4; ++m) {
      bf16x8 pa0 = pack8(s[0][m], s[1][m]);  // keys qq*8+0..7
      bf16x8 pa1 = pack8(s[2][m], s[3][m]);  // keys 32+qq*8+0..7
#pragma unroll
      for (int n = 0; n < 4; ++n) acc[m][n] = mfma16(pa0, vfr[n][0], acc[m][n]);
#pragma unroll
      for (int n = 0; n < 4; ++n) acc[m][n] = mfma16(pa1, vfr[n][1], acc[m][n]);
    }
    __builtin_amdgcn_s_setprio(0);
  }

  // epilogue: sum partials across qq groups, invert, redistribute to acc layout
  float li[4][4];
#pragma unroll
  for (int m = 0; m < 4; ++m) {
    float l = l_run[m];
    l += __shfl_xor(l, 16);
    l += __shfl_xor(l, 32);
    float inv = 1.0f / l;
#pragma unroll
    for (int i = 0; i < 4; ++i) li[m][i] = __shfl(inv, qq * 4 + i);
  }
#pragma unroll
  for (int m = 0; m < 4; ++m)
#pragma unroll
    for (int n = 0; n < 4; ++n)
#pragma unroll
      for (int i = 0; i < 4; ++i)
        Y[((size_t)(b * 2048 + q0w + m * 16 + qq * 4 + i)) * 1024 + h * 64 + n * 16 + r] =
            f2b(acc[m][n][i] * li[m][i]);
}

// ---------------- launch ----------------
extern "C" void kernel_launch(void* const* d_in, const int* in_sizes, int n_in,
                              void* d_out, int out_size, void* d_ws, size_t ws_size,
                              hipStream_t stream) {
  const float* x = (const float*)d_in[0];       // [4,2048,1024]
  const float* w_attn = (const float*)d_in[1];  // [1024,3072]
  const float* w_o = (const float*)d_in[2];     // [1024,1024]
  float* out = (float*)d_out;                   // [4,2048,1024]

  char* ws = (char*)d_ws;
  u16* xb = (u16*)(ws + 0);                    // [8192][1024]        16,777,216 B
  u16* watT = (u16*)(ws + 16777216);           // [3072][1024]         6,291,456 B
  u16* woT = (u16*)(ws + 23068672);            // [1024][1024]         2,097,152 B
  u16* qb = (u16*)(ws + 25165824);             // q [4][16][2048][64] 16,777,216 B
  u16* kb = (u16*)(ws + 41943040);             // k                   16,777,216 B
  u16* vb = (u16*)(ws + 58720256);             // V^T [4][16][64][2048] 16,777,216 B
  u16* yb = (u16*)(ws + 75497472);             // y [4][2048][1024]   16,777,216 B

  k_cvt<<<2048, 256, 0, stream>>>(x, xb, 8192 * 1024 / 4);
  k_tr<<<dim3(3072 / 32, 1024 / 32), dim3(32, 8), 0, stream>>>(w_attn, watT, 1024, 3072);
  k_tr<<<dim3(1024 / 32, 1024 / 32), dim3(32, 8), 0, stream>>>(w_o, woT, 1024, 1024);
  k_gemm<0><<<dim3(24, 64), 256, 0, stream>>>(xb, watT, (void*)qb);
  k_attn<<<dim3(2048), 64, 0, stream>>>(qb, kb, vb, yb);
  k_gemm<1><<<dim3(8, 64), 256, 0, stream>>>(yb, woT, (void*)out);
}

// Round 9
// 212.481 us; speedup vs baseline: 1.6645x; 1.0821x over previous
//
#include <hip/hip_runtime.h>

typedef unsigned short u16;
typedef unsigned int u32;
typedef __attribute__((ext_vector_type(8))) __bf16 bf16x8;
typedef __attribute__((ext_vector_type(4))) float f32x4;
typedef __attribute__((ext_vector_type(8))) unsigned short u16x8;
typedef __attribute__((ext_vector_type(4))) unsigned int u32x4;

typedef const __attribute__((address_space(1))) u32 gu32;
typedef __attribute__((address_space(3))) u32 lu32;

// fp32 -> bf16 round-to-nearest-even
__device__ __forceinline__ u16 f2b(float f) {
  u32 u = __builtin_bit_cast(u32, f);
  u32 r = u + 0x7fffu + ((u >> 16) & 1u);
  return (u16)(r >> 16);
}

// packed fp32 pair -> bf16 pair (RNE), lo in [15:0]
__device__ __forceinline__ u32 pk2(float lo, float hi) {
  u32 d;
  asm("v_cvt_pk_bf16_f32 %0, %1, %2" : "=v"(d) : "v"(lo), "v"(hi));
  return d;
}

// two f32x4 -> one bf16x8 (elements 0..3 from a, 4..7 from b)
__device__ __forceinline__ bf16x8 pack8(f32x4 a, f32x4 b) {
  u32x4 u;
  u[0] = pk2(a[0], a[1]);
  u[1] = pk2(a[2], a[3]);
  u[2] = pk2(b[0], b[1]);
  u[3] = pk2(b[2], b[3]);
  return __builtin_bit_cast(bf16x8, u);
}

__device__ __forceinline__ bf16x8 ld8(const u16* p) {
  return __builtin_bit_cast(bf16x8, *(const u16x8*)p);
}

__device__ __forceinline__ void gll16(const void* g, void* l) {
  __builtin_amdgcn_global_load_lds((gu32*)g, (lu32*)l, 16, 0, 0);
}

__device__ __forceinline__ f32x4 mfma16(bf16x8 a, bf16x8 b, f32x4 c) {
  return __builtin_amdgcn_mfma_f32_16x16x32_bf16(a, b, c, 0, 0, 0);
}

// ---------------- fp32 -> bf16 elementwise ----------------
__global__ void k_cvt(const float* __restrict__ in, u16* __restrict__ out, int n4) {
  int i = blockIdx.x * blockDim.x + threadIdx.x;
  int stride = gridDim.x * blockDim.x;
  for (int idx = i; idx < n4; idx += stride) {
    float4 v = ((const float4*)in)[idx];
    u32 lo = (u32)f2b(v.x) | ((u32)f2b(v.y) << 16);
    u32 hi = (u32)f2b(v.z) | ((u32)f2b(v.w) << 16);
    ((uint2*)out)[idx] = make_uint2(lo, hi);
  }
}

// ---------------- transpose+convert: in[R][C] f32 -> out[C][R] bf16 ----------------
__global__ void k_tr(const float* __restrict__ in, u16* __restrict__ out, int R, int C) {
  __shared__ u16 tile[32][33];
  int bx = blockIdx.x * 32;  // along C
  int by = blockIdx.y * 32;  // along R
  int tx = threadIdx.x, ty = threadIdx.y;  // (32, 8)
#pragma unroll
  for (int i = 0; i < 32; i += 8)
    tile[ty + i][tx] = f2b(in[(size_t)(by + ty + i) * C + bx + tx]);
  __syncthreads();
#pragma unroll
  for (int i = 0; i < 32; i += 8)
    out[(size_t)(bx + ty + i) * R + by + tx] = tile[tx][ty + i];
}

// ---------------- GEMM: A[M][1024] * B^T (B given as [N][1024]), 128x128 tile ----------------
// EPI=0: scatter bf16 into q/k [B=4][H=16][T=2048][64] and V TRANSPOSED [B][H][64][T=2048].
//        q is stored PRE-SCALED by csc = 1/sqrt(64)*log2(e) (folded out of the attn loop).
// EPI=1: fp32 out [M][1024]
template <int EPI>
__global__ __launch_bounds__(256) void k_gemm(const u16* __restrict__ A,
                                              const u16* __restrict__ B,
                                              void* __restrict__ Cp) {
  const int K = 1024;
  __shared__ __align__(16) u16 As[128 * 32];
  __shared__ __align__(16) u16 Bs[128 * 32];
  int tid = threadIdx.x;
  int lane = tid & 63, wid = tid >> 6;
  int wr = wid >> 1, wc = wid & 1;
  int m0 = blockIdx.y * 128, n0 = blockIdx.x * 128;
  int r = lane & 15, qq = lane >> 4;

  const u16* Ag0 = A + (size_t)(m0 + wid * 32 + (lane >> 2)) * K + (lane & 3) * 8;
  const u16* Bg0 = B + (size_t)(n0 + wid * 32 + (lane >> 2)) * K + (lane & 3) * 8;
  u16* Asl0 = As + (wid * 32) * 32;
  u16* Asl1 = As + (wid * 32 + 16) * 32;
  u16* Bsl0 = Bs + (wid * 32) * 32;
  u16* Bsl1 = Bs + (wid * 32 + 16) * 32;

  f32x4 acc[4][4] = {};

  for (int k0 = 0; k0 < K; k0 += 32) {
    gll16(Ag0 + k0, Asl0);
    gll16(Ag0 + 16 * K + k0, Asl1);
    gll16(Bg0 + k0, Bsl0);
    gll16(Bg0 + 16 * K + k0, Bsl1);
    __syncthreads();
    bf16x8 af[4], bfr[4];
#pragma unroll
    for (int m = 0; m < 4; ++m) af[m] = ld8(&As[(wr * 64 + m * 16 + r) * 32 + qq * 8]);
#pragma unroll
    for (int n = 0; n < 4; ++n) bfr[n] = ld8(&Bs[(wc * 64 + n * 16 + r) * 32 + qq * 8]);
#pragma unroll
    for (int m = 0; m < 4; ++m)
#pragma unroll
      for (int n = 0; n < 4; ++n) acc[m][n] = mfma16(af[m], bfr[n], acc[m][n]);
    __syncthreads();
  }

  if constexpr (EPI == 0) {
    u16* qkv = (u16*)Cp;
#pragma unroll
    for (int m = 0; m < 4; ++m) {
      int gr = m0 + wr * 64 + m * 16 + qq * 4;
      int b = gr >> 11, t0 = gr & 2047;
#pragma unroll
      for (int n = 0; n < 4; ++n) {
        int gc = n0 + wc * 64 + n * 16 + r;
        int which = gc >> 10, rem = gc & 1023;
        int hh = rem >> 6, d = rem & 63;
        if (which == 2) {
          // V^T: [(b*16+hh)*64 + d][2048] ; acc i-index is t (contiguous) -> one 8B store
          u16* dst = qkv + (size_t)2 * 8388608u +
                     ((size_t)((b * 16 + hh) * 64 + d)) * 2048 + t0;
          u32 p0 = pk2(acc[m][n][0], acc[m][n][1]);
          u32 p1 = pk2(acc[m][n][2], acc[m][n][3]);
          *(uint2*)dst = make_uint2(p0, p1);
        } else {
          // q (which==0) pre-scaled by csc; k (which==1) raw
          float sc = (which == 0) ? 0.18033688011112042f : 1.0f;
          u16* dst = qkv + (size_t)which * 8388608u +
                     ((size_t)((b * 16 + hh) * 2048 + t0)) * 64 + d;
#pragma unroll
          for (int i = 0; i < 4; ++i) dst[(size_t)i * 64] = f2b(acc[m][n][i] * sc);
        }
      }
    }
  } else {
    float* out = (float*)Cp;
#pragma unroll
    for (int m = 0; m < 4; ++m) {
      int gr = m0 + wr * 64 + m * 16 + qq * 4;
#pragma unroll
      for (int n = 0; n < 4; ++n) {
        int gc = n0 + wc * 64 + n * 16 + r;
#pragma unroll
        for (int i = 0; i < 4; ++i) out[(size_t)(gr + i) * 1024 + gc] = acc[m][n][i];
      }
    }
  }
}

// ---------------- flash attention v2 (split-KV x2 per WG, QBLK=64, swapped QK^T) ----------------
// R9: R8 showed dispatch time == (max 32 tiles/wave) x (~3.45us/tile, latency-stalled).
// Split the KV range: 2 waves per workgroup, SAME q-tile, wave w takes KV tiles
// it = w, w+2, w+4, ... (<= 16 each). Each wave runs the identical R8 body with its
// own online (m, l, acc); at the end wave 1 stores unnormalized acc+m+l to LDS and
// wave 0 does the exact flash merge (O = OA*e^{mA-m} + OB*e^{mB-m}, / merged l) and
// writes Y. No global partials, no combine kernel. Critical path halves (32 -> 16
// tiles) and residency doubles (4096 waves = 16/CU = 4/SIMD at t=0; VGPR 128, LDS
// 18KB x 8 WG = 144KB <= 160KB). ntw==1 edge: wave 1 runs 0 tiles, stores m=-1e30,
// l=0 -> merge factor exp2(-1e30-m)=0 exactly.
// Spill tripwire: WRITE_SIZE (R8: 25.6MB incl. ~9MB scratch; waves x2 -> watch).
__global__ __launch_bounds__(128, 2) void k_attn(const u16* __restrict__ Qm,
                                                 const u16* __restrict__ Km,
                                                 const u16* __restrict__ VTm,
                                                 u16* __restrict__ Y) {
  int bi = blockIdx.x;
  int qt = bi >> 6;  // 0..31, 0 = longest q-tile
  int bh = bi & 63;  // bi%8 = bh%8 -> head pinned to one XCD residue
  int b = bh >> 4, h = bh & 15;
  int q0w = 1984 - qt * 64;  // this WG's first q row (multiple of 64)
  int tid = threadIdx.x;
  int lane = tid & 63, w = tid >> 6;  // w = 0,1: KV-split half
  int r = lane & 15, qq = lane >> 4;
  const size_t base = (size_t)bh * (2048 * 64);

  // merge staging (wave1 -> wave0)
  __shared__ __align__(16) float accB[4][4][64][4];  // 16 KB
  __shared__ float mlB[2][4][64];                    //  2 KB

  // Q fragments (B-operand): q rows m*16+r, d-slices kc*32+qq*8
  bf16x8 qf[4][2];
#pragma unroll
  for (int m = 0; m < 4; ++m)
#pragma unroll
    for (int kc = 0; kc < 2; ++kc)
      qf[m][kc] = ld8(Qm + base + (size_t)(q0w + m * 16 + r) * 64 + kc * 32 + qq * 8);

  f32x4 acc[4][4] = {};
  float m_run[4] = {-1e30f, -1e30f, -1e30f, -1e30f};
  float l_run[4] = {0.f, 0.f, 0.f, 0.f};  // per-lane partial sums over this lane's keys
  int ntw = (q0w >> 6) + 1;  // causal tiles for this q-tile (q0w % 64 == 0)

  // K A-fragment per-lane row offset: row = 8*(r>>2) + (r&3) (+ knt per tile-quarter)
  int ar = 8 * (r >> 2) + (r & 3);
  const u16* Kp = Km + base + (size_t)ar * 64 + qq * 8;    // + (j0+knt)*64 + kc*32
  const u16* Vp = VTm + base + (size_t)r * 2048 + qq * 8;  // + n*16*2048 + j0 + kc*32

  // preload K fragments for this wave's first tile (it = w)
  bf16x8 kf[4][2];
#pragma unroll
  for (int nt = 0; nt < 4; ++nt) {
    int knt = 32 * (nt >> 1) + 4 * (nt & 1);
#pragma unroll
    for (int kc = 0; kc < 2; ++kc)
      kf[nt][kc] = ld8(Kp + (size_t)(w * 64 + knt) * 64 + kc * 32);
  }

  for (int it = w; it < ntw; it += 2) {
    int j0 = it << 6;

    // V^T fragments for THIS tile: issued FIRST (independent of QK^T) -> latency
    // hides under QK^T issue + the whole softmax.
    bf16x8 vfr[4][2];
#pragma unroll
    for (int n = 0; n < 4; ++n)
#pragma unroll
      for (int kc = 0; kc < 2; ++kc)
        vfr[n][kc] = ld8(Vp + (size_t)(n * 16) * 2048 + j0 + kc * 32);

    // S = K . Q^T : lane holds S[key = j0+knt+8*qq+i][q = m*16+r]
    f32x4 s[4][4] = {};
    __builtin_amdgcn_s_setprio(1);
#pragma unroll
    for (int nt = 0; nt < 4; ++nt)
#pragma unroll
      for (int kc = 0; kc < 2; ++kc)
#pragma unroll
        for (int m = 0; m < 4; ++m) s[nt][m] = mfma16(kf[nt][kc], qf[m][kc], s[nt][m]);
    __builtin_amdgcn_s_setprio(0);

    // K fragments for this wave's NEXT tile (it+2), in flight across softmax+PV
    if (it + 2 < ntw) {
#pragma unroll
      for (int nt = 0; nt < 4; ++nt) {
        int knt = 32 * (nt >> 1) + 4 * (nt & 1);
#pragma unroll
        for (int kc = 0; kc < 2; ++kc)
          kf[nt][kc] = ld8(Kp + (size_t)(j0 + 128 + knt) * 64 + kc * 32);
      }
    }

    // causal mask: only the single diagonal tile (j0 == q0w); q pre-scaled -> no scale op
    bool nm = (j0 + 63 > q0w);
    if (nm) {
#pragma unroll
      for (int nt = 0; nt < 4; ++nt) {
        int kb = j0 + 32 * (nt >> 1) + 4 * (nt & 1) + 8 * qq;
#pragma unroll
        for (int m = 0; m < 4; ++m) {
          int qg = q0w + m * 16 + r;
#pragma unroll
          for (int i = 0; i < 4; ++i)
            s[nt][m][i] = (kb + i <= qg) ? s[nt][m][i] : -1e30f;
        }
      }
    }

    // row max: fold 16 in-lane, then 2 shuffle rounds across qq groups
    float tm[4];
#pragma unroll
    for (int m = 0; m < 4; ++m) {
      float t0 = fmaxf(fmaxf(s[0][m][0], s[0][m][1]), fmaxf(s[0][m][2], s[0][m][3]));
      float t1 = fmaxf(fmaxf(s[1][m][0], s[1][m][1]), fmaxf(s[1][m][2], s[1][m][3]));
      float t2 = fmaxf(fmaxf(s[2][m][0], s[2][m][1]), fmaxf(s[2][m][2], s[2][m][3]));
      float t3 = fmaxf(fmaxf(s[3][m][0], s[3][m][1]), fmaxf(s[3][m][2], s[3][m][3]));
      float t = fmaxf(fmaxf(t0, t1), fmaxf(t2, t3));
      t = fmaxf(t, __shfl_xor(t, 16));
      t = fmaxf(t, __shfl_xor(t, 32));
      tm[m] = t;
    }

    // rescale only if the running max grew (corr would be exactly 1 otherwise)
    int grow = (tm[0] > m_run[0]) | (tm[1] > m_run[1]) | (tm[2] > m_run[2]) |
               (tm[3] > m_run[3]);
    if (__any(grow)) {
#pragma unroll
      for (int m = 0; m < 4; ++m) {
        float mn = fmaxf(m_run[m], tm[m]);
        float corr = __builtin_amdgcn_exp2f(m_run[m] - mn);
        m_run[m] = mn;
        l_run[m] *= corr;
        // acc layout has q = m*16 + qq*4 + i -> pull corr from lane qq*4+i
#pragma unroll
        for (int i = 0; i < 4; ++i) {
          float c = __shfl(corr, qq * 4 + i);
#pragma unroll
          for (int n = 0; n < 4; ++n) acc[m][n][i] *= c;
        }
      }
    }

    // P = exp2(S - m) via raw v_exp_f32; per-lane partial row sums
#pragma unroll
    for (int m = 0; m < 4; ++m) {
      float ls = 0.f;
#pragma unroll
      for (int nt = 0; nt < 4; ++nt)
#pragma unroll
        for (int i = 0; i < 4; ++i) {
          float e = __builtin_amdgcn_exp2f(s[nt][m][i] - m_run[m]);
          s[nt][m][i] = e;
          ls += e;
        }
      l_run[m] += ls;
    }

    // PV: P packs straight into A-fragments in-lane (8 cvt_pk per m), no LDS
    __builtin_amdgcn_s_setprio(1);
#pragma unroll
    for (int m = 0; m < 4; ++m) {
      bf16x8 pa0 = pack8(s[0][m], s[1][m]);  // keys qq*8+0..7
      bf16x8 pa1 = pack8(s[2][m], s[3][m]);  // keys 32+qq*8+0..7
#pragma unroll
      for (int n = 0; n < 4; ++n) acc[m][n] = mfma16(pa0, vfr[n][0], acc[m][n]);
#pragma unroll
      for (int n = 0; n < 4; ++n) acc[m][n] = mfma16(pa1, vfr[n][1], acc[m][n]);
    }
    __builtin_amdgcn_s_setprio(0);
  }

  // per-wave: reduce row-sum partials across qq groups (full row sum for q=m*16+r)
  float lfin[4];
#pragma unroll
  for (int m = 0; m < 4; ++m) {
    float l = l_run[m];
    l += __shfl_xor(l, 16);
    l += __shfl_xor(l, 32);
    lfin[m] = l;
  }

  // wave 1 stages its state; wave 0 merges and writes
  if (w == 1) {
#pragma unroll
    for (int m = 0; m < 4; ++m) {
#pragma unroll
      for (int n = 0; n < 4; ++n) *(f32x4*)&accB[m][n][lane][0] = acc[m][n];
      mlB[0][m][lane] = m_run[m];
      mlB[1][m][lane] = lfin[m];
    }
  }
  __syncthreads();
  if (w == 1) return;

  // flash merge (lane holds q = m*16+r state): m = max(mA,mB);
  // fA = e^{mA-m}/l, fB = e^{mB-m}/l with l = lA e^{mA-m} + lB e^{mB-m}
  float fA[4], fB[4];
#pragma unroll
  for (int m = 0; m < 4; ++m) {
    float mBv = mlB[0][m][lane], lBv = mlB[1][m][lane];
    float mM = fmaxf(m_run[m], mBv);
    float cA = __builtin_amdgcn_exp2f(m_run[m] - mM);
    float cB = __builtin_amdgcn_exp2f(mBv - mM);
    float inv = 1.0f / (lfin[m] * cA + lBv * cB);
    fA[m] = cA * inv;
    fB[m] = cB * inv;
  }
#pragma unroll
  for (int m = 0; m < 4; ++m)
#pragma unroll
    for (int i = 0; i < 4; ++i) {
      float a = __shfl(fA[m], qq * 4 + i);   // factor for q = m*16 + qq*4 + i
      float bq = __shfl(fB[m], qq * 4 + i);
#pragma unroll
      for (int n = 0; n < 4; ++n) {
        float o = acc[m][n][i] * a + accB[m][n][lane][i] * bq;
        Y[((size_t)(b * 2048 + q0w + m * 16 + qq * 4 + i)) * 1024 + h * 64 + n * 16 + r] =
            f2b(o);
      }
    }
}

// ---------------- launch ----------------
extern "C" void kernel_launch(void* const* d_in, const int* in_sizes, int n_in,
                              void* d_out, int out_size, void* d_ws, size_t ws_size,
                              hipStream_t stream) {
  const float* x = (const float*)d_in[0];       // [4,2048,1024]
  const float* w_attn = (const float*)d_in[1];  // [1024,3072]
  const float* w_o = (const float*)d_in[2];     // [1024,1024]
  float* out = (float*)d_out;                   // [4,2048,1024]

  char* ws = (char*)d_ws;
  u16* xb = (u16*)(ws + 0);                    // [8192][1024]        16,777,216 B
  u16* watT = (u16*)(ws + 16777216);           // [3072][1024]         6,291,456 B
  u16* woT = (u16*)(ws + 23068672);            // [1024][1024]         2,097,152 B
  u16* qb = (u16*)(ws + 25165824);             // q [4][16][2048][64] 16,777,216 B
  u16* kb = (u16*)(ws + 41943040);             // k                   16,777,216 B
  u16* vb = (u16*)(ws + 58720256);             // V^T [4][16][64][2048] 16,777,216 B
  u16* yb = (u16*)(ws + 75497472);             // y [4][2048][1024]   16,777,216 B

  k_cvt<<<2048, 256, 0, stream>>>(x, xb, 8192 * 1024 / 4);
  k_tr<<<dim3(3072 / 32, 1024 / 32), dim3(32, 8), 0, stream>>>(w_attn, watT, 1024, 3072);
  k_tr<<<dim3(1024 / 32, 1024 / 32), dim3(32, 8), 0, stream>>>(w_o, woT, 1024, 1024);
  k_gemm<0><<<dim3(24, 64), 256, 0, stream>>>(xb, watT, (void*)qb);
  k_attn<<<dim3(2048), 128, 0, stream>>>(qb, kb, vb, yb);
  k_gemm<1><<<dim3(8, 64), 256, 0, stream>>>(yb, woT, (void*)out);
}

// Round 10
// 205.830 us; speedup vs baseline: 1.7183x; 1.0323x over previous
//
#include <hip/hip_runtime.h>

typedef unsigned short u16;
typedef unsigned int u32;
typedef __attribute__((ext_vector_type(8))) __bf16 bf16x8;
typedef __attribute__((ext_vector_type(4))) float f32x4;
typedef __attribute__((ext_vector_type(8))) unsigned short u16x8;
typedef __attribute__((ext_vector_type(4))) unsigned int u32x4;

typedef const __attribute__((address_space(1))) u32 gu32;
typedef __attribute__((address_space(3))) u32 lu32;

// fp32 -> bf16 round-to-nearest-even
__device__ __forceinline__ u16 f2b(float f) {
  u32 u = __builtin_bit_cast(u32, f);
  u32 r = u + 0x7fffu + ((u >> 16) & 1u);
  return (u16)(r >> 16);
}

// packed fp32 pair -> bf16 pair (RNE), lo in [15:0]
__device__ __forceinline__ u32 pk2(float lo, float hi) {
  u32 d;
  asm("v_cvt_pk_bf16_f32 %0, %1, %2" : "=v"(d) : "v"(lo), "v"(hi));
  return d;
}

// two f32x4 -> one bf16x8 (elements 0..3 from a, 4..7 from b)
__device__ __forceinline__ bf16x8 pack8(f32x4 a, f32x4 b) {
  u32x4 u;
  u[0] = pk2(a[0], a[1]);
  u[1] = pk2(a[2], a[3]);
  u[2] = pk2(b[0], b[1]);
  u[3] = pk2(b[2], b[3]);
  return __builtin_bit_cast(bf16x8, u);
}

__device__ __forceinline__ bf16x8 ld8(const u16* p) {
  return __builtin_bit_cast(bf16x8, *(const u16x8*)p);
}

__device__ __forceinline__ void gll16(const void* g, void* l) {
  __builtin_amdgcn_global_load_lds((gu32*)g, (lu32*)l, 16, 0, 0);
}

__device__ __forceinline__ f32x4 mfma16(bf16x8 a, bf16x8 b, f32x4 c) {
  return __builtin_amdgcn_mfma_f32_16x16x32_bf16(a, b, c, 0, 0, 0);
}

// ---------------- fp32 -> bf16 elementwise ----------------
__global__ void k_cvt(const float* __restrict__ in, u16* __restrict__ out, int n4) {
  int i = blockIdx.x * blockDim.x + threadIdx.x;
  int stride = gridDim.x * blockDim.x;
  for (int idx = i; idx < n4; idx += stride) {
    float4 v = ((const float4*)in)[idx];
    u32 lo = (u32)f2b(v.x) | ((u32)f2b(v.y) << 16);
    u32 hi = (u32)f2b(v.z) | ((u32)f2b(v.w) << 16);
    ((uint2*)out)[idx] = make_uint2(lo, hi);
  }
}

// ---------------- transpose+convert: in[R][C] f32 -> out[C][R] bf16 ----------------
__global__ void k_tr(const float* __restrict__ in, u16* __restrict__ out, int R, int C) {
  __shared__ u16 tile[32][33];
  int bx = blockIdx.x * 32;  // along C
  int by = blockIdx.y * 32;  // along R
  int tx = threadIdx.x, ty = threadIdx.y;  // (32, 8)
#pragma unroll
  for (int i = 0; i < 32; i += 8)
    tile[ty + i][tx] = f2b(in[(size_t)(by + ty + i) * C + bx + tx]);
  __syncthreads();
#pragma unroll
  for (int i = 0; i < 32; i += 8)
    out[(size_t)(bx + ty + i) * R + by + tx] = tile[tx][ty + i];
}

// ---------------- GEMM: A[M][1024] * B^T (B given as [N][1024]), 128x128 tile ----------------
// EPI=0: scatter bf16 into q/k [B=4][H=16][T=2048][64] and V TRANSPOSED [B][H][64][T=2048].
//        q is stored PRE-SCALED by csc = 1/sqrt(64)*log2(e) (folded out of the attn loop).
// EPI=1: fp32 out [M][1024]
template <int EPI>
__global__ __launch_bounds__(256) void k_gemm(const u16* __restrict__ A,
                                              const u16* __restrict__ B,
                                              void* __restrict__ Cp) {
  const int K = 1024;
  __shared__ __align__(16) u16 As[128 * 32];
  __shared__ __align__(16) u16 Bs[128 * 32];
  int tid = threadIdx.x;
  int lane = tid & 63, wid = tid >> 6;
  int wr = wid >> 1, wc = wid & 1;
  int m0 = blockIdx.y * 128, n0 = blockIdx.x * 128;
  int r = lane & 15, qq = lane >> 4;

  const u16* Ag0 = A + (size_t)(m0 + wid * 32 + (lane >> 2)) * K + (lane & 3) * 8;
  const u16* Bg0 = B + (size_t)(n0 + wid * 32 + (lane >> 2)) * K + (lane & 3) * 8;
  u16* Asl0 = As + (wid * 32) * 32;
  u16* Asl1 = As + (wid * 32 + 16) * 32;
  u16* Bsl0 = Bs + (wid * 32) * 32;
  u16* Bsl1 = Bs + (wid * 32 + 16) * 32;

  f32x4 acc[4][4] = {};

  for (int k0 = 0; k0 < K; k0 += 32) {
    gll16(Ag0 + k0, Asl0);
    gll16(Ag0 + 16 * K + k0, Asl1);
    gll16(Bg0 + k0, Bsl0);
    gll16(Bg0 + 16 * K + k0, Bsl1);
    __syncthreads();
    bf16x8 af[4], bfr[4];
#pragma unroll
    for (int m = 0; m < 4; ++m) af[m] = ld8(&As[(wr * 64 + m * 16 + r) * 32 + qq * 8]);
#pragma unroll
    for (int n = 0; n < 4; ++n) bfr[n] = ld8(&Bs[(wc * 64 + n * 16 + r) * 32 + qq * 8]);
#pragma unroll
    for (int m = 0; m < 4; ++m)
#pragma unroll
      for (int n = 0; n < 4; ++n) acc[m][n] = mfma16(af[m], bfr[n], acc[m][n]);
    __syncthreads();
  }

  if constexpr (EPI == 0) {
    u16* qkv = (u16*)Cp;
#pragma unroll
    for (int m = 0; m < 4; ++m) {
      int gr = m0 + wr * 64 + m * 16 + qq * 4;
      int b = gr >> 11, t0 = gr & 2047;
#pragma unroll
      for (int n = 0; n < 4; ++n) {
        int gc = n0 + wc * 64 + n * 16 + r;
        int which = gc >> 10, rem = gc & 1023;
        int hh = rem >> 6, d = rem & 63;
        if (which == 2) {
          // V^T: [(b*16+hh)*64 + d][2048] ; acc i-index is t (contiguous) -> one 8B store
          u16* dst = qkv + (size_t)2 * 8388608u +
                     ((size_t)((b * 16 + hh) * 64 + d)) * 2048 + t0;
          u32 p0 = pk2(acc[m][n][0], acc[m][n][1]);
          u32 p1 = pk2(acc[m][n][2], acc[m][n][3]);
          *(uint2*)dst = make_uint2(p0, p1);
        } else {
          // q (which==0) pre-scaled by csc; k (which==1) raw
          float sc = (which == 0) ? 0.18033688011112042f : 1.0f;
          u16* dst = qkv + (size_t)which * 8388608u +
                     ((size_t)((b * 16 + hh) * 2048 + t0)) * 64 + d;
#pragma unroll
          for (int i = 0; i < 4; ++i) dst[(size_t)i * 64] = f2b(acc[m][n][i] * sc);
        }
      }
    }
  } else {
    float* out = (float*)Cp;
#pragma unroll
    for (int m = 0; m < 4; ++m) {
      int gr = m0 + wr * 64 + m * 16 + qq * 4;
#pragma unroll
      for (int n = 0; n < 4; ++n) {
        int gc = n0 + wc * 64 + n * 16 + r;
#pragma unroll
        for (int i = 0; i < 4; ++i) out[(size_t)(gr + i) * 1024 + gc] = acc[m][n][i];
      }
    }
  }
}

// ---------------- flash attention (shared-KV LDS, 4 waves/WG, swapped QK^T) ----------------
// R10: root cause since R7 is per-tile global-load latency that the allocator refuses to
// register-pipeline (pins 128 VGPR, serializes loads). Fix: 4 waves share each 64-key
// K/V tile via DOUBLE-BUFFERED LDS (32 KB), staged with global_load_lds from a
// pre-swizzled global source; waves read fragments JIT via ds_read_b128 (~100 cy,
// compiler-scheduled) so nothing is held across a tile. Global K/V traffic /4.
// Geometry: WG = 256 thr = 4 waves x 32 q-rows (128-row q-block); grid = 16 x 64 = 1024
// WGs = EXACTLY 4 WGs/CU resident (LDS 32 KB); per-CU work balanced (one long + med +
// short + shortest q-block each). Dispatch: bi = x*64+bh, x=0 longest; bi%8=bh%8 (XCD).
// Per-tile schedule: QK^T (JIT kf) -> bulk vfr reads -> STAGE next tile (gll16 issued
// AFTER this tile's LDS reads -> no conservative vmcnt before them; flies under
// softmax+PV) -> softmax -> PV -> ONE __syncthreads (its vmcnt drain = where the next
// tile's data is needed anyway).
// LDS swizzle (both-sides XOR, verified by hand): K row knt+8a+c read pattern spans
// only row&3 -> fk(row) = (row&3)|(((row>>3)&1)<<2) spreads 8 slots; V^T rows are
// r-consecutive -> fv(row) = row&7. Store chunk (lane&7)^f at slot lane&7 (linear
// dest); read chunk q at slot q^f.
__global__ __launch_bounds__(256) void k_attn(const u16* __restrict__ Qm,
                                              const u16* __restrict__ Km,
                                              const u16* __restrict__ VTm,
                                              u16* __restrict__ Y) {
  int bi = blockIdx.x;
  int x = bi >> 6;   // 0..15, 0 = longest q-block
  int bh = bi & 63;  // bi%8 = bh%8 -> head pinned to one XCD residue
  int b = bh >> 4, h = bh & 15;
  int qb0 = (15 - x) * 128;  // WG's first q row
  int tid = threadIdx.x, lane = tid & 63, w = tid >> 6;
  int r = lane & 15, qq = lane >> 4;
  const size_t base = (size_t)bh * (2048 * 64);
  int q0w = qb0 + w * 32;  // this wave's first q row

  __shared__ __align__(16) u16 Kt[2][64 * 64];  // [buf][key][64], slot-swizzled (fk)
  __shared__ __align__(16) u16 Vt[2][64 * 64];  // [buf][d][64 keys], slot-swizzled (fv)

  // Q fragments (B-operand): q rows m*16+r, d-slices kc*32+qq*8 (q pre-scaled by csc)
  bf16x8 qf[2][2];
#pragma unroll
  for (int m = 0; m < 2; ++m)
#pragma unroll
    for (int kc = 0; kc < 2; ++kc)
      qf[m][kc] = ld8(Qm + base + (size_t)(q0w + m * 16 + r) * 64 + kc * 32 + qq * 8);

  f32x4 acc[2][4] = {};
  float m_run[2] = {-1e30f, -1e30f};
  float l_run[2] = {0.f, 0.f};
  int ntwg = (qb0 >> 6) + 2;  // WG-uniform tile count (keys 0..qb0+127)

  // staging constants: wave w stages K rows / V^T d-rows w*16..w*16+15 (2 slabs of 8)
  int srow = lane >> 3;                        // 0..7 within a slab
  int kch0 = (lane & 7) ^ (srow & 3);          // slab c=0: fk = (srow&3)|0
  int kch1 = (lane & 7) ^ ((srow & 3) | 4);    // slab c=1: row bit3=1 -> fk bit2=1
  int vch = (lane & 7) ^ srow;                 // fv = row&7 = srow
  const u16* Kg = Km + base;
  const u16* Vg = VTm + base;

  // read-side constants
  int ar = 8 * (r >> 2) + (r & 3);                       // A-fragment row offset
  int fkl = (r & 3) | (((r >> 2) & 1) << 2);             // fk(knt+ar), knt-independent
  int ks0 = ((qq ^ fkl)) * 8, ks1 = ((qq ^ fkl) ^ 4) * 8;
  int fvl = r & 7;
  int vs0 = ((qq ^ fvl)) * 8, vs1 = ((qq ^ fvl) ^ 4) * 8;

#define STAGE(buf, j0n)                                                                 \
  do {                                                                                  \
    gll16(Kg + (size_t)((j0n) + w * 16 + srow) * 64 + kch0 * 8,                         \
          &Kt[buf][(w * 16) * 64]);                                                     \
    gll16(Kg + (size_t)((j0n) + w * 16 + 8 + srow) * 64 + kch1 * 8,                     \
          &Kt[buf][(w * 16 + 8) * 64]);                                                 \
    gll16(Vg + (size_t)(w * 16 + srow) * 2048 + (j0n) + vch * 8,                        \
          &Vt[buf][(w * 16) * 64]);                                                     \
    gll16(Vg + (size_t)(w * 16 + 8 + srow) * 2048 + (j0n) + vch * 8,                    \
          &Vt[buf][(w * 16 + 8) * 64]);                                                 \
  } while (0)

  STAGE(0, 0);
  __syncthreads();

  for (int it = 0; it < ntwg; ++it) {
    int j0 = it << 6;
    int cur = it & 1;
    bool active = (j0 <= q0w + 31);  // wave-uniform
    f32x4 s[4][2];
    bf16x8 vfr[4][2];

    if (active) {
      // S = K . Q^T with JIT kf reads from LDS
      __builtin_amdgcn_s_setprio(1);
#pragma unroll
      for (int nt = 0; nt < 4; ++nt) {
        int knt = 32 * (nt >> 1) + 4 * (nt & 1);
        const u16* kb_ = &Kt[cur][(knt + ar) * 64];
        bf16x8 k0 = ld8(kb_ + ks0);
        bf16x8 k1 = ld8(kb_ + ks1);
#pragma unroll
        for (int m = 0; m < 2; ++m) {
          f32x4 z = {};
          s[nt][m] = mfma16(k1, qf[m][1], mfma16(k0, qf[m][0], z));
        }
      }
      // bulk V^T fragment reads (consumed at PV; issued before STAGE on purpose)
#pragma unroll
      for (int n = 0; n < 4; ++n) {
        const u16* vb_ = &Vt[cur][(n * 16 + r) * 64];
        vfr[n][0] = ld8(vb_ + vs0);
        vfr[n][1] = ld8(vb_ + vs1);
      }
      __builtin_amdgcn_s_setprio(0);
    }

    // stage NEXT tile: issued after this tile's LDS reads; flies under softmax+PV
    if (it + 1 < ntwg) STAGE(cur ^ 1, j0 + 64);

    if (active) {
      // causal mask on diagonal tiles only (q pre-scaled -> no scale op)
      bool nm = (j0 + 63 > q0w);
      if (nm) {
#pragma unroll
        for (int nt = 0; nt < 4; ++nt) {
          int kb = j0 + 32 * (nt >> 1) + 4 * (nt & 1) + 8 * qq;
#pragma unroll
          for (int m = 0; m < 2; ++m) {
            int qg = q0w + m * 16 + r;
#pragma unroll
            for (int i = 0; i < 4; ++i)
              s[nt][m][i] = (kb + i <= qg) ? s[nt][m][i] : -1e30f;
          }
        }
      }

      // row max: 15 in-lane fmax + 2 shfl rounds across qq groups
      float tm[2];
#pragma unroll
      for (int m = 0; m < 2; ++m) {
        float t0 = fmaxf(fmaxf(s[0][m][0], s[0][m][1]), fmaxf(s[0][m][2], s[0][m][3]));
        float t1 = fmaxf(fmaxf(s[1][m][0], s[1][m][1]), fmaxf(s[1][m][2], s[1][m][3]));
        float t2 = fmaxf(fmaxf(s[2][m][0], s[2][m][1]), fmaxf(s[2][m][2], s[2][m][3]));
        float t3 = fmaxf(fmaxf(s[3][m][0], s[3][m][1]), fmaxf(s[3][m][2], s[3][m][3]));
        float t = fmaxf(fmaxf(t0, t1), fmaxf(t2, t3));
        t = fmaxf(t, __shfl_xor(t, 16));
        t = fmaxf(t, __shfl_xor(t, 32));
        tm[m] = t;
      }

      // rescale only if the running max grew
      int grow = (tm[0] > m_run[0]) | (tm[1] > m_run[1]);
      if (__any(grow)) {
#pragma unroll
        for (int m = 0; m < 2; ++m) {
          float mn = fmaxf(m_run[m], tm[m]);
          float corr = __builtin_amdgcn_exp2f(m_run[m] - mn);
          m_run[m] = mn;
          l_run[m] *= corr;
#pragma unroll
          for (int i = 0; i < 4; ++i) {
            float c = __shfl(corr, qq * 4 + i);
#pragma unroll
            for (int n = 0; n < 4; ++n) acc[m][n][i] *= c;
          }
        }
      }

      // P = exp2(S - m) via raw v_exp_f32; per-lane partial row sums
#pragma unroll
      for (int m = 0; m < 2; ++m) {
        float ls = 0.f;
#pragma unroll
        for (int nt = 0; nt < 4; ++nt)
#pragma unroll
          for (int i = 0; i < 4; ++i) {
            float e = __builtin_amdgcn_exp2f(s[nt][m][i] - m_run[m]);
            s[nt][m][i] = e;
            ls += e;
          }
        l_run[m] += ls;
      }

      // PV: P packs straight into A-fragments in-lane; vfr already in regs
      __builtin_amdgcn_s_setprio(1);
#pragma unroll
      for (int m = 0; m < 2; ++m) {
        bf16x8 pa0 = pack8(s[0][m], s[1][m]);  // keys qq*8+0..7
        bf16x8 pa1 = pack8(s[2][m], s[3][m]);  // keys 32+qq*8+0..7
#pragma unroll
        for (int n = 0; n < 4; ++n) acc[m][n] = mfma16(pa0, vfr[n][0], acc[m][n]);
#pragma unroll
        for (int n = 0; n < 4; ++n) acc[m][n] = mfma16(pa1, vfr[n][1], acc[m][n]);
      }
      __builtin_amdgcn_s_setprio(0);
    }

    __syncthreads();  // drains next-tile stage (already flown) + protects buf reuse
  }
#undef STAGE

  // epilogue: sum partials across qq groups, invert, redistribute to acc layout
  float li[2][4];
#pragma unroll
  for (int m = 0; m < 2; ++m) {
    float l = l_run[m];
    l += __shfl_xor(l, 16);
    l += __shfl_xor(l, 32);
    float inv = 1.0f / l;
#pragma unroll
    for (int i = 0; i < 4; ++i) li[m][i] = __shfl(inv, qq * 4 + i);
  }
#pragma unroll
  for (int m = 0; m < 2; ++m)
#pragma unroll
    for (int n = 0; n < 4; ++n)
#pragma unroll
      for (int i = 0; i < 4; ++i)
        Y[((size_t)(b * 2048 + q0w + m * 16 + qq * 4 + i)) * 1024 + h * 64 + n * 16 + r] =
            f2b(acc[m][n][i] * li[m][i]);
}

// ---------------- launch ----------------
extern "C" void kernel_launch(void* const* d_in, const int* in_sizes, int n_in,
                              void* d_out, int out_size, void* d_ws, size_t ws_size,
                              hipStream_t stream) {
  const float* x = (const float*)d_in[0];       // [4,2048,1024]
  const float* w_attn = (const float*)d_in[1];  // [1024,3072]
  const float* w_o = (const float*)d_in[2];     // [1024,1024]
  float* out = (float*)d_out;                   // [4,2048,1024]

  char* ws = (char*)d_ws;
  u16* xb = (u16*)(ws + 0);                    // [8192][1024]        16,777,216 B
  u16* watT = (u16*)(ws + 16777216);           // [3072][1024]         6,291,456 B
  u16* woT = (u16*)(ws + 23068672);            // [1024][1024]         2,097,152 B
  u16* qb = (u16*)(ws + 25165824);             // q [4][16][2048][64] 16,777,216 B
  u16* kb = (u16*)(ws + 41943040);             // k                   16,777,216 B
  u16* vb = (u16*)(ws + 58720256);             // V^T [4][16][64][2048] 16,777,216 B
  u16* yb = (u16*)(ws + 75497472);             // y [4][2048][1024]   16,777,216 B

  k_cvt<<<2048, 256, 0, stream>>>(x, xb, 8192 * 1024 / 4);
  k_tr<<<dim3(3072 / 32, 1024 / 32), dim3(32, 8), 0, stream>>>(w_attn, watT, 1024, 3072);
  k_tr<<<dim3(1024 / 32, 1024 / 32), dim3(32, 8), 0, stream>>>(w_o, woT, 1024, 1024);
  k_gemm<0><<<dim3(24, 64), 256, 0, stream>>>(xb, watT, (void*)qb);
  k_attn<<<dim3(1024), 256, 0, stream>>>(qb, kb, vb, yb);
  k_gemm<1><<<dim3(8, 64), 256, 0, stream>>>(yb, woT, (void*)out);
}

// Round 11
// 187.645 us; speedup vs baseline: 1.8849x; 1.0969x over previous
//
#include <hip/hip_runtime.h>

typedef unsigned short u16;
typedef unsigned int u32;
typedef __attribute__((ext_vector_type(8))) __bf16 bf16x8;
typedef __attribute__((ext_vector_type(4))) float f32x4;
typedef __attribute__((ext_vector_type(8))) unsigned short u16x8;
typedef __attribute__((ext_vector_type(4))) unsigned int u32x4;

typedef const __attribute__((address_space(1))) u32 gu32;
typedef __attribute__((address_space(3))) u32 lu32;

// fp32 -> bf16 round-to-nearest-even
__device__ __forceinline__ u16 f2b(float f) {
  u32 u = __builtin_bit_cast(u32, f);
  u32 r = u + 0x7fffu + ((u >> 16) & 1u);
  return (u16)(r >> 16);
}

// packed fp32 pair -> bf16 pair (RNE), lo in [15:0]
__device__ __forceinline__ u32 pk2(float lo, float hi) {
  u32 d;
  asm("v_cvt_pk_bf16_f32 %0, %1, %2" : "=v"(d) : "v"(lo), "v"(hi));
  return d;
}

// two f32x4 -> one bf16x8 (elements 0..3 from a, 4..7 from b)
__device__ __forceinline__ bf16x8 pack8(f32x4 a, f32x4 b) {
  u32x4 u;
  u[0] = pk2(a[0], a[1]);
  u[1] = pk2(a[2], a[3]);
  u[2] = pk2(b[0], b[1]);
  u[3] = pk2(b[2], b[3]);
  return __builtin_bit_cast(bf16x8, u);
}

__device__ __forceinline__ bf16x8 ld8(const u16* p) {
  return __builtin_bit_cast(bf16x8, *(const u16x8*)p);
}

__device__ __forceinline__ void gll16(const void* g, void* l) {
  __builtin_amdgcn_global_load_lds((gu32*)g, (lu32*)l, 16, 0, 0);
}

__device__ __forceinline__ f32x4 mfma16(bf16x8 a, bf16x8 b, f32x4 c) {
  return __builtin_amdgcn_mfma_f32_16x16x32_bf16(a, b, c, 0, 0, 0);
}

// ---------------- fp32 -> bf16 elementwise ----------------
__global__ void k_cvt(const float* __restrict__ in, u16* __restrict__ out, int n4) {
  int i = blockIdx.x * blockDim.x + threadIdx.x;
  int stride = gridDim.x * blockDim.x;
  for (int idx = i; idx < n4; idx += stride) {
    float4 v = ((const float4*)in)[idx];
    u32 lo = (u32)f2b(v.x) | ((u32)f2b(v.y) << 16);
    u32 hi = (u32)f2b(v.z) | ((u32)f2b(v.w) << 16);
    ((uint2*)out)[idx] = make_uint2(lo, hi);
  }
}

// ---------------- transpose+convert: in[R][C] f32 -> out[C][R] bf16 ----------------
__global__ void k_tr(const float* __restrict__ in, u16* __restrict__ out, int R, int C) {
  __shared__ u16 tile[32][33];
  int bx = blockIdx.x * 32;  // along C
  int by = blockIdx.y * 32;  // along R
  int tx = threadIdx.x, ty = threadIdx.y;  // (32, 8)
#pragma unroll
  for (int i = 0; i < 32; i += 8)
    tile[ty + i][tx] = f2b(in[(size_t)(by + ty + i) * C + bx + tx]);
  __syncthreads();
#pragma unroll
  for (int i = 0; i < 32; i += 8)
    out[(size_t)(bx + ty + i) * R + by + tx] = tile[tx][ty + i];
}

// ---------------- GEMM: A[M][1024] * B^T (B given as [N][1024]), 128x128 tile ----------------
// R11: counted-vmcnt double-buffered pipeline (T3/T4 minimum form). The old loop's first
// __syncthreads drained vmcnt(0) right after issuing the stage -> full HBM/L2 latency
// exposed on every one of the 32 K-steps (MfmaUtil 22%, m233's stage+vmcnt+barrier
// overhead regime). New per-step protocol, 2-deep prefetch, 2 LDS buffers:
//   s_waitcnt vmcnt(4)   (tile kt landed; kt+1's 4 loads stay IN FLIGHT across barrier)
//   s_barrier            (raw -- no vmcnt drain, unlike __syncthreads)
//   ds_read_b128 frags; s_waitcnt lgkmcnt(0); sched_barrier(0)   (reads done, pinned)
//   s_barrier            (all waves done reading buf -> safe to overwrite)
//   STAGE(kt+2) into this buf (flies under MFMA + next step's wait)
//   16x MFMA
// Only vmcnt(0) is the last step. LDS 16->32 KB (still >=5 WG/CU at VGPR ~92).
// EPI=0: scatter bf16 into q/k [B=4][H=16][T=2048][64] and V TRANSPOSED [B][H][64][T=2048].
//        q is stored PRE-SCALED by csc = 1/sqrt(64)*log2(e).
// EPI=1: fp32 out [M][1024]
template <int EPI>
__global__ __launch_bounds__(256) void k_gemm(const u16* __restrict__ A,
                                              const u16* __restrict__ B,
                                              void* __restrict__ Cp) {
  const int K = 1024;
  const int NT = 32;  // K / 32
  __shared__ __align__(16) u16 As[2][128 * 32];
  __shared__ __align__(16) u16 Bs[2][128 * 32];
  int tid = threadIdx.x;
  int lane = tid & 63, wid = tid >> 6;
  int wr = wid >> 1, wc = wid & 1;
  int m0 = blockIdx.y * 128, n0 = blockIdx.x * 128;
  int r = lane & 15, qq = lane >> 4;

  const u16* Ag0 = A + (size_t)(m0 + wid * 32 + (lane >> 2)) * K + (lane & 3) * 8;
  const u16* Bg0 = B + (size_t)(n0 + wid * 32 + (lane >> 2)) * K + (lane & 3) * 8;
  int sl0 = (wid * 32) * 32;        // this wave's staging rows (0..15)
  int sl1 = (wid * 32 + 16) * 32;   // rows 16..31

#define GSTAGE(buf, k0)                          \
  do {                                           \
    gll16(Ag0 + (k0), &As[buf][sl0]);            \
    gll16(Ag0 + 16 * K + (k0), &As[buf][sl1]);   \
    gll16(Bg0 + (k0), &Bs[buf][sl0]);            \
    gll16(Bg0 + 16 * K + (k0), &Bs[buf][sl1]);   \
  } while (0)

  f32x4 acc[4][4] = {};

  GSTAGE(0, 0);
  GSTAGE(1, 32);

  for (int kt = 0; kt < NT; ++kt) {
    int cur = kt & 1;
    if (kt + 1 < NT)
      asm volatile("s_waitcnt vmcnt(4)" ::: "memory");  // kt landed, kt+1 in flight
    else
      asm volatile("s_waitcnt vmcnt(0)" ::: "memory");  // final tile
    __builtin_amdgcn_s_barrier();  // raw: no vmcnt drain

    bf16x8 af[4], bfr[4];
#pragma unroll
    for (int m = 0; m < 4; ++m)
      af[m] = ld8(&As[cur][(wr * 64 + m * 16 + r) * 32 + qq * 8]);
#pragma unroll
    for (int n = 0; n < 4; ++n)
      bfr[n] = ld8(&Bs[cur][(wc * 64 + n * 16 + r) * 32 + qq * 8]);
    asm volatile("s_waitcnt lgkmcnt(0)" ::: "memory");
    __builtin_amdgcn_sched_barrier(0);
    __builtin_amdgcn_s_barrier();  // all waves done reading buf cur

    if (kt + 2 < NT) GSTAGE(cur, (kt + 2) * 32);  // overwrite cur; flies under MFMA

#pragma unroll
    for (int m = 0; m < 4; ++m)
#pragma unroll
      for (int n = 0; n < 4; ++n) acc[m][n] = mfma16(af[m], bfr[n], acc[m][n]);
  }
#undef GSTAGE

  if constexpr (EPI == 0) {
    u16* qkv = (u16*)Cp;
#pragma unroll
    for (int m = 0; m < 4; ++m) {
      int gr = m0 + wr * 64 + m * 16 + qq * 4;
      int b = gr >> 11, t0 = gr & 2047;
#pragma unroll
      for (int n = 0; n < 4; ++n) {
        int gc = n0 + wc * 64 + n * 16 + r;
        int which = gc >> 10, rem = gc & 1023;
        int hh = rem >> 6, d = rem & 63;
        if (which == 2) {
          // V^T: [(b*16+hh)*64 + d][2048] ; acc i-index is t (contiguous) -> one 8B store
          u16* dst = qkv + (size_t)2 * 8388608u +
                     ((size_t)((b * 16 + hh) * 64 + d)) * 2048 + t0;
          u32 p0 = pk2(acc[m][n][0], acc[m][n][1]);
          u32 p1 = pk2(acc[m][n][2], acc[m][n][3]);
          *(uint2*)dst = make_uint2(p0, p1);
        } else {
          // q (which==0) pre-scaled by csc; k (which==1) raw
          float sc = (which == 0) ? 0.18033688011112042f : 1.0f;
          u16* dst = qkv + (size_t)which * 8388608u +
                     ((size_t)((b * 16 + hh) * 2048 + t0)) * 64 + d;
#pragma unroll
          for (int i = 0; i < 4; ++i) dst[(size_t)i * 64] = f2b(acc[m][n][i] * sc);
        }
      }
    }
  } else {
    float* out = (float*)Cp;
#pragma unroll
    for (int m = 0; m < 4; ++m) {
      int gr = m0 + wr * 64 + m * 16 + qq * 4;
#pragma unroll
      for (int n = 0; n < 4; ++n) {
        int gc = n0 + wc * 64 + n * 16 + r;
#pragma unroll
        for (int i = 0; i < 4; ++i) out[(size_t)(gr + i) * 1024 + gc] = acc[m][n][i];
      }
    }
  }
}

// ---------------- flash attention (shared-KV LDS, 4 waves/WG, swapped QK^T) ----------------
// R10 (unchanged this round): 4 waves share each 64-key K/V tile via double-buffered LDS
// (32 KB) staged with global_load_lds from a pre-swizzled global source; fragments read
// JIT via ds_read_b128. Grid 1024 WGs = 4/CU; bi = x*64+bh, x=0 longest; bi%8=bh%8 (XCD).
// Per-tile: QK^T (JIT kf) -> bulk vfr -> STAGE next -> softmax -> PV -> one __syncthreads.
// Swizzles: fk(row) = (row&3)|(((row>>3)&1)<<2) for K; fv(row) = row&7 for V^T.
__global__ __launch_bounds__(256) void k_attn(const u16* __restrict__ Qm,
                                              const u16* __restrict__ Km,
                                              const u16* __restrict__ VTm,
                                              u16* __restrict__ Y) {
  int bi = blockIdx.x;
  int x = bi >> 6;   // 0..15, 0 = longest q-block
  int bh = bi & 63;  // bi%8 = bh%8 -> head pinned to one XCD residue
  int b = bh >> 4, h = bh & 15;
  int qb0 = (15 - x) * 128;  // WG's first q row
  int tid = threadIdx.x, lane = tid & 63, w = tid >> 6;
  int r = lane & 15, qq = lane >> 4;
  const size_t base = (size_t)bh * (2048 * 64);
  int q0w = qb0 + w * 32;  // this wave's first q row

  __shared__ __align__(16) u16 Kt[2][64 * 64];  // [buf][key][64], slot-swizzled (fk)
  __shared__ __align__(16) u16 Vt[2][64 * 64];  // [buf][d][64 keys], slot-swizzled (fv)

  // Q fragments (B-operand): q rows m*16+r, d-slices kc*32+qq*8 (q pre-scaled by csc)
  bf16x8 qf[2][2];
#pragma unroll
  for (int m = 0; m < 2; ++m)
#pragma unroll
    for (int kc = 0; kc < 2; ++kc)
      qf[m][kc] = ld8(Qm + base + (size_t)(q0w + m * 16 + r) * 64 + kc * 32 + qq * 8);

  f32x4 acc[2][4] = {};
  float m_run[2] = {-1e30f, -1e30f};
  float l_run[2] = {0.f, 0.f};
  int ntwg = (qb0 >> 6) + 2;  // WG-uniform tile count (keys 0..qb0+127)

  // staging constants: wave w stages K rows / V^T d-rows w*16..w*16+15 (2 slabs of 8)
  int srow = lane >> 3;                        // 0..7 within a slab
  int kch0 = (lane & 7) ^ (srow & 3);          // slab c=0: fk = (srow&3)|0
  int kch1 = (lane & 7) ^ ((srow & 3) | 4);    // slab c=1: row bit3=1 -> fk bit2=1
  int vch = (lane & 7) ^ srow;                 // fv = row&7 = srow
  const u16* Kg = Km + base;
  const u16* Vg = VTm + base;

  // read-side constants
  int ar = 8 * (r >> 2) + (r & 3);                       // A-fragment row offset
  int fkl = (r & 3) | (((r >> 2) & 1) << 2);             // fk(knt+ar), knt-independent
  int ks0 = ((qq ^ fkl)) * 8, ks1 = ((qq ^ fkl) ^ 4) * 8;
  int fvl = r & 7;
  int vs0 = ((qq ^ fvl)) * 8, vs1 = ((qq ^ fvl) ^ 4) * 8;

#define STAGE(buf, j0n)                                                                 \
  do {                                                                                  \
    gll16(Kg + (size_t)((j0n) + w * 16 + srow) * 64 + kch0 * 8,                         \
          &Kt[buf][(w * 16) * 64]);                                                     \
    gll16(Kg + (size_t)((j0n) + w * 16 + 8 + srow) * 64 + kch1 * 8,                     \
          &Kt[buf][(w * 16 + 8) * 64]);                                                 \
    gll16(Vg + (size_t)(w * 16 + srow) * 2048 + (j0n) + vch * 8,                        \
          &Vt[buf][(w * 16) * 64]);                                                     \
    gll16(Vg + (size_t)(w * 16 + 8 + srow) * 2048 + (j0n) + vch * 8,                    \
          &Vt[buf][(w * 16 + 8) * 64]);                                                 \
  } while (0)

  STAGE(0, 0);
  __syncthreads();

  for (int it = 0; it < ntwg; ++it) {
    int j0 = it << 6;
    int cur = it & 1;
    bool active = (j0 <= q0w + 31);  // wave-uniform
    f32x4 s[4][2];
    bf16x8 vfr[4][2];

    if (active) {
      // S = K . Q^T with JIT kf reads from LDS
      __builtin_amdgcn_s_setprio(1);
#pragma unroll
      for (int nt = 0; nt < 4; ++nt) {
        int knt = 32 * (nt >> 1) + 4 * (nt & 1);
        const u16* kb_ = &Kt[cur][(knt + ar) * 64];
        bf16x8 k0 = ld8(kb_ + ks0);
        bf16x8 k1 = ld8(kb_ + ks1);
#pragma unroll
        for (int m = 0; m < 2; ++m) {
          f32x4 z = {};
          s[nt][m] = mfma16(k1, qf[m][1], mfma16(k0, qf[m][0], z));
        }
      }
      // bulk V^T fragment reads (consumed at PV; issued before STAGE on purpose)
#pragma unroll
      for (int n = 0; n < 4; ++n) {
        const u16* vb_ = &Vt[cur][(n * 16 + r) * 64];
        vfr[n][0] = ld8(vb_ + vs0);
        vfr[n][1] = ld8(vb_ + vs1);
      }
      __builtin_amdgcn_s_setprio(0);
    }

    // stage NEXT tile: issued after this tile's LDS reads; flies under softmax+PV
    if (it + 1 < ntwg) STAGE(cur ^ 1, j0 + 64);

    if (active) {
      // causal mask on diagonal tiles only (q pre-scaled -> no scale op)
      bool nm = (j0 + 63 > q0w);
      if (nm) {
#pragma unroll
        for (int nt = 0; nt < 4; ++nt) {
          int kb = j0 + 32 * (nt >> 1) + 4 * (nt & 1) + 8 * qq;
#pragma unroll
          for (int m = 0; m < 2; ++m) {
            int qg = q0w + m * 16 + r;
#pragma unroll
            for (int i = 0; i < 4; ++i)
              s[nt][m][i] = (kb + i <= qg) ? s[nt][m][i] : -1e30f;
          }
        }
      }

      // row max: 15 in-lane fmax + 2 shfl rounds across qq groups
      float tm[2];
#pragma unroll
      for (int m = 0; m < 2; ++m) {
        float t0 = fmaxf(fmaxf(s[0][m][0], s[0][m][1]), fmaxf(s[0][m][2], s[0][m][3]));
        float t1 = fmaxf(fmaxf(s[1][m][0], s[1][m][1]), fmaxf(s[1][m][2], s[1][m][3]));
        float t2 = fmaxf(fmaxf(s[2][m][0], s[2][m][1]), fmaxf(s[2][m][2], s[2][m][3]));
        float t3 = fmaxf(fmaxf(s[3][m][0], s[3][m][1]), fmaxf(s[3][m][2], s[3][m][3]));
        float t = fmaxf(fmaxf(t0, t1), fmaxf(t2, t3));
        t = fmaxf(t, __shfl_xor(t, 16));
        t = fmaxf(t, __shfl_xor(t, 32));
        tm[m] = t;
      }

      // rescale only if the running max grew
      int grow = (tm[0] > m_run[0]) | (tm[1] > m_run[1]);
      if (__any(grow)) {
#pragma unroll
        for (int m = 0; m < 2; ++m) {
          float mn = fmaxf(m_run[m], tm[m]);
          float corr = __builtin_amdgcn_exp2f(m_run[m] - mn);
          m_run[m] = mn;
          l_run[m] *= corr;
#pragma unroll
          for (int i = 0; i < 4; ++i) {
            float c = __shfl(corr, qq * 4 + i);
#pragma unroll
            for (int n = 0; n < 4; ++n) acc[m][n][i] *= c;
          }
        }
      }

      // P = exp2(S - m) via raw v_exp_f32; per-lane partial row sums
#pragma unroll
      for (int m = 0; m < 2; ++m) {
        float ls = 0.f;
#pragma unroll
        for (int nt = 0; nt < 4; ++nt)
#pragma unroll
          for (int i = 0; i < 4; ++i) {
            float e = __builtin_amdgcn_exp2f(s[nt][m][i] - m_run[m]);
            s[nt][m][i] = e;
            ls += e;
          }
        l_run[m] += ls;
      }

      // PV: P packs straight into A-fragments in-lane; vfr already in regs
      __builtin_amdgcn_s_setprio(1);
#pragma unroll
      for (int m = 0; m < 2; ++m) {
        bf16x8 pa0 = pack8(s[0][m], s[1][m]);  // keys qq*8+0..7
        bf16x8 pa1 = pack8(s[2][m], s[3][m]);  // keys 32+qq*8+0..7
#pragma unroll
        for (int n = 0; n < 4; ++n) acc[m][n] = mfma16(pa0, vfr[n][0], acc[m][n]);
#pragma unroll
        for (int n = 0; n < 4; ++n) acc[m][n] = mfma16(pa1, vfr[n][1], acc[m][n]);
      }
      __builtin_amdgcn_s_setprio(0);
    }

    __syncthreads();  // drains next-tile stage (already flown) + protects buf reuse
  }
#undef STAGE

  // epilogue: sum partials across qq groups, invert, redistribute to acc layout
  float li[2][4];
#pragma unroll
  for (int m = 0; m < 2; ++m) {
    float l = l_run[m];
    l += __shfl_xor(l, 16);
    l += __shfl_xor(l, 32);
    float inv = 1.0f / l;
#pragma unroll
    for (int i = 0; i < 4; ++i) li[m][i] = __shfl(inv, qq * 4 + i);
  }
#pragma unroll
  for (int m = 0; m < 2; ++m)
#pragma unroll
    for (int n = 0; n < 4; ++n)
#pragma unroll
      for (int i = 0; i < 4; ++i)
        Y[((size_t)(b * 2048 + q0w + m * 16 + qq * 4 + i)) * 1024 + h * 64 + n * 16 + r] =
            f2b(acc[m][n][i] * li[m][i]);
}

// ---------------- launch ----------------
extern "C" void kernel_launch(void* const* d_in, const int* in_sizes, int n_in,
                              void* d_out, int out_size, void* d_ws, size_t ws_size,
                              hipStream_t stream) {
  const float* x = (const float*)d_in[0];       // [4,2048,1024]
  const float* w_attn = (const float*)d_in[1];  // [1024,3072]
  const float* w_o = (const float*)d_in[2];     // [1024,1024]
  float* out = (float*)d_out;                   // [4,2048,1024]

  char* ws = (char*)d_ws;
  u16* xb = (u16*)(ws + 0);                    // [8192][1024]        16,777,216 B
  u16* watT = (u16*)(ws + 16777216);           // [3072][1024]         6,291,456 B
  u16* woT = (u16*)(ws + 23068672);            // [1024][1024]         2,097,152 B
  u16* qb = (u16*)(ws + 25165824);             // q [4][16][2048][64] 16,777,216 B
  u16* kb = (u16*)(ws + 41943040);             // k                   16,777,216 B
  u16* vb = (u16*)(ws + 58720256);             // V^T [4][16][64][2048] 16,777,216 B
  u16* yb = (u16*)(ws + 75497472);             // y [4][2048][1024]   16,777,216 B

  k_cvt<<<2048, 256, 0, stream>>>(x, xb, 8192 * 1024 / 4);
  k_tr<<<dim3(3072 / 32, 1024 / 32), dim3(32, 8), 0, stream>>>(w_attn, watT, 1024, 3072);
  k_tr<<<dim3(1024 / 32, 1024 / 32), dim3(32, 8), 0, stream>>>(w_o, woT, 1024, 1024);
  k_gemm<0><<<dim3(24, 64), 256, 0, stream>>>(xb, watT, (void*)qb);
  k_attn<<<dim3(1024), 256, 0, stream>>>(qb, kb, vb, yb);
  k_gemm<1><<<dim3(8, 64), 256, 0, stream>>>(yb, woT, (void*)out);
}

// Round 12
// 185.314 us; speedup vs baseline: 1.9086x; 1.0126x over previous
//
#include <hip/hip_runtime.h>

typedef unsigned short u16;
typedef unsigned int u32;
typedef __attribute__((ext_vector_type(8))) __bf16 bf16x8;
typedef __attribute__((ext_vector_type(4))) float f32x4;
typedef __attribute__((ext_vector_type(8))) unsigned short u16x8;
typedef __attribute__((ext_vector_type(4))) unsigned int u32x4;

typedef const __attribute__((address_space(1))) u32 gu32;
typedef __attribute__((address_space(3))) u32 lu32;

// fp32 -> bf16 round-to-nearest-even
__device__ __forceinline__ u16 f2b(float f) {
  u32 u = __builtin_bit_cast(u32, f);
  u32 r = u + 0x7fffu + ((u >> 16) & 1u);
  return (u16)(r >> 16);
}

// packed fp32 pair -> bf16 pair (RNE), lo in [15:0]
__device__ __forceinline__ u32 pk2(float lo, float hi) {
  u32 d;
  asm("v_cvt_pk_bf16_f32 %0, %1, %2" : "=v"(d) : "v"(lo), "v"(hi));
  return d;
}

// two f32x4 -> one bf16x8 (elements 0..3 from a, 4..7 from b)
__device__ __forceinline__ bf16x8 pack8(f32x4 a, f32x4 b) {
  u32x4 u;
  u[0] = pk2(a[0], a[1]);
  u[1] = pk2(a[2], a[3]);
  u[2] = pk2(b[0], b[1]);
  u[3] = pk2(b[2], b[3]);
  return __builtin_bit_cast(bf16x8, u);
}

__device__ __forceinline__ bf16x8 ld8(const u16* p) {
  return __builtin_bit_cast(bf16x8, *(const u16x8*)p);
}

__device__ __forceinline__ void gll16(const void* g, void* l) {
  __builtin_amdgcn_global_load_lds((gu32*)g, (lu32*)l, 16, 0, 0);
}

__device__ __forceinline__ f32x4 mfma16(bf16x8 a, bf16x8 b, f32x4 c) {
  return __builtin_amdgcn_mfma_f32_16x16x32_bf16(a, b, c, 0, 0, 0);
}

// ---------------- fp32 -> bf16 elementwise ----------------
__global__ void k_cvt(const float* __restrict__ in, u16* __restrict__ out, int n4) {
  int i = blockIdx.x * blockDim.x + threadIdx.x;
  int stride = gridDim.x * blockDim.x;
  for (int idx = i; idx < n4; idx += stride) {
    float4 v = ((const float4*)in)[idx];
    u32 lo = (u32)f2b(v.x) | ((u32)f2b(v.y) << 16);
    u32 hi = (u32)f2b(v.z) | ((u32)f2b(v.w) << 16);
    ((uint2*)out)[idx] = make_uint2(lo, hi);
  }
}

// ---------------- transpose+convert: in[R][C] f32 -> out[C][R] bf16 ----------------
__global__ void k_tr(const float* __restrict__ in, u16* __restrict__ out, int R, int C) {
  __shared__ u16 tile[32][33];
  int bx = blockIdx.x * 32;  // along C
  int by = blockIdx.y * 32;  // along R
  int tx = threadIdx.x, ty = threadIdx.y;  // (32, 8)
#pragma unroll
  for (int i = 0; i < 32; i += 8)
    tile[ty + i][tx] = f2b(in[(size_t)(by + ty + i) * C + bx + tx]);
  __syncthreads();
#pragma unroll
  for (int i = 0; i < 32; i += 8)
    out[(size_t)(bx + ty + i) * R + by + tx] = tile[tx][ty + i];
}

// ---------------- GEMM: A[M][1024] * B^T (B given as [N][1024]), 128x128 tile ----------------
// R11: counted-vmcnt double-buffered pipeline (2-deep prefetch, raw s_barrier, vmcnt(4)).
// R12: T2 LDS swizzle. Old fragment read As[row*32 + qq*8] had bank group
// (row&1)*16 + qq*4 -> 8 same-parity lanes per qq on the SAME 4 banks, 128B apart =
// 8-way conflict on every ds_read_b128 (6.29M SQ_LDS_BANK_CONFLICT). Fix (rule 21,
// both-sides XOR with linear gll16 dest): stage global chunk (lane&3)^((lane>>3)&3)
// (f(R)=(R>>1)&3; f(R+16)=f(R) so one formula serves both slabs), read at slot
// qq^((r>>1)&3). Now 2 lanes/bank = free (m136).
// EPI=0: scatter bf16 into q/k [B=4][H=16][T=2048][64] and V TRANSPOSED [B][H][64][T=2048].
//        q is stored PRE-SCALED by csc = 1/sqrt(64)*log2(e).
// EPI=1: fp32 out [M][1024]
template <int EPI>
__global__ __launch_bounds__(256) void k_gemm(const u16* __restrict__ A,
                                              const u16* __restrict__ B,
                                              void* __restrict__ Cp) {
  const int K = 1024;
  const int NT = 32;  // K / 32
  __shared__ __align__(16) u16 As[2][128 * 32];
  __shared__ __align__(16) u16 Bs[2][128 * 32];
  int tid = threadIdx.x;
  int lane = tid & 63, wid = tid >> 6;
  int wr = wid >> 1, wc = wid & 1;
  int m0 = blockIdx.y * 128, n0 = blockIdx.x * 128;
  int r = lane & 15, qq = lane >> 4;

  // staging: pre-swizzled global chunk so linear LDS dest yields swizzled layout
  int schunk = (lane & 3) ^ ((lane >> 3) & 3);
  const u16* Ag0 = A + (size_t)(m0 + wid * 32 + (lane >> 2)) * K + schunk * 8;
  const u16* Bg0 = B + (size_t)(n0 + wid * 32 + (lane >> 2)) * K + schunk * 8;
  int sl0 = (wid * 32) * 32;        // this wave's staging rows (0..15)
  int sl1 = (wid * 32 + 16) * 32;   // rows 16..31
  int rsw = (qq ^ ((r >> 1) & 3)) * 8;  // read-side swizzled slot (lane-constant)

#define GSTAGE(buf, k0)                          \
  do {                                           \
    gll16(Ag0 + (k0), &As[buf][sl0]);            \
    gll16(Ag0 + 16 * K + (k0), &As[buf][sl1]);   \
    gll16(Bg0 + (k0), &Bs[buf][sl0]);            \
    gll16(Bg0 + 16 * K + (k0), &Bs[buf][sl1]);   \
  } while (0)

  f32x4 acc[4][4] = {};

  GSTAGE(0, 0);
  GSTAGE(1, 32);

  for (int kt = 0; kt < NT; ++kt) {
    int cur = kt & 1;
    if (kt + 1 < NT)
      asm volatile("s_waitcnt vmcnt(4)" ::: "memory");  // kt landed, kt+1 in flight
    else
      asm volatile("s_waitcnt vmcnt(0)" ::: "memory");  // final tile
    __builtin_amdgcn_s_barrier();  // raw: no vmcnt drain

    bf16x8 af[4], bfr[4];
#pragma unroll
    for (int m = 0; m < 4; ++m)
      af[m] = ld8(&As[cur][(wr * 64 + m * 16 + r) * 32 + rsw]);
#pragma unroll
    for (int n = 0; n < 4; ++n)
      bfr[n] = ld8(&Bs[cur][(wc * 64 + n * 16 + r) * 32 + rsw]);
    asm volatile("s_waitcnt lgkmcnt(0)" ::: "memory");
    __builtin_amdgcn_sched_barrier(0);
    __builtin_amdgcn_s_barrier();  // all waves done reading buf cur

    if (kt + 2 < NT) GSTAGE(cur, (kt + 2) * 32);  // overwrite cur; flies under MFMA

#pragma unroll
    for (int m = 0; m < 4; ++m)
#pragma unroll
      for (int n = 0; n < 4; ++n) acc[m][n] = mfma16(af[m], bfr[n], acc[m][n]);
  }
#undef GSTAGE

  if constexpr (EPI == 0) {
    u16* qkv = (u16*)Cp;
#pragma unroll
    for (int m = 0; m < 4; ++m) {
      int gr = m0 + wr * 64 + m * 16 + qq * 4;
      int b = gr >> 11, t0 = gr & 2047;
#pragma unroll
      for (int n = 0; n < 4; ++n) {
        int gc = n0 + wc * 64 + n * 16 + r;
        int which = gc >> 10, rem = gc & 1023;
        int hh = rem >> 6, d = rem & 63;
        if (which == 2) {
          // V^T: [(b*16+hh)*64 + d][2048] ; acc i-index is t (contiguous) -> one 8B store
          u16* dst = qkv + (size_t)2 * 8388608u +
                     ((size_t)((b * 16 + hh) * 64 + d)) * 2048 + t0;
          u32 p0 = pk2(acc[m][n][0], acc[m][n][1]);
          u32 p1 = pk2(acc[m][n][2], acc[m][n][3]);
          *(uint2*)dst = make_uint2(p0, p1);
        } else {
          // q (which==0) pre-scaled by csc; k (which==1) raw
          float sc = (which == 0) ? 0.18033688011112042f : 1.0f;
          u16* dst = qkv + (size_t)which * 8388608u +
                     ((size_t)((b * 16 + hh) * 2048 + t0)) * 64 + d;
#pragma unroll
          for (int i = 0; i < 4; ++i) dst[(size_t)i * 64] = f2b(acc[m][n][i] * sc);
        }
      }
    }
  } else {
    float* out = (float*)Cp;
#pragma unroll
    for (int m = 0; m < 4; ++m) {
      int gr = m0 + wr * 64 + m * 16 + qq * 4;
#pragma unroll
      for (int n = 0; n < 4; ++n) {
        int gc = n0 + wc * 64 + n * 16 + r;
#pragma unroll
        for (int i = 0; i < 4; ++i) out[(size_t)(gr + i) * 1024 + gc] = acc[m][n][i];
      }
    }
  }
}

// ---------------- flash attention (pair-fused, shared-KV LDS, 4 waves/WG) ----------------
// R12: PAIR FUSION. R11's counters showed avg occupancy 18.4% vs 16 waves/CU at t=0:
// per-CU WG tile counts {32,24,16,8} -> short WGs drain and the dispatch tail runs one
// 4-wave WG per CU. Fuse q-blocks (15-p, p) into one WG run SEQUENTIALLY: every WG does
// exactly (2(15-p)+2)+(2p+2) = 34 tiles -> all WGs finish together, occupancy flat.
// Grid 512 WGs = 8 pairs x 64 heads; bi = p*64+bh keeps bi%8 = bh%8 (XCD pinning).
// Phase boundary race-free: final tile's __syncthreads precedes next phase's STAGE
// overwrite; epilogue touches only global memory.
// Per-tile schedule and swizzles unchanged from R10/R11 (bank conflicts already 0).
__global__ __launch_bounds__(256) void k_attn(const u16* __restrict__ Qm,
                                              const u16* __restrict__ Km,
                                              const u16* __restrict__ VTm,
                                              u16* __restrict__ Y) {
  int bi = blockIdx.x;
  int p = bi >> 6;   // 0..7 pair id
  int bh = bi & 63;  // bi%8 = bh%8 -> head pinned to one XCD residue
  int b = bh >> 4, h = bh & 15;
  int tid = threadIdx.x, lane = tid & 63, w = tid >> 6;
  int r = lane & 15, qq = lane >> 4;
  const size_t base = (size_t)bh * (2048 * 64);

  __shared__ __align__(16) u16 Kt[2][64 * 64];  // [buf][key][64], slot-swizzled (fk)
  __shared__ __align__(16) u16 Vt[2][64 * 64];  // [buf][d][64 keys], slot-swizzled (fv)

  // staging constants: wave w stages K rows / V^T d-rows w*16..w*16+15 (2 slabs of 8)
  int srow = lane >> 3;                        // 0..7 within a slab
  int kch0 = (lane & 7) ^ (srow & 3);          // slab c=0: fk = (srow&3)|0
  int kch1 = (lane & 7) ^ ((srow & 3) | 4);    // slab c=1: row bit3=1 -> fk bit2=1
  int vch = (lane & 7) ^ srow;                 // fv = row&7 = srow
  const u16* Kg = Km + base;
  const u16* Vg = VTm + base;

  // read-side constants
  int ar = 8 * (r >> 2) + (r & 3);                       // A-fragment row offset
  int fkl = (r & 3) | (((r >> 2) & 1) << 2);             // fk(knt+ar), knt-independent
  int ks0 = ((qq ^ fkl)) * 8, ks1 = ((qq ^ fkl) ^ 4) * 8;
  int fvl = r & 7;
  int vs0 = ((qq ^ fvl)) * 8, vs1 = ((qq ^ fvl) ^ 4) * 8;

#define STAGE(buf, j0n)                                                                 \
  do {                                                                                  \
    gll16(Kg + (size_t)((j0n) + w * 16 + srow) * 64 + kch0 * 8,                         \
          &Kt[buf][(w * 16) * 64]);                                                     \
    gll16(Kg + (size_t)((j0n) + w * 16 + 8 + srow) * 64 + kch1 * 8,                     \
          &Kt[buf][(w * 16 + 8) * 64]);                                                 \
    gll16(Vg + (size_t)(w * 16 + srow) * 2048 + (j0n) + vch * 8,                        \
          &Vt[buf][(w * 16) * 64]);                                                     \
    gll16(Vg + (size_t)(w * 16 + 8 + srow) * 2048 + (j0n) + vch * 8,                    \
          &Vt[buf][(w * 16 + 8) * 64]);                                                 \
  } while (0)

  for (int ph = 0; ph < 2; ++ph) {
    int qb = (ph == 0) ? (15 - p) : p;  // long block first (order arbitrary)
    int qb0 = qb * 128;
    int q0w = qb0 + w * 32;  // this wave's first q row

    // Q fragments (B-operand): q rows m*16+r, d-slices kc*32+qq*8 (q pre-scaled by csc)
    bf16x8 qf[2][2];
#pragma unroll
    for (int m = 0; m < 2; ++m)
#pragma unroll
      for (int kc = 0; kc < 2; ++kc)
        qf[m][kc] = ld8(Qm + base + (size_t)(q0w + m * 16 + r) * 64 + kc * 32 + qq * 8);

    f32x4 acc[2][4] = {};
    float m_run[2] = {-1e30f, -1e30f};
    float l_run[2] = {0.f, 0.f};
    int ntwg = (qb0 >> 6) + 2;  // WG-uniform tile count (keys 0..qb0+127)

    STAGE(0, 0);
    __syncthreads();

    for (int it = 0; it < ntwg; ++it) {
      int j0 = it << 6;
      int cur = it & 1;
      bool active = (j0 <= q0w + 31);  // wave-uniform
      f32x4 s[4][2];
      bf16x8 vfr[4][2];

      if (active) {
        // S = K . Q^T with JIT kf reads from LDS
        __builtin_amdgcn_s_setprio(1);
#pragma unroll
        for (int nt = 0; nt < 4; ++nt) {
          int knt = 32 * (nt >> 1) + 4 * (nt & 1);
          const u16* kb_ = &Kt[cur][(knt + ar) * 64];
          bf16x8 k0 = ld8(kb_ + ks0);
          bf16x8 k1 = ld8(kb_ + ks1);
#pragma unroll
          for (int m = 0; m < 2; ++m) {
            f32x4 z = {};
            s[nt][m] = mfma16(k1, qf[m][1], mfma16(k0, qf[m][0], z));
          }
        }
        // bulk V^T fragment reads (consumed at PV; issued before STAGE on purpose)
#pragma unroll
        for (int n = 0; n < 4; ++n) {
          const u16* vb_ = &Vt[cur][(n * 16 + r) * 64];
          vfr[n][0] = ld8(vb_ + vs0);
          vfr[n][1] = ld8(vb_ + vs1);
        }
        __builtin_amdgcn_s_setprio(0);
      }

      // stage NEXT tile: issued after this tile's LDS reads; flies under softmax+PV
      if (it + 1 < ntwg) STAGE(cur ^ 1, j0 + 64);

      if (active) {
        // causal mask on diagonal tiles only (q pre-scaled -> no scale op)
        bool nm = (j0 + 63 > q0w);
        if (nm) {
#pragma unroll
          for (int nt = 0; nt < 4; ++nt) {
            int kb = j0 + 32 * (nt >> 1) + 4 * (nt & 1) + 8 * qq;
#pragma unroll
            for (int m = 0; m < 2; ++m) {
              int qg = q0w + m * 16 + r;
#pragma unroll
              for (int i = 0; i < 4; ++i)
                s[nt][m][i] = (kb + i <= qg) ? s[nt][m][i] : -1e30f;
            }
          }
        }

        // row max: 15 in-lane fmax + 2 shfl rounds across qq groups
        float tm[2];
#pragma unroll
        for (int m = 0; m < 2; ++m) {
          float t0 = fmaxf(fmaxf(s[0][m][0], s[0][m][1]), fmaxf(s[0][m][2], s[0][m][3]));
          float t1 = fmaxf(fmaxf(s[1][m][0], s[1][m][1]), fmaxf(s[1][m][2], s[1][m][3]));
          float t2 = fmaxf(fmaxf(s[2][m][0], s[2][m][1]), fmaxf(s[2][m][2], s[2][m][3]));
          float t3 = fmaxf(fmaxf(s[3][m][0], s[3][m][1]), fmaxf(s[3][m][2], s[3][m][3]));
          float t = fmaxf(fmaxf(t0, t1), fmaxf(t2, t3));
          t = fmaxf(t, __shfl_xor(t, 16));
          t = fmaxf(t, __shfl_xor(t, 32));
          tm[m] = t;
        }

        // rescale only if the running max grew
        int grow = (tm[0] > m_run[0]) | (tm[1] > m_run[1]);
        if (__any(grow)) {
#pragma unroll
          for (int m = 0; m < 2; ++m) {
            float mn = fmaxf(m_run[m], tm[m]);
            float corr = __builtin_amdgcn_exp2f(m_run[m] - mn);
            m_run[m] = mn;
            l_run[m] *= corr;
#pragma unroll
            for (int i = 0; i < 4; ++i) {
              float c = __shfl(corr, qq * 4 + i);
#pragma unroll
              for (int n = 0; n < 4; ++n) acc[m][n][i] *= c;
            }
          }
        }

        // P = exp2(S - m) via raw v_exp_f32; per-lane partial row sums
#pragma unroll
        for (int m = 0; m < 2; ++m) {
          float ls = 0.f;
#pragma unroll
          for (int nt = 0; nt < 4; ++nt)
#pragma unroll
            for (int i = 0; i < 4; ++i) {
              float e = __builtin_amdgcn_exp2f(s[nt][m][i] - m_run[m]);
              s[nt][m][i] = e;
              ls += e;
            }
          l_run[m] += ls;
        }

        // PV: P packs straight into A-fragments in-lane; vfr already in regs
        __builtin_amdgcn_s_setprio(1);
#pragma unroll
        for (int m = 0; m < 2; ++m) {
          bf16x8 pa0 = pack8(s[0][m], s[1][m]);  // keys qq*8+0..7
          bf16x8 pa1 = pack8(s[2][m], s[3][m]);  // keys 32+qq*8+0..7
#pragma unroll
          for (int n = 0; n < 4; ++n) acc[m][n] = mfma16(pa0, vfr[n][0], acc[m][n]);
#pragma unroll
          for (int n = 0; n < 4; ++n) acc[m][n] = mfma16(pa1, vfr[n][1], acc[m][n]);
        }
        __builtin_amdgcn_s_setprio(0);
      }

      __syncthreads();  // drains next-tile stage (already flown) + protects buf reuse
    }

    // epilogue: sum partials across qq groups, invert, redistribute to acc layout
    float li[2][4];
#pragma unroll
    for (int m = 0; m < 2; ++m) {
      float l = l_run[m];
      l += __shfl_xor(l, 16);
      l += __shfl_xor(l, 32);
      float inv = 1.0f / l;
#pragma unroll
      for (int i = 0; i < 4; ++i) li[m][i] = __shfl(inv, qq * 4 + i);
    }
#pragma unroll
    for (int m = 0; m < 2; ++m)
#pragma unroll
      for (int n = 0; n < 4; ++n)
#pragma unroll
        for (int i = 0; i < 4; ++i)
          Y[((size_t)(b * 2048 + q0w + m * 16 + qq * 4 + i)) * 1024 + h * 64 + n * 16 +
            r] = f2b(acc[m][n][i] * li[m][i]);
  }
#undef STAGE
}

// ---------------- launch ----------------
extern "C" void kernel_launch(void* const* d_in, const int* in_sizes, int n_in,
                              void* d_out, int out_size, void* d_ws, size_t ws_size,
                              hipStream_t stream) {
  const float* x = (const float*)d_in[0];       // [4,2048,1024]
  const float* w_attn = (const float*)d_in[1];  // [1024,3072]
  const float* w_o = (const float*)d_in[2];     // [1024,1024]
  float* out = (float*)d_out;                   // [4,2048,1024]

  char* ws = (char*)d_ws;
  u16* xb = (u16*)(ws + 0);                    // [8192][1024]        16,777,216 B
  u16* watT = (u16*)(ws + 16777216);           // [3072][1024]         6,291,456 B
  u16* woT = (u16*)(ws + 23068672);            // [1024][1024]         2,097,152 B
  u16* qb = (u16*)(ws + 25165824);             // q [4][16][2048][64] 16,777,216 B
  u16* kb = (u16*)(ws + 41943040);             // k                   16,777,216 B
  u16* vb = (u16*)(ws + 58720256);             // V^T [4][16][64][2048] 16,777,216 B
  u16* yb = (u16*)(ws + 75497472);             // y [4][2048][1024]   16,777,216 B

  k_cvt<<<2048, 256, 0, stream>>>(x, xb, 8192 * 1024 / 4);
  k_tr<<<dim3(3072 / 32, 1024 / 32), dim3(32, 8), 0, stream>>>(w_attn, watT, 1024, 3072);
  k_tr<<<dim3(1024 / 32, 1024 / 32), dim3(32, 8), 0, stream>>>(w_o, woT, 1024, 1024);
  k_gemm<0><<<dim3(24, 64), 256, 0, stream>>>(xb, watT, (void*)qb);
  k_attn<<<dim3(512), 256, 0, stream>>>(qb, kb, vb, yb);
  k_gemm<1><<<dim3(8, 64), 256, 0, stream>>>(yb, woT, (void*)out);
}

// Round 13
// 184.092 us; speedup vs baseline: 1.9212x; 1.0066x over previous
//
#include <hip/hip_runtime.h>

typedef unsigned short u16;
typedef unsigned int u32;
typedef __attribute__((ext_vector_type(8))) __bf16 bf16x8;
typedef __attribute__((ext_vector_type(4))) float f32x4;
typedef __attribute__((ext_vector_type(8))) unsigned short u16x8;
typedef __attribute__((ext_vector_type(4))) unsigned int u32x4;

typedef const __attribute__((address_space(1))) u32 gu32;
typedef __attribute__((address_space(3))) u32 lu32;

// fp32 -> bf16 round-to-nearest-even
__device__ __forceinline__ u16 f2b(float f) {
  u32 u = __builtin_bit_cast(u32, f);
  u32 r = u + 0x7fffu + ((u >> 16) & 1u);
  return (u16)(r >> 16);
}

// packed fp32 pair -> bf16 pair (RNE), lo in [15:0]
__device__ __forceinline__ u32 pk2(float lo, float hi) {
  u32 d;
  asm("v_cvt_pk_bf16_f32 %0, %1, %2" : "=v"(d) : "v"(lo), "v"(hi));
  return d;
}

// two f32x4 -> one bf16x8 (elements 0..3 from a, 4..7 from b)
__device__ __forceinline__ bf16x8 pack8(f32x4 a, f32x4 b) {
  u32x4 u;
  u[0] = pk2(a[0], a[1]);
  u[1] = pk2(a[2], a[3]);
  u[2] = pk2(b[0], b[1]);
  u[3] = pk2(b[2], b[3]);
  return __builtin_bit_cast(bf16x8, u);
}

__device__ __forceinline__ bf16x8 ld8(const u16* p) {
  return __builtin_bit_cast(bf16x8, *(const u16x8*)p);
}

__device__ __forceinline__ void gll16(const void* g, void* l) {
  __builtin_amdgcn_global_load_lds((gu32*)g, (lu32*)l, 16, 0, 0);
}

__device__ __forceinline__ f32x4 mfma16(bf16x8 a, bf16x8 b, f32x4 c) {
  return __builtin_amdgcn_mfma_f32_16x16x32_bf16(a, b, c, 0, 0, 0);
}

// ---------------- fp32 -> bf16 elementwise ----------------
__global__ void k_cvt(const float* __restrict__ in, u16* __restrict__ out, int n4) {
  int i = blockIdx.x * blockDim.x + threadIdx.x;
  int stride = gridDim.x * blockDim.x;
  for (int idx = i; idx < n4; idx += stride) {
    float4 v = ((const float4*)in)[idx];
    u32 lo = (u32)f2b(v.x) | ((u32)f2b(v.y) << 16);
    u32 hi = (u32)f2b(v.z) | ((u32)f2b(v.w) << 16);
    ((uint2*)out)[idx] = make_uint2(lo, hi);
  }
}

// ---------------- transpose+convert: in[R][C] f32 -> out[C][R] bf16 ----------------
__global__ void k_tr(const float* __restrict__ in, u16* __restrict__ out, int R, int C) {
  __shared__ u16 tile[32][33];
  int bx = blockIdx.x * 32;  // along C
  int by = blockIdx.y * 32;  // along R
  int tx = threadIdx.x, ty = threadIdx.y;  // (32, 8)
#pragma unroll
  for (int i = 0; i < 32; i += 8)
    tile[ty + i][tx] = f2b(in[(size_t)(by + ty + i) * C + bx + tx]);
  __syncthreads();
#pragma unroll
  for (int i = 0; i < 32; i += 8)
    out[(size_t)(bx + ty + i) * R + by + tx] = tile[tx][ty + i];
}

// ---------------- GEMM: A[M][1024] * B^T (B given as [N][1024]), 128x128 tile ----------------
// R11: counted-vmcnt double-buffered pipeline (2-deep prefetch, raw s_barrier, vmcnt(4)).
// R12: T2 LDS swizzle (stage chunk (lane&3)^((lane>>3)&3), read slot qq^((r>>1)&3)).
// EPI=0: scatter bf16 into q/k [B=4][H=16][T=2048][64] and V TRANSPOSED [B][H][64][T=2048].
//        q is stored PRE-SCALED by csc = 1/sqrt(64)*log2(e).
// EPI=1: fp32 out [M][1024]
template <int EPI>
__global__ __launch_bounds__(256) void k_gemm(const u16* __restrict__ A,
                                              const u16* __restrict__ B,
                                              void* __restrict__ Cp) {
  const int K = 1024;
  const int NT = 32;  // K / 32
  __shared__ __align__(16) u16 As[2][128 * 32];
  __shared__ __align__(16) u16 Bs[2][128 * 32];
  int tid = threadIdx.x;
  int lane = tid & 63, wid = tid >> 6;
  int wr = wid >> 1, wc = wid & 1;
  int m0 = blockIdx.y * 128, n0 = blockIdx.x * 128;
  int r = lane & 15, qq = lane >> 4;

  // staging: pre-swizzled global chunk so linear LDS dest yields swizzled layout
  int schunk = (lane & 3) ^ ((lane >> 3) & 3);
  const u16* Ag0 = A + (size_t)(m0 + wid * 32 + (lane >> 2)) * K + schunk * 8;
  const u16* Bg0 = B + (size_t)(n0 + wid * 32 + (lane >> 2)) * K + schunk * 8;
  int sl0 = (wid * 32) * 32;        // this wave's staging rows (0..15)
  int sl1 = (wid * 32 + 16) * 32;   // rows 16..31
  int rsw = (qq ^ ((r >> 1) & 3)) * 8;  // read-side swizzled slot (lane-constant)

#define GSTAGE(buf, k0)                          \
  do {                                           \
    gll16(Ag0 + (k0), &As[buf][sl0]);            \
    gll16(Ag0 + 16 * K + (k0), &As[buf][sl1]);   \
    gll16(Bg0 + (k0), &Bs[buf][sl0]);            \
    gll16(Bg0 + 16 * K + (k0), &Bs[buf][sl1]);   \
  } while (0)

  f32x4 acc[4][4] = {};

  GSTAGE(0, 0);
  GSTAGE(1, 32);

  for (int kt = 0; kt < NT; ++kt) {
    int cur = kt & 1;
    if (kt + 1 < NT)
      asm volatile("s_waitcnt vmcnt(4)" ::: "memory");  // kt landed, kt+1 in flight
    else
      asm volatile("s_waitcnt vmcnt(0)" ::: "memory");  // final tile
    __builtin_amdgcn_s_barrier();  // raw: no vmcnt drain

    bf16x8 af[4], bfr[4];
#pragma unroll
    for (int m = 0; m < 4; ++m)
      af[m] = ld8(&As[cur][(wr * 64 + m * 16 + r) * 32 + rsw]);
#pragma unroll
    for (int n = 0; n < 4; ++n)
      bfr[n] = ld8(&Bs[cur][(wc * 64 + n * 16 + r) * 32 + rsw]);
    asm volatile("s_waitcnt lgkmcnt(0)" ::: "memory");
    __builtin_amdgcn_sched_barrier(0);
    __builtin_amdgcn_s_barrier();  // all waves done reading buf cur

    if (kt + 2 < NT) GSTAGE(cur, (kt + 2) * 32);  // overwrite cur; flies under MFMA

#pragma unroll
    for (int m = 0; m < 4; ++m)
#pragma unroll
      for (int n = 0; n < 4; ++n) acc[m][n] = mfma16(af[m], bfr[n], acc[m][n]);
  }
#undef GSTAGE

  if constexpr (EPI == 0) {
    u16* qkv = (u16*)Cp;
#pragma unroll
    for (int m = 0; m < 4; ++m) {
      int gr = m0 + wr * 64 + m * 16 + qq * 4;
      int b = gr >> 11, t0 = gr & 2047;
#pragma unroll
      for (int n = 0; n < 4; ++n) {
        int gc = n0 + wc * 64 + n * 16 + r;
        int which = gc >> 10, rem = gc & 1023;
        int hh = rem >> 6, d = rem & 63;
        if (which == 2) {
          // V^T: [(b*16+hh)*64 + d][2048] ; acc i-index is t (contiguous) -> one 8B store
          u16* dst = qkv + (size_t)2 * 8388608u +
                     ((size_t)((b * 16 + hh) * 64 + d)) * 2048 + t0;
          u32 p0 = pk2(acc[m][n][0], acc[m][n][1]);
          u32 p1 = pk2(acc[m][n][2], acc[m][n][3]);
          *(uint2*)dst = make_uint2(p0, p1);
        } else {
          // q (which==0) pre-scaled by csc; k (which==1) raw
          float sc = (which == 0) ? 0.18033688011112042f : 1.0f;
          u16* dst = qkv + (size_t)which * 8388608u +
                     ((size_t)((b * 16 + hh) * 2048 + t0)) * 64 + d;
#pragma unroll
          for (int i = 0; i < 4; ++i) dst[(size_t)i * 64] = f2b(acc[m][n][i] * sc);
        }
      }
    }
  } else {
    float* out = (float*)Cp;
#pragma unroll
    for (int m = 0; m < 4; ++m) {
      int gr = m0 + wr * 64 + m * 16 + qq * 4;
#pragma unroll
      for (int n = 0; n < 4; ++n) {
        int gc = n0 + wc * 64 + n * 16 + r;
#pragma unroll
        for (int i = 0; i < 4; ++i) out[(size_t)(gr + i) * 1024 + gc] = acc[m][n][i];
      }
    }
  }
}

// ---------------- flash attention (in-WG split-KV x2, 8 waves, pair-fused) ----------------
// R13: R11/R12 showed the limiter is the ~34-tile serial critical path with only 2
// waves/SIMD to hide per-tile latency. New geometry: WG = 512 thr = 8 waves over ONE
// 128-row q-block; group A (waves 0-3) computes EVEN 64-key tiles, group B (waves 4-7)
// ODD tiles, each with private online (m,l,acc). Pair-fused (15-p, p) -> every WG runs
// exactly 17 pair-iterations + 2 merges. Grid 512 WGs = exactly 2 WGs/CU (64 KB LDS) =
// 4 waves/SIMD resident throughout: critical path HALVED, TLP DOUBLED.
// LDS: Kt/Vt[parity][group] (4 x 8KB each of K and V) -> stage pair t2+1 while both
// groups compute pair t2 (same counted-drain schedule as R10-12).
// Merge (exact flash combine) is LANE-ALIGNED: wave w and w+4 hold identical (q,d)
// assignments, so B dumps raw acc+m+l to LDS (stride 17/5 floats -> conflict-free
// scalar ops), one barrier, A rescales and writes Y. ntw==0-tile group-B waves store
// m=-1e30, l=0 -> merge factor exactly 0.
__global__ __launch_bounds__(512) void k_attn(const u16* __restrict__ Qm,
                                              const u16* __restrict__ Km,
                                              const u16* __restrict__ VTm,
                                              u16* __restrict__ Y) {
  int bi = blockIdx.x;
  int p = bi >> 6;   // 0..7 pair id
  int bh = bi & 63;  // bi%8 = bh%8 -> head pinned to one XCD residue
  int b = bh >> 4, h = bh & 15;
  int tid = threadIdx.x, lane = tid & 63, w = tid >> 6;
  int g = w >> 2, wl = w & 3;  // KV-split group, wave-in-group
  int r = lane & 15, qq = lane >> 4;
  const size_t base = (size_t)bh * (2048 * 64);

  __shared__ __align__(16) u16 Kt[2][2][64 * 64];  // [parity][group][key][64], fk-swizzled
  __shared__ __align__(16) u16 Vt[2][2][64 * 64];  // [parity][group][d][64 keys], fv-swizzled

  // staging constants: wave wl stages rows wl*16..wl*16+15 of its GROUP's tile
  int srow = lane >> 3;                      // 0..7 within a slab
  int kch0 = (lane & 7) ^ (srow & 3);        // slab c=0: fk = (srow&3)|0
  int kch1 = (lane & 7) ^ ((srow & 3) | 4);  // slab c=1: row bit3=1 -> fk bit2=1
  int vch = (lane & 7) ^ srow;               // fv = row&7 = srow
  const u16* Kg = Km + base;
  const u16* Vg = VTm + base;

  // read-side constants
  int ar = 8 * (r >> 2) + (r & 3);            // A-fragment row offset
  int fkl = (r & 3) | (((r >> 2) & 1) << 2);  // fk(knt+ar), knt-independent
  int ks0 = ((qq ^ fkl)) * 8, ks1 = ((qq ^ fkl) ^ 4) * 8;
  int fvl = r & 7;
  int vs0 = ((qq ^ fvl)) * 8, vs1 = ((qq ^ fvl) ^ 4) * 8;

#define STAGE(par, j0n)                                                                 \
  do {                                                                                  \
    gll16(Kg + (size_t)((j0n) + wl * 16 + srow) * 64 + kch0 * 8,                        \
          &Kt[par][g][(wl * 16) * 64]);                                                 \
    gll16(Kg + (size_t)((j0n) + wl * 16 + 8 + srow) * 64 + kch1 * 8,                    \
          &Kt[par][g][(wl * 16 + 8) * 64]);                                             \
    gll16(Vg + (size_t)(wl * 16 + srow) * 2048 + (j0n) + vch * 8,                       \
          &Vt[par][g][(wl * 16) * 64]);                                                 \
    gll16(Vg + (size_t)(wl * 16 + 8 + srow) * 2048 + (j0n) + vch * 8,                   \
          &Vt[par][g][(wl * 16 + 8) * 64]);                                             \
  } while (0)

  for (int ph = 0; ph < 2; ++ph) {
    int qb = (ph == 0) ? (15 - p) : p;
    int qb0 = qb * 128;
    int q0w = qb0 + wl * 32;  // this wave's first q row

    // Q fragments (B-operand): q rows m*16+r, d-slices kc*32+qq*8 (q pre-scaled by csc)
    bf16x8 qf[2][2];
#pragma unroll
    for (int m = 0; m < 2; ++m)
#pragma unroll
      for (int kc = 0; kc < 2; ++kc)
        qf[m][kc] = ld8(Qm + base + (size_t)(q0w + m * 16 + r) * 64 + kc * 32 + qq * 8);

    f32x4 acc[2][4] = {};
    float m_run[2] = {-1e30f, -1e30f};
    float l_run[2] = {0.f, 0.f};
    int npairs = qb + 1;  // tile pairs (2qb+2 tiles split A=even B=odd)

    STAGE(0, g << 6);  // pair 0: group g's tile at j0 = g*64
    __syncthreads();

    for (int t2 = 0; t2 < npairs; ++t2) {
      int j0 = (t2 << 7) + (g << 6);  // this group's tile
      int cur = t2 & 1;
      bool active = (j0 <= q0w + 31);  // wave-uniform
      f32x4 s[4][2];
      bf16x8 vfr[4][2];

      if (active) {
        // S = K . Q^T with JIT kf reads from LDS
        __builtin_amdgcn_s_setprio(1);
#pragma unroll
        for (int nt = 0; nt < 4; ++nt) {
          int knt = 32 * (nt >> 1) + 4 * (nt & 1);
          const u16* kb_ = &Kt[cur][g][(knt + ar) * 64];
          bf16x8 k0 = ld8(kb_ + ks0);
          bf16x8 k1 = ld8(kb_ + ks1);
#pragma unroll
          for (int m = 0; m < 2; ++m) {
            f32x4 z = {};
            s[nt][m] = mfma16(k1, qf[m][1], mfma16(k0, qf[m][0], z));
          }
        }
        // bulk V^T fragment reads (consumed at PV; issued before STAGE on purpose)
#pragma unroll
        for (int n = 0; n < 4; ++n) {
          const u16* vb_ = &Vt[cur][g][(n * 16 + r) * 64];
          vfr[n][0] = ld8(vb_ + vs0);
          vfr[n][1] = ld8(vb_ + vs1);
        }
        __builtin_amdgcn_s_setprio(0);
      }

      // stage NEXT pair: issued after this tile's LDS reads; flies under softmax+PV
      if (t2 + 1 < npairs) STAGE((t2 + 1) & 1, ((t2 + 1) << 7) + (g << 6));

      if (active) {
        // causal mask on diagonal tiles only (q pre-scaled -> no scale op)
        bool nm = (j0 + 63 > q0w);
        if (nm) {
#pragma unroll
          for (int nt = 0; nt < 4; ++nt) {
            int kb = j0 + 32 * (nt >> 1) + 4 * (nt & 1) + 8 * qq;
#pragma unroll
            for (int m = 0; m < 2; ++m) {
              int qg = q0w + m * 16 + r;
#pragma unroll
              for (int i = 0; i < 4; ++i)
                s[nt][m][i] = (kb + i <= qg) ? s[nt][m][i] : -1e30f;
            }
          }
        }

        // row max: 15 in-lane fmax + 2 shfl rounds across qq groups
        float tm[2];
#pragma unroll
        for (int m = 0; m < 2; ++m) {
          float t0 = fmaxf(fmaxf(s[0][m][0], s[0][m][1]), fmaxf(s[0][m][2], s[0][m][3]));
          float t1 = fmaxf(fmaxf(s[1][m][0], s[1][m][1]), fmaxf(s[1][m][2], s[1][m][3]));
          float t2f = fmaxf(fmaxf(s[2][m][0], s[2][m][1]), fmaxf(s[2][m][2], s[2][m][3]));
          float t3 = fmaxf(fmaxf(s[3][m][0], s[3][m][1]), fmaxf(s[3][m][2], s[3][m][3]));
          float t = fmaxf(fmaxf(t0, t1), fmaxf(t2f, t3));
          t = fmaxf(t, __shfl_xor(t, 16));
          t = fmaxf(t, __shfl_xor(t, 32));
          tm[m] = t;
        }

        // rescale only if the running max grew
        int grow = (tm[0] > m_run[0]) | (tm[1] > m_run[1]);
        if (__any(grow)) {
#pragma unroll
          for (int m = 0; m < 2; ++m) {
            float mn = fmaxf(m_run[m], tm[m]);
            float corr = __builtin_amdgcn_exp2f(m_run[m] - mn);
            m_run[m] = mn;
            l_run[m] *= corr;
#pragma unroll
            for (int i = 0; i < 4; ++i) {
              float c = __shfl(corr, qq * 4 + i);
#pragma unroll
              for (int n = 0; n < 4; ++n) acc[m][n][i] *= c;
            }
          }
        }

        // P = exp2(S - m) via raw v_exp_f32; per-lane partial row sums
#pragma unroll
        for (int m = 0; m < 2; ++m) {
          float ls = 0.f;
#pragma unroll
          for (int nt = 0; nt < 4; ++nt)
#pragma unroll
            for (int i = 0; i < 4; ++i) {
              float e = __builtin_amdgcn_exp2f(s[nt][m][i] - m_run[m]);
              s[nt][m][i] = e;
              ls += e;
            }
          l_run[m] += ls;
        }

        // PV: P packs straight into A-fragments in-lane; vfr already in regs
        __builtin_amdgcn_s_setprio(1);
#pragma unroll
        for (int m = 0; m < 2; ++m) {
          bf16x8 pa0 = pack8(s[0][m], s[1][m]);  // keys qq*8+0..7
          bf16x8 pa1 = pack8(s[2][m], s[3][m]);  // keys 32+qq*8+0..7
#pragma unroll
          for (int n = 0; n < 4; ++n) acc[m][n] = mfma16(pa0, vfr[n][0], acc[m][n]);
#pragma unroll
          for (int n = 0; n < 4; ++n) acc[m][n] = mfma16(pa1, vfr[n][1], acc[m][n]);
        }
        __builtin_amdgcn_s_setprio(0);
      }

      __syncthreads();  // drains next-pair stage + protects buffer reuse
    }

    // per-wave: reduce row-sum partials across qq groups
    float lfin[2];
#pragma unroll
    for (int m = 0; m < 2; ++m) {
      float l = l_run[m];
      l += __shfl_xor(l, 16);
      l += __shfl_xor(l, 32);
      lfin[m] = l;
    }

    // merge staging in (reused) Kt/Vt: m=0 half in Kt, m=1 half in Vt; strides 17/5
    // floats keep scalar LDS ops conflict-free. Lane-aligned: wave wl <-> wave wl+4.
    float* mgK = (float*)&Kt[0][0][0];  // acc m=0 (16 floats/lane) + ml (4 floats/lane)
    float* mgV = (float*)&Vt[0][0][0];  // acc m=1
    int offA = wl * 1104 + lane * 17;
    int offM = 4608 + wl * 320 + lane * 5;
    if (g == 1) {
#pragma unroll
      for (int n = 0; n < 4; ++n)
#pragma unroll
        for (int i = 0; i < 4; ++i) {
          mgK[offA + n * 4 + i] = acc[0][n][i];
          mgV[offA + n * 4 + i] = acc[1][n][i];
        }
      mgK[offM + 0] = m_run[0];
      mgK[offM + 1] = m_run[1];
      mgK[offM + 2] = lfin[0];
      mgK[offM + 3] = lfin[1];
    }
    __syncthreads();

    if (g == 0) {
      // exact flash combine: m = max(mA,mB); fX = e^{mX-m} / (lA e^{mA-m} + lB e^{mB-m})
      float fA[2], fB[2];
#pragma unroll
      for (int m = 0; m < 2; ++m) {
        float mB = mgK[offM + m];
        float lB = mgK[offM + 2 + m];
        float mM = fmaxf(m_run[m], mB);
        float cA = __builtin_amdgcn_exp2f(m_run[m] - mM);
        float cB = __builtin_amdgcn_exp2f(mB - mM);
        float inv = 1.0f / (lfin[m] * cA + lB * cB);
        fA[m] = cA * inv;
        fB[m] = cB * inv;
      }
#pragma unroll
      for (int m = 0; m < 2; ++m)
#pragma unroll
        for (int i = 0; i < 4; ++i) {
          float a = __shfl(fA[m], qq * 4 + i);  // factor for q = m*16 + qq*4 + i
          float bq = __shfl(fB[m], qq * 4 + i);
          float* mg = (m == 0) ? mgK : mgV;
#pragma unroll
          for (int n = 0; n < 4; ++n) {
            float o = acc[m][n][i] * a + mg[offA + n * 4 + i] * bq;
            Y[((size_t)(b * 2048 + q0w + m * 16 + qq * 4 + i)) * 1024 + h * 64 +
              n * 16 + r] = f2b(o);
          }
        }
    }
    __syncthreads();  // merge reads done before next phase's STAGE overwrites
  }
#undef STAGE
}

// ---------------- launch ----------------
extern "C" void kernel_launch(void* const* d_in, const int* in_sizes, int n_in,
                              void* d_out, int out_size, void* d_ws, size_t ws_size,
                              hipStream_t stream) {
  const float* x = (const float*)d_in[0];       // [4,2048,1024]
  const float* w_attn = (const float*)d_in[1];  // [1024,3072]
  const float* w_o = (const float*)d_in[2];     // [1024,1024]
  float* out = (float*)d_out;                   // [4,2048,1024]

  char* ws = (char*)d_ws;
  u16* xb = (u16*)(ws + 0);                    // [8192][1024]        16,777,216 B
  u16* watT = (u16*)(ws + 16777216);           // [3072][1024]         6,291,456 B
  u16* woT = (u16*)(ws + 23068672);            // [1024][1024]         2,097,152 B
  u16* qb = (u16*)(ws + 25165824);             // q [4][16][2048][64] 16,777,216 B
  u16* kb = (u16*)(ws + 41943040);             // k                   16,777,216 B
  u16* vb = (u16*)(ws + 58720256);             // V^T [4][16][64][2048] 16,777,216 B
  u16* yb = (u16*)(ws + 75497472);             // y [4][2048][1024]   16,777,216 B

  k_cvt<<<2048, 256, 0, stream>>>(x, xb, 8192 * 1024 / 4);
  k_tr<<<dim3(3072 / 32, 1024 / 32), dim3(32, 8), 0, stream>>>(w_attn, watT, 1024, 3072);
  k_tr<<<dim3(1024 / 32, 1024 / 32), dim3(32, 8), 0, stream>>>(w_o, woT, 1024, 1024);
  k_gemm<0><<<dim3(24, 64), 256, 0, stream>>>(xb, watT, (void*)qb);
  k_attn<<<dim3(512), 512, 0, stream>>>(qb, kb, vb, yb);
  k_gemm<1><<<dim3(8, 64), 256, 0, stream>>>(yb, woT, (void*)out);
}